// Round 4
// baseline (278.450 us; speedup 1.0000x reference)
//
#include <hip/hip_runtime.h>
#include <hip/hip_bf16.h>

// Problem: B=2, S=2048, D=1024, H=16, hd=64
// ws layout (58 MiB, bf16-element offsets from d_ws):
//   Xb  [0, 4M)        8 MiB  (x bf16)             -- dead after gemm_qkv
//   PO0 [0, 4M)        8 MiB  (attn partial half0) -- aliases Xb
//   Wt  [4M, 7M)       6 MiB  (Wqkv^T bf16)        -- dead after gemm_qkv
//   PO1 [4M, 8M)       8 MiB  (attn partial half1) -- aliases Wt+gap
//   Qb  [8M, 12M)      8 MiB
//   Kb  [12M, 16M)     8 MiB
//   Vtb [16M, 20M)     8 MiB  (V^T [B,H,hd,S])     -- dead after attn
//   AOb [16M, 20M)     8 MiB  (combined attn out)  -- aliases Vtb
//   MB  [20M, 28M)    16 MiB  (mask+bias, S^T-fragment order, *log2e)
//   Wt2 [28M+..]       2 MiB  (Wout^T bf16)
//   L sums (f32, 512KB) live at the FRONT of d_out (overwritten by gemm_out).
//
// R11: R10 (QBLK=128) gave -7%: efficiency doubled but occupancy fell to
// 2 waves/SIMD; still ~45% issue-idle (latency-bound). Fix #1: KV-SPLIT x2
// -- each wg does 16 k-tiles, grid 1024 = 4 wg/CU = 4 waves/SIMD, partial
// unnormalized O + row-sums combined by a small elementwise kernel.
// Fix #2: fuse cvt_x + 2x cvt_wt + mb_fuse into ONE preprocess dispatch
// (7 -> 5 kernels; removes launch gaps, co-schedules memory-bound jobs).

#define S_LEN 2048
#define DMODEL 1024
#define NH 16
#define HD 64

typedef __bf16 bf16x8 __attribute__((ext_vector_type(8)));
typedef __bf16 bf16x4 __attribute__((ext_vector_type(4)));
typedef __bf16 bf16x2v __attribute__((ext_vector_type(2)));
typedef float f32x4 __attribute__((ext_vector_type(4)));
typedef short s16x4 __attribute__((ext_vector_type(4)));

#define GLD_LDS16(g, l)                                              \
  __builtin_amdgcn_global_load_lds(                                  \
      (const __attribute__((address_space(1))) unsigned int*)(g),    \
      (__attribute__((address_space(3))) unsigned int*)(l), 16, 0, 0)

#if __has_builtin(__builtin_amdgcn_mfma_f32_16x16x16bf16_1k)
#define HAVE_MFMA_16x16x16_BF16 1
#else
#define HAVE_MFMA_16x16x16_BF16 0
#endif

#if __has_builtin(__builtin_amdgcn_exp2f)
#define EXP2F(x) __builtin_amdgcn_exp2f(x)
#else
static __device__ __forceinline__ float EXP2F(float x) {
  float r;
  asm volatile("v_exp_f32 %0, %1" : "=v"(r) : "v"(x));
  return r;
}
#endif

#define LOG2E 1.44269504f

// ---------- fused preprocess: cvt_x | cvt_wt(Wqkv) | cvt_wt(Wout) | mb_fuse
// blockIdx.x ranges: [0,4096) cvt_x, [4096,4864) Wqkv^T, [4864,5120) Wout^T,
// [5120,7168) mb_fuse. One dispatch replaces four.
__global__ __launch_bounds__(256) void preprocess(
    const float* __restrict__ x, const float* __restrict__ mask,
    const float* __restrict__ bias, const float* __restrict__ Wqkv,
    const float* __restrict__ Wout, __bf16* __restrict__ Xb,
    __bf16* __restrict__ Wt, __bf16* __restrict__ Wt2,
    __bf16* __restrict__ MB) {
  __shared__ __align__(16) char smem[64 * 65 * 4];
  const int bid = blockIdx.x;
  const int tid = threadIdx.x;

  if (bid < 4096) {
    // ---- cvt_x: fp32 -> bf16 ----
    int i = bid * 256 + tid;
    float4 v = ((const float4*)x)[i];
    bf16x4 o = {(__bf16)v.x, (__bf16)v.y, (__bf16)v.z, (__bf16)v.w};
    *(bf16x4*)&Xb[(size_t)i * 4] = o;
  } else if (bid < 5120) {
    // ---- cvt_wt: W[1024,ncols] -> Wt[ncols,1024] bf16 transpose ----
    const float* W;
    __bf16* Wo;
    int ncols, n0, k0;
    if (bid < 4864) {
      int id = bid - 4096;
      W = Wqkv; Wo = Wt; ncols = 3072;
      n0 = (id % 48) * 64; k0 = (id / 48) * 64;
    } else {
      int id = bid - 4864;
      W = Wout; Wo = Wt2; ncols = 1024;
      n0 = (id & 15) * 64; k0 = (id >> 4) * 64;
    }
    float(*tile)[65] = (float(*)[65])smem;
    {
      int c = tid & 63, r4 = tid >> 6;
#pragma unroll
      for (int p = 0; p < 16; ++p) {
        int r = r4 + p * 4;
        tile[r][c] = W[(size_t)(k0 + r) * ncols + n0 + c];
      }
    }
    __syncthreads();
    {
      int cc = (tid & 31) * 2, r8 = tid >> 5;
#pragma unroll
      for (int p = 0; p < 8; ++p) {
        int rr = r8 + p * 8;
        bf16x2v o = {(__bf16)tile[cc][rr], (__bf16)tile[cc + 1][rr]};
        *(bf16x2v*)&Wo[(size_t)(n0 + rr) * 1024 + k0 + cc] = o;
      }
    }
  } else {
    // ---- mb_fuse: (mask+bias)*log2e -> per-lane S^T-fragment tiles ----
    int id = bid - 5120;
    const int kt = id & 31, qt = (id >> 5) & 31, b = id >> 10;
    __bf16(*sm)[68] = (__bf16(*)[68])smem;
    {
      const int r0 = tid >> 4;
      const int cc = (tid & 15) * 4;
      const float* mrow = mask + (size_t)(qt * 64) * S_LEN + kt * 64;
      const float* brow =
          bias + ((size_t)b * S_LEN + qt * 64) * S_LEN + kt * 64;
#pragma unroll
      for (int p = 0; p < 4; ++p) {
        int r = r0 + p * 16;
        float4 m = *(const float4*)(mrow + (size_t)r * S_LEN + cc);
        float4 a = *(const float4*)(brow + (size_t)r * S_LEN + cc);
        sm[r][cc + 0] = (__bf16)((m.x + a.x) * LOG2E);
        sm[r][cc + 1] = (__bf16)((m.y + a.y) * LOG2E);
        sm[r][cc + 2] = (__bf16)((m.z + a.z) * LOG2E);
        sm[r][cc + 3] = (__bf16)((m.w + a.w) * LOG2E);
      }
    }
    __syncthreads();
    const int w = tid >> 6, lane = tid & 63;
    const int quad = lane >> 4, cl = lane & 15;
    __bf16 vals[16];
#pragma unroll
    for (int ct = 0; ct < 4; ++ct) {
      bf16x4 v = *(const bf16x4*)&sm[w * 16 + cl][ct * 16 + quad * 4];
      *(bf16x4*)&vals[ct * 4] = v;
    }
    __bf16* op =
        MB + (((size_t)(b * 32 + qt) * 32 + kt) * 4096) + (w * 64 + lane) * 16;
    *(bf16x8*)op = *(bf16x8*)&vals[0];
    *(bf16x8*)(op + 8) = *(bf16x8*)&vals[8];
  }
}

// ---------------- QKV projection: bf16 MFMA 128x128 tile ----------------
__global__ __launch_bounds__(256) void gemm_qkv_mfma(
    const __bf16* __restrict__ Xb, const __bf16* __restrict__ Wt,
    const float* __restrict__ bqkv, __bf16* __restrict__ Qb,
    __bf16* __restrict__ Kb, __bf16* __restrict__ Vtb) {
  __shared__ __align__(16) __bf16 As[128 * 32];
  __shared__ __align__(16) __bf16 Bs[128 * 32];
  const int tid = threadIdx.x;
  const int w = tid >> 6, lane = tid & 63;
  const int c = lane & 15, quad = lane >> 4;
  const int wm = w >> 1, wn = w & 1;
  const int rowBase = blockIdx.y * 128;
  const int colBase = blockIdx.x * 128;

  f32x4 acc[4][4] = {};

  const __bf16* gA0 =
      Xb + (size_t)(rowBase + w * 32 + (lane >> 2)) * 1024 + (lane & 3) * 8;
  const __bf16* gB0 =
      Wt + (size_t)(colBase + w * 32 + (lane >> 2)) * 1024 + (lane & 3) * 8;
  __bf16* lA0 = &As[(w * 32) * 32];
  __bf16* lB0 = &Bs[(w * 32) * 32];

  for (int k0 = 0; k0 < 1024; k0 += 32) {
    __syncthreads();
#pragma unroll
    for (int p = 0; p < 2; ++p) {
      GLD_LDS16(gA0 + (size_t)p * 16 * 1024 + k0, lA0 + p * 16 * 32);
      GLD_LDS16(gB0 + (size_t)p * 16 * 1024 + k0, lB0 + p * 16 * 32);
    }
    __syncthreads();

    bf16x8 af[4], bfr[4];
#pragma unroll
    for (int mt = 0; mt < 4; ++mt)
      af[mt] = *(const bf16x8*)&As[(wm * 64 + mt * 16 + c) * 32 + quad * 8];
#pragma unroll
    for (int nt = 0; nt < 4; ++nt)
      bfr[nt] = *(const bf16x8*)&Bs[(wn * 64 + nt * 16 + c) * 32 + quad * 8];
#pragma unroll
    for (int mt = 0; mt < 4; ++mt)
#pragma unroll
      for (int nt = 0; nt < 4; ++nt)
        acc[mt][nt] = __builtin_amdgcn_mfma_f32_16x16x32_bf16(
            af[mt], bfr[nt], acc[mt][nt], 0, 0, 0);
  }

#pragma unroll
  for (int mt = 0; mt < 4; ++mt) {
    int row0 = rowBase + wm * 64 + mt * 16 + quad * 4;
#pragma unroll
    for (int nt = 0; nt < 4; ++nt) {
      int col = colBase + wn * 64 + nt * 16 + c;
      float bias = bqkv[col];
      int three = col >> 10;
      int h = (col & 1023) >> 6;
      int d = col & 63;
#pragma unroll
      for (int r = 0; r < 4; ++r) {
        int rr = row0 + r;
        int bb = rr >> 11, s = rr & 2047;
        float val = acc[mt][nt][r] + bias;
        size_t ho = (size_t)(bb * NH + h);
        if (three == 0)
          Qb[(ho * S_LEN + s) * HD + d] = (__bf16)val;
        else if (three == 1)
          Kb[(ho * S_LEN + s) * HD + d] = (__bf16)val;
        else
          Vtb[(ho * HD + d) * S_LEN + s] = (__bf16)val;
      }
    }
  }
}

// ------- MFMA flash attention: S^T dataflow, QBLK=128, KV-SPLIT x2 -------
// blockIdx.z = b*2 + half; each wg covers k-tiles [half*16, half*16+16).
// Writes UNNORMALIZED partial O (bf16) to PO[half] and row-sums (f32) to
// L[half]. No max-shift -> halves share the same (absent) max, so the
// combine is a plain sum: O = (PO0+PO1)/(L0+L1).
__global__ __launch_bounds__(256) void attn_mfma(
    const __bf16* __restrict__ Qb, const __bf16* __restrict__ Kb,
    const __bf16* __restrict__ Vtb, const __bf16* __restrict__ MB,
    __bf16* __restrict__ PO, float* __restrict__ L) {
  const int qt = blockIdx.x, h = blockIdx.y;
  const int b = blockIdx.z >> 1, half = blockIdx.z & 1;
  const int kt0 = half * 16;  // local k-tile window [kt0, kt0+16)
  const int tid = threadIdx.x;
  const int w = tid >> 6;
  const int lane = tid & 63;
  const int c = lane & 15;
  const int quad = lane >> 4;

  __shared__ __align__(16) __bf16 Ks[2][64 * 64];
  __shared__ __align__(16) __bf16 Vs[2][64 * 64];  // [feat][key], swizzled
#if !HAVE_MFMA_16x16x16_BF16
  __shared__ __align__(16) __bf16 P2[4][16 * 72];  // fallback: P^T per wave
#endif

  const size_t headoff = (size_t)(b * NH + h) * S_LEN * HD;
  const __bf16* Qg = Qb + headoff + (size_t)(qt * 128) * HD;
  const __bf16* Kg = Kb + headoff;
  const __bf16* Vg = Vtb + headoff;  // [hd][S]
  // MB tile bases for the two q-groups, offset to this half's k-window
  const __bf16* MBq0 = MB + ((size_t)(b * 32 + qt * 2 + 0) * 32 + kt0) * 4096 +
                       (w * 64 + lane) * 16;
  const __bf16* MBq1 = MB + ((size_t)(b * 32 + qt * 2 + 1) * 32 + kt0) * 4096 +
                       (w * 64 + lane) * 16;

  __bf16* POx = PO + (size_t)half * 4194304;
  float* Lx = L + half * 65536;

  // staging geometry (chunk ch = p*256+tid -> row f, col-chunk j, swizzled)
  const int f0 = tid >> 3, f1 = f0 + 32;
  const int j = tid & 7;
  const int sj0 = j ^ (f0 & 7);
  const int sj1 = j ^ (f1 & 7);
  const int lds0 = tid * 8;
  const int lds1 = (256 + tid) * 8;

  // Q fragments: lane holds Q[qrow=g*64+w*16+c][d=quad*8+j] (loop-invariant)
  bf16x8 qa[2][2];
#pragma unroll
  for (int g = 0; g < 2; ++g) {
    qa[g][0] = *(const bf16x8*)(Qg + (g * 64 + w * 16 + c) * HD + quad * 8);
    qa[g][1] =
        *(const bf16x8*)(Qg + (g * 64 + w * 16 + c) * HD + quad * 8 + 32);
  }

  // swizzled b128 read offsets (row&7 == c&7)
  const int rs0 = (quad ^ (c & 7)) * 8;
  const int rs1 = ((quad + 4) ^ (c & 7)) * 8;

  f32x4 Oa[2][4] = {};  // O^T[d=ft*16+quad*4+r][qrow=c] per group
  f32x4 psum[2] = {};   // packed row-partial sums of p per group

  // preamble: DMA local tile 0 (global k-tile kt0) into buffer 0
  const int kb0 = kt0 * 64;
  GLD_LDS16(Kg + (size_t)(kb0 + f0) * HD + sj0 * 8, &Ks[0][lds0]);
  GLD_LDS16(Kg + (size_t)(kb0 + f1) * HD + sj1 * 8, &Ks[0][lds1]);
  GLD_LDS16(Vg + (size_t)f0 * S_LEN + kb0 + sj0 * 8, &Vs[0][lds0]);
  GLD_LDS16(Vg + (size_t)f1 * S_LEN + kb0 + sj1 * 8, &Vs[0][lds1]);

  // strength-reduced DMA source pointers (next-tile positions)
  const __bf16* kgp0 = Kg + (size_t)(kb0 + 64 + f0) * HD + sj0 * 8;
  const __bf16* kgp1 = Kg + (size_t)(kb0 + 64 + f1) * HD + sj1 * 8;
  const __bf16* vgp0 = Vg + (size_t)f0 * S_LEN + kb0 + 64 + sj0 * 8;
  const __bf16* vgp1 = Vg + (size_t)f1 * S_LEN + kb0 + 64 + sj1 * 8;

  // MB fragment prefetch (local tile 0, both groups)
  bf16x8 rMB[2][2];
  rMB[0][0] = *(const bf16x8*)MBq0;
  rMB[0][1] = *(const bf16x8*)(MBq0 + 8);
  rMB[1][0] = *(const bf16x8*)MBq1;
  rMB[1][1] = *(const bf16x8*)(MBq1 + 8);

  __syncthreads();

  const float c1 = 0.125f * LOG2E;  // 1/sqrt(hd) * log2(e)

#pragma unroll 2
  for (int lkt = 0; lkt < 16; ++lkt) {
    const int cur = lkt & 1, nxt = cur ^ 1;
    // prefetch next MB fragments (over-read on last iter lands in the
    // following MB tile / Wt2 region -- allocated, read-only, safe)
    bf16x8 nMB[2][2];
    {
      const __bf16* m0 = MBq0 + (size_t)(lkt + 1) * 4096;
      const __bf16* m1 = MBq1 + (size_t)(lkt + 1) * 4096;
      nMB[0][0] = *(const bf16x8*)m0;
      nMB[0][1] = *(const bf16x8*)(m0 + 8);
      nMB[1][0] = *(const bf16x8*)m1;
      nMB[1][1] = *(const bf16x8*)(m1 + 8);
    }
    // async DMA of next local tile into the inactive buffer
    if (lkt < 15) {
      GLD_LDS16(kgp0, &Ks[nxt][lds0]);
      GLD_LDS16(kgp1, &Ks[nxt][lds1]);
      GLD_LDS16(vgp0, &Vs[nxt][lds0]);
      GLD_LDS16(vgp1, &Vs[nxt][lds1]);
    }
    kgp0 += 64 * HD;
    kgp1 += 64 * HD;
    vgp0 += 64;
    vgp1 += 64;

    // ---- K fragment reads (shared by both q-groups) ----
    bf16x8 kf0[4], kf1[4];
#pragma unroll
    for (int ct = 0; ct < 4; ++ct) {
      kf0[ct] = *(const bf16x8*)&Ks[cur][(ct * 16 + c) * 64 + rs0];
      kf1[ct] = *(const bf16x8*)&Ks[cur][(ct * 16 + c) * 64 + rs1];
    }

    // ---- S^T = K * Q^T for both groups (pure-register MFMA cluster) ----
    f32x4 sv[2][4];
    __builtin_amdgcn_s_setprio(1);
#pragma unroll
    for (int g = 0; g < 2; ++g)
#pragma unroll
      for (int ct = 0; ct < 4; ++ct) {
        f32x4 a = {};
        a = __builtin_amdgcn_mfma_f32_16x16x32_bf16(kf0[ct], qa[g][0], a, 0,
                                                    0, 0);
        a = __builtin_amdgcn_mfma_f32_16x16x32_bf16(kf1[ct], qa[g][1], a, 0,
                                                    0, 0);
        sv[g][ct] = a;
      }
    __builtin_amdgcn_s_setprio(0);

#if HAVE_MFMA_16x16x16_BF16
    // ---- V fragment reads (shared by both groups) ----
    s16x4 vf[4][4];
#pragma unroll
    for (int ft = 0; ft < 4; ++ft) {
      const int fr = ft * 16 + c;
#pragma unroll
      for (int ct = 0; ct < 4; ++ct) {
        const int chunk = ((ct * 2 + (quad >> 1)) ^ (fr & 7)) * 8 +
                          (quad & 1) * 4;
        vf[ft][ct] = *(const s16x4*)&Vs[cur][fr * 64 + chunk];
      }
    }
#endif

    // p = exp2(s*c1 + mb'), packed row-partial psum, pack P^T fragments
    s16x4 pb[2][4];
#pragma unroll
    for (int g = 0; g < 2; ++g)
#pragma unroll
      for (int ct = 0; ct < 4; ++ct) {
        f32x4 pv;
#pragma unroll
        for (int r = 0; r < 4; ++r) {
          float mb = (ct < 2) ? (float)rMB[g][0][ct * 4 + r]
                              : (float)rMB[g][1][(ct - 2) * 4 + r];
          pv[r] = EXP2F(sv[g][ct][r] * c1 + mb);
        }
        psum[g] += pv;
        __bf16 t4[4];
#pragma unroll
        for (int r = 0; r < 4; ++r) t4[r] = (__bf16)pv[r];
        pb[g][ct] = *(s16x4*)t4;
      }
#pragma unroll
    for (int g = 0; g < 2; ++g) {
      rMB[g][0] = nMB[g][0];
      rMB[g][1] = nMB[g][1];
    }

#if HAVE_MFMA_16x16x16_BF16
    // ---- O^T += V^T * P^T: pure-register MFMA cluster, both groups ----
    __builtin_amdgcn_s_setprio(1);
#pragma unroll
    for (int g = 0; g < 2; ++g)
#pragma unroll
      for (int ft = 0; ft < 4; ++ft)
#pragma unroll
        for (int ct = 0; ct < 4; ++ct)
          Oa[g][ft] = __builtin_amdgcn_mfma_f32_16x16x16bf16_1k(
              vf[ft][ct], pb[g][ct], Oa[g][ft], 0, 0, 0);
    __builtin_amdgcn_s_setprio(0);
#else
    // ---- fallback: P^T via wave-private LDS (b64 writes, b128 reads) ----
#pragma unroll
    for (int g = 0; g < 2; ++g) {
#pragma unroll
      for (int ct = 0; ct < 4; ++ct)
        *(bf16x4*)&P2[w][c * 72 + ct * 16 + quad * 4] = *(bf16x4*)&pb[g][ct];
      bf16x8 pf0 = *(const bf16x8*)&P2[w][c * 72 + quad * 8];
      bf16x8 pf1 = *(const bf16x8*)&P2[w][c * 72 + 32 + quad * 8];
#pragma unroll
      for (int ft = 0; ft < 4; ++ft) {
        const int fr = ft * 16 + c;
        bf16x8 vf0 = *(const bf16x8*)&Vs[cur][fr * 64 + rs0];
        bf16x8 vf1 = *(const bf16x8*)&Vs[cur][fr * 64 + rs1];
        Oa[g][ft] = __builtin_amdgcn_mfma_f32_16x16x32_bf16(vf0, pf0,
                                                            Oa[g][ft], 0, 0, 0);
        Oa[g][ft] = __builtin_amdgcn_mfma_f32_16x16x32_bf16(vf1, pf1,
                                                            Oa[g][ft], 0, 0, 0);
      }
    }
#endif

    // one barrier per iter: LDS[cur] reads done; implicit vmcnt(0) completes
    // the next-tile DMAs (issued before the full compute body).
    __syncthreads();
  }
  // row-sum reduce + store partial L and UNNORMALIZED partial O
#pragma unroll
  for (int g = 0; g < 2; ++g) {
    float lsum = psum[g][0] + psum[g][1] + psum[g][2] + psum[g][3];
    lsum += __shfl_xor(lsum, 16);
    lsum += __shfl_xor(lsum, 32);
    if (lane < 16)  // quad 0: one writer per q-row
      Lx[(size_t)(b * NH + h) * S_LEN + qt * 128 + g * 64 + w * 16 + c] = lsum;
    __bf16* orow = POx +
                   (size_t)(b * S_LEN + qt * 128 + g * 64 + w * 16 + c) *
                       DMODEL +
                   h * HD;
#pragma unroll
    for (int ft = 0; ft < 4; ++ft) {
      __bf16 t4[4];
#pragma unroll
      for (int r = 0; r < 4; ++r) t4[r] = (__bf16)Oa[g][ft][r];
      *(bf16x4*)(orow + ft * 16 + quad * 4) = *(bf16x4*)t4;
    }
  }
}

// -------- combine: AOb = (PO0 + PO1) / (L0 + L1), elementwise --------
__global__ __launch_bounds__(256) void combine(const __bf16* __restrict__ PO,
                                               const float* __restrict__ L,
                                               __bf16* __restrict__ AOb) {
  const int i = blockIdx.x * 256 + threadIdx.x;
  const size_t e = (size_t)i * 8;
  const int hidx = (int)(e >> 6) & 15;
  const int s = (int)(e >> 10) & 2047;
  const int b = (int)(e >> 21);
  const size_t li = ((size_t)(b * NH + hidx) << 11) + s;
  const float invl = 1.0f / (L[li] + L[65536 + li]);
  bf16x8 a = *(const bf16x8*)&PO[e];
  bf16x8 c = *(const bf16x8*)&PO[4194304 + e];
  __bf16 o[8];
#pragma unroll
  for (int k = 0; k < 8; ++k)
    o[k] = (__bf16)(((float)a[k] + (float)c[k]) * invl);
  *(bf16x8*)&AOb[e] = *(bf16x8*)o;
}

// ---------------- Output projection: bf16 MFMA 128x64 tile ----------------
__global__ __launch_bounds__(256) void gemm_out_mfma(
    const __bf16* __restrict__ AOb, const __bf16* __restrict__ Wt2,
    const float* __restrict__ bout, float* __restrict__ Out) {
  __shared__ __align__(16) __bf16 As[128 * 32];
  __shared__ __align__(16) __bf16 Bs[64 * 32];
  const int tid = threadIdx.x;
  const int w = tid >> 6, lane = tid & 63;
  const int c = lane & 15, quad = lane >> 4;
  const int rowBase = blockIdx.y * 128;
  const int colBase = blockIdx.x * 64;

  f32x4 acc[2][4] = {};

  const __bf16* gA0 =
      AOb + (size_t)(rowBase + w * 32 + (lane >> 2)) * 1024 + (lane & 3) * 8;
  const __bf16* gB0 =
      Wt2 + (size_t)(colBase + w * 16 + (lane >> 2)) * 1024 + (lane & 3) * 8;
  __bf16* lA0 = &As[(w * 32) * 32];
  __bf16* lB0 = &Bs[(w * 16) * 32];

  for (int k0 = 0; k0 < 1024; k0 += 32) {
    __syncthreads();
#pragma unroll
    for (int p = 0; p < 2; ++p)
      GLD_LDS16(gA0 + (size_t)p * 16 * 1024 + k0, lA0 + p * 16 * 32);
    GLD_LDS16(gB0 + k0, lB0);
    __syncthreads();

    bf16x8 af[2], bfr[4];
#pragma unroll
    for (int mt = 0; mt < 2; ++mt)
      af[mt] = *(const bf16x8*)&As[(w * 32 + mt * 16 + c) * 32 + quad * 8];
#pragma unroll
    for (int nt = 0; nt < 4; ++nt)
      bfr[nt] = *(const bf16x8*)&Bs[(nt * 16 + c) * 32 + quad * 8];
#pragma unroll
    for (int mt = 0; mt < 2; ++mt)
#pragma unroll
      for (int nt = 0; nt < 4; ++nt)
        acc[mt][nt] = __builtin_amdgcn_mfma_f32_16x16x32_bf16(
            af[mt], bfr[nt], acc[mt][nt], 0, 0, 0);
  }

#pragma unroll
  for (int mt = 0; mt < 2; ++mt) {
    int row0 = rowBase + w * 32 + mt * 16 + quad * 4;
#pragma unroll
    for (int nt = 0; nt < 4; ++nt) {
      int col = colBase + nt * 16 + c;
      float bias = bout[col];
#pragma unroll
      for (int r = 0; r < 4; ++r)
        Out[(size_t)(row0 + r) * 1024 + col] = acc[mt][nt][r] + bias;
    }
  }
}

extern "C" void kernel_launch(void* const* d_in, const int* in_sizes, int n_in,
                              void* d_out, int out_size, void* d_ws,
                              size_t ws_size, hipStream_t stream) {
  const float* x = (const float*)d_in[0];
  const float* attn_mask = (const float*)d_in[1];
  const float* attn_bias = (const float*)d_in[2];
  const float* Wqkv = (const float*)d_in[3];
  const float* bqkv = (const float*)d_in[4];
  const float* Wout = (const float*)d_in[5];
  const float* bout = (const float*)d_in[6];
  float* out = (float*)d_out;

  __bf16* base = (__bf16*)d_ws;
  __bf16* Xb = base;                  // [0, 4M)
  __bf16* PO = base;                  // PO0 [0,4M), PO1 [4M,8M)
  __bf16* Wt = base + 4194304;        // [4M, 7M)
  __bf16* Qb = base + 8388608;        // [8M, 12M)
  __bf16* Kb = base + 12582912;       // [12M, 16M)
  __bf16* Vtb = base + 16777216;      // [16M, 20M)
  __bf16* AOb = base + 16777216;      // aliases Vtb (disjoint lifetime)
  __bf16* MB = base + 20971520;       // [20M, 28M)
  __bf16* Wt2 = base + 29360128;      // [28M, 29M)
  float* Lf = (float*)d_out;          // 512 KB at front of out (temp)

  preprocess<<<7168, 256, 0, stream>>>(x, attn_mask, attn_bias, Wqkv, Wout,
                                       Xb, Wt, Wt2, MB);
  gemm_qkv_mfma<<<dim3(24, 32), 256, 0, stream>>>(Xb, Wt, bqkv, Qb, Kb, Vtb);
  attn_mfma<<<dim3(16, NH, 4), 256, 0, stream>>>(Qb, Kb, Vtb, MB, PO, Lf);
  combine<<<2048, 256, 0, stream>>>(PO, Lf, AOb);
  gemm_out_mfma<<<dim3(16, 32), 256, 0, stream>>>(AOb, Wt2, bout, out);
}

// Round 5
// 270.814 us; speedup vs baseline: 1.0282x; 1.0282x over previous
//
#include <hip/hip_runtime.h>
#include <hip/hip_bf16.h>

// Problem: B=2, S=2048, D=1024, H=16, hd=64
// ws layout (58 MiB, bf16-element offsets from d_ws):
//   Xb  [0, 4M)        8 MiB  (x bf16)             -- dead after gemm_qkv
//   AOb [0, 4M)        8 MiB  (attn out bf16)      -- aliases Xb
//   Wt  [4M, 7M)       6 MiB  (Wqkv^T bf16)
//   Qb  [8M, 12M)      8 MiB
//   Kb  [12M, 16M)     8 MiB
//   Vtb [16M, 20M)     8 MiB  (V^T [B,H,hd,S])
//   MB  [20M, 28M)    16 MiB  (mask+bias, S^T-fragment order, *log2e)
//   Wt2 [28M+..]       2 MiB  (Wout^T bf16)
//
// R12: R11's KV-split was a no-op -- occupancy/VALUBusy/dur all identical,
// proving residency is pinned at 2 wg/CU by REGISTERS (VGPR_Count=128 is
// arch-only; unified VGPR+AGPR ~190/wave -> 2 waves/SIMD). Reverted.
// The wall is per-iteration sync overhead (~4000 cy/iter vs ~1100 compute)
// at fixed 2 wg/CU. Fix: amortize -- TWO 64-key subtiles per barrier
// (KVBLK=128 effective, LDS 64 KB, registers reused across subtiles).
// Barrier count 32 -> 16 per wg; DMA cover doubled. Also: mb_fuse handles
// both b per block (mask read once, -16 MB HBM).

#define S_LEN 2048
#define DMODEL 1024
#define NH 16
#define HD 64

typedef __bf16 bf16x8 __attribute__((ext_vector_type(8)));
typedef __bf16 bf16x4 __attribute__((ext_vector_type(4)));
typedef __bf16 bf16x2v __attribute__((ext_vector_type(2)));
typedef float f32x4 __attribute__((ext_vector_type(4)));
typedef short s16x4 __attribute__((ext_vector_type(4)));

#define GLD_LDS16(g, l)                                              \
  __builtin_amdgcn_global_load_lds(                                  \
      (const __attribute__((address_space(1))) unsigned int*)(g),    \
      (__attribute__((address_space(3))) unsigned int*)(l), 16, 0, 0)

#if __has_builtin(__builtin_amdgcn_mfma_f32_16x16x16bf16_1k)
#define HAVE_MFMA_16x16x16_BF16 1
#else
#define HAVE_MFMA_16x16x16_BF16 0
#endif

#if __has_builtin(__builtin_amdgcn_exp2f)
#define EXP2F(x) __builtin_amdgcn_exp2f(x)
#else
static __device__ __forceinline__ float EXP2F(float x) {
  float r;
  asm volatile("v_exp_f32 %0, %1" : "=v"(r) : "v"(x));
  return r;
}
#endif

#define LOG2E 1.44269504f

// ---------- fused preprocess: cvt_x | cvt_wt(Wqkv) | cvt_wt(Wout) | mb_fuse
// blockIdx.x ranges: [0,4096) cvt_x, [4096,4864) Wqkv^T, [4864,5120) Wout^T,
// [5120,6144) mb_fuse (BOTH b per block; mask read once).
__global__ __launch_bounds__(256) void preprocess(
    const float* __restrict__ x, const float* __restrict__ mask,
    const float* __restrict__ bias, const float* __restrict__ Wqkv,
    const float* __restrict__ Wout, __bf16* __restrict__ Xb,
    __bf16* __restrict__ Wt, __bf16* __restrict__ Wt2,
    __bf16* __restrict__ MB) {
  __shared__ __align__(16) char smem[64 * 65 * 4];
  const int bid = blockIdx.x;
  const int tid = threadIdx.x;

  if (bid < 4096) {
    // ---- cvt_x: fp32 -> bf16 ----
    int i = bid * 256 + tid;
    float4 v = ((const float4*)x)[i];
    bf16x4 o = {(__bf16)v.x, (__bf16)v.y, (__bf16)v.z, (__bf16)v.w};
    *(bf16x4*)&Xb[(size_t)i * 4] = o;
  } else if (bid < 5120) {
    // ---- cvt_wt: W[1024,ncols] -> Wt[ncols,1024] bf16 transpose ----
    const float* W;
    __bf16* Wo;
    int ncols, n0, k0;
    if (bid < 4864) {
      int id = bid - 4096;
      W = Wqkv; Wo = Wt; ncols = 3072;
      n0 = (id % 48) * 64; k0 = (id / 48) * 64;
    } else {
      int id = bid - 4864;
      W = Wout; Wo = Wt2; ncols = 1024;
      n0 = (id & 15) * 64; k0 = (id >> 4) * 64;
    }
    float(*tile)[65] = (float(*)[65])smem;
    {
      int c = tid & 63, r4 = tid >> 6;
#pragma unroll
      for (int p = 0; p < 16; ++p) {
        int r = r4 + p * 4;
        tile[r][c] = W[(size_t)(k0 + r) * ncols + n0 + c];
      }
    }
    __syncthreads();
    {
      int cc = (tid & 31) * 2, r8 = tid >> 5;
#pragma unroll
      for (int p = 0; p < 8; ++p) {
        int rr = r8 + p * 8;
        bf16x2v o = {(__bf16)tile[cc][rr], (__bf16)tile[cc + 1][rr]};
        *(bf16x2v*)&Wo[(size_t)(n0 + rr) * 1024 + k0 + cc] = o;
      }
    }
  } else {
    // ---- mb_fuse: (mask+bias)*log2e, BOTH b, mask loaded once ----
    int id = bid - 5120;  // [0,1024)
    const int kt = id & 31, qt = id >> 5;
    __bf16(*sm)[68] = (__bf16(*)[68])smem;
    const int r0 = tid >> 4;        // 0..15
    const int cc = (tid & 15) * 4;  // 0,4,..,60
    const float* mrow = mask + (size_t)(qt * 64) * S_LEN + kt * 64;
    float4 mld[4];
#pragma unroll
    for (int p = 0; p < 4; ++p)
      mld[p] = *(const float4*)(mrow + (size_t)(r0 + p * 16) * S_LEN + cc);
    const int w = tid >> 6, lane = tid & 63;
    const int quad = lane >> 4, cl = lane & 15;
    for (int b = 0; b < 2; ++b) {
      const float* brow =
          bias + ((size_t)b * S_LEN + qt * 64) * S_LEN + kt * 64;
#pragma unroll
      for (int p = 0; p < 4; ++p) {
        int r = r0 + p * 16;
        float4 a = *(const float4*)(brow + (size_t)r * S_LEN + cc);
        sm[r][cc + 0] = (__bf16)((mld[p].x + a.x) * LOG2E);
        sm[r][cc + 1] = (__bf16)((mld[p].y + a.y) * LOG2E);
        sm[r][cc + 2] = (__bf16)((mld[p].z + a.z) * LOG2E);
        sm[r][cc + 3] = (__bf16)((mld[p].w + a.w) * LOG2E);
      }
      __syncthreads();
      __bf16 vals[16];
#pragma unroll
      for (int ct = 0; ct < 4; ++ct) {
        bf16x4 v = *(const bf16x4*)&sm[w * 16 + cl][ct * 16 + quad * 4];
        *(bf16x4*)&vals[ct * 4] = v;
      }
      __bf16* op = MB + (((size_t)(b * 32 + qt) * 32 + kt) * 4096) +
                   (w * 64 + lane) * 16;
      *(bf16x8*)op = *(bf16x8*)&vals[0];
      *(bf16x8*)(op + 8) = *(bf16x8*)&vals[8];
      __syncthreads();  // sm reuse for next b
    }
  }
}

// ---------------- QKV projection: bf16 MFMA 128x128 tile ----------------
__global__ __launch_bounds__(256) void gemm_qkv_mfma(
    const __bf16* __restrict__ Xb, const __bf16* __restrict__ Wt,
    const float* __restrict__ bqkv, __bf16* __restrict__ Qb,
    __bf16* __restrict__ Kb, __bf16* __restrict__ Vtb) {
  __shared__ __align__(16) __bf16 As[128 * 32];
  __shared__ __align__(16) __bf16 Bs[128 * 32];
  const int tid = threadIdx.x;
  const int w = tid >> 6, lane = tid & 63;
  const int c = lane & 15, quad = lane >> 4;
  const int wm = w >> 1, wn = w & 1;
  const int rowBase = blockIdx.y * 128;
  const int colBase = blockIdx.x * 128;

  f32x4 acc[4][4] = {};

  const __bf16* gA0 =
      Xb + (size_t)(rowBase + w * 32 + (lane >> 2)) * 1024 + (lane & 3) * 8;
  const __bf16* gB0 =
      Wt + (size_t)(colBase + w * 32 + (lane >> 2)) * 1024 + (lane & 3) * 8;
  __bf16* lA0 = &As[(w * 32) * 32];
  __bf16* lB0 = &Bs[(w * 32) * 32];

  for (int k0 = 0; k0 < 1024; k0 += 32) {
    __syncthreads();
#pragma unroll
    for (int p = 0; p < 2; ++p) {
      GLD_LDS16(gA0 + (size_t)p * 16 * 1024 + k0, lA0 + p * 16 * 32);
      GLD_LDS16(gB0 + (size_t)p * 16 * 1024 + k0, lB0 + p * 16 * 32);
    }
    __syncthreads();

    bf16x8 af[4], bfr[4];
#pragma unroll
    for (int mt = 0; mt < 4; ++mt)
      af[mt] = *(const bf16x8*)&As[(wm * 64 + mt * 16 + c) * 32 + quad * 8];
#pragma unroll
    for (int nt = 0; nt < 4; ++nt)
      bfr[nt] = *(const bf16x8*)&Bs[(wn * 64 + nt * 16 + c) * 32 + quad * 8];
#pragma unroll
    for (int mt = 0; mt < 4; ++mt)
#pragma unroll
      for (int nt = 0; nt < 4; ++nt)
        acc[mt][nt] = __builtin_amdgcn_mfma_f32_16x16x32_bf16(
            af[mt], bfr[nt], acc[mt][nt], 0, 0, 0);
  }

#pragma unroll
  for (int mt = 0; mt < 4; ++mt) {
    int row0 = rowBase + wm * 64 + mt * 16 + quad * 4;
#pragma unroll
    for (int nt = 0; nt < 4; ++nt) {
      int col = colBase + wn * 64 + nt * 16 + c;
      float bias = bqkv[col];
      int three = col >> 10;
      int h = (col & 1023) >> 6;
      int d = col & 63;
#pragma unroll
      for (int r = 0; r < 4; ++r) {
        int rr = row0 + r;
        int bb = rr >> 11, s = rr & 2047;
        float val = acc[mt][nt][r] + bias;
        size_t ho = (size_t)(bb * NH + h);
        if (three == 0)
          Qb[(ho * S_LEN + s) * HD + d] = (__bf16)val;
        else if (three == 1)
          Kb[(ho * S_LEN + s) * HD + d] = (__bf16)val;
        else
          Vtb[(ho * HD + d) * S_LEN + s] = (__bf16)val;
      }
    }
  }
}

// ------- MFMA flash attention: S^T dataflow, QBLK=128, 2 subtiles/barrier
// S^T = K*Q^T via mfma(A=kf, B=qa): lane holds S^T[kcol][qrow=c]; that IS
// the B-operand layout of mfma_f32_16x16x16_bf16, so PV runs from registers.
// Each barrier region processes TWO 64-key subtiles (KVBLK=128 effective):
// per-iteration sync overhead (vmcnt drain + convoy) amortized over 2x
// compute; DMAs for the next PAIR issued at iter top get ~2x latency cover.
// Registers are reused sequentially across subtiles (kf/vf/sv/pb per-sub).
__global__ __launch_bounds__(256) void attn_mfma(
    const __bf16* __restrict__ Qb, const __bf16* __restrict__ Kb,
    const __bf16* __restrict__ Vtb, const __bf16* __restrict__ MB,
    __bf16* __restrict__ AOb) {
  const int qt = blockIdx.x, h = blockIdx.y, b = blockIdx.z;
  const int tid = threadIdx.x;
  const int w = tid >> 6;
  const int lane = tid & 63;
  const int c = lane & 15;
  const int quad = lane >> 4;

  __shared__ __align__(16) __bf16 Ks[2][2][64 * 64];  // [dbuf][subtile]
  __shared__ __align__(16) __bf16 Vs[2][2][64 * 64];  // [feat][key], swizzled
#if !HAVE_MFMA_16x16x16_BF16
  __shared__ __align__(16) __bf16 P2[4][16 * 72];
#endif

  const size_t headoff = (size_t)(b * NH + h) * S_LEN * HD;
  const __bf16* Qg = Qb + headoff + (size_t)(qt * 128) * HD;
  const __bf16* Kg = Kb + headoff;
  const __bf16* Vg = Vtb + headoff;  // [hd][S]
  const __bf16* MBq0 =
      MB + ((size_t)(b * 32 + qt * 2 + 0) * 32) * 4096 + (w * 64 + lane) * 16;
  const __bf16* MBq1 =
      MB + ((size_t)(b * 32 + qt * 2 + 1) * 32) * 4096 + (w * 64 + lane) * 16;

  // staging geometry (chunk ch = p*256+tid -> row f, col-chunk j, swizzled)
  const int f0 = tid >> 3, f1 = f0 + 32;
  const int j = tid & 7;
  const int sj0 = j ^ (f0 & 7);
  const int sj1 = j ^ (f1 & 7);
  const int lds0 = tid * 8;
  const int lds1 = (256 + tid) * 8;

  // Q fragments: lane holds Q[qrow=g*64+w*16+c][d=quad*8+j] (loop-invariant)
  bf16x8 qa[2][2];
#pragma unroll
  for (int g = 0; g < 2; ++g) {
    qa[g][0] = *(const bf16x8*)(Qg + (g * 64 + w * 16 + c) * HD + quad * 8);
    qa[g][1] =
        *(const bf16x8*)(Qg + (g * 64 + w * 16 + c) * HD + quad * 8 + 32);
  }

  // swizzled b128 read offsets (row&7 == c&7)
  const int rs0 = (quad ^ (c & 7)) * 8;
  const int rs1 = ((quad + 4) ^ (c & 7)) * 8;

  f32x4 Oa[2][4] = {};  // O^T[d=ft*16+quad*4+r][qrow=c] per group
  f32x4 psum[2] = {};   // packed row-partial sums of p per group

  const float c1 = 0.125f * LOG2E;  // 1/sqrt(hd) * log2(e)

  // one-subtile compute: QK -> softmax (with rmb) -> PV, accumulate Oa/psum
  auto subtile = [&](const __bf16* KsS, const __bf16* VsS,
                     bf16x8(&rmb)[2][2]) {
    bf16x8 kf0[4], kf1[4];
#pragma unroll
    for (int ct = 0; ct < 4; ++ct) {
      kf0[ct] = *(const bf16x8*)&KsS[(ct * 16 + c) * 64 + rs0];
      kf1[ct] = *(const bf16x8*)&KsS[(ct * 16 + c) * 64 + rs1];
    }
    f32x4 sv[2][4];
    __builtin_amdgcn_s_setprio(1);
#pragma unroll
    for (int g = 0; g < 2; ++g)
#pragma unroll
      for (int ct = 0; ct < 4; ++ct) {
        f32x4 a = {};
        a = __builtin_amdgcn_mfma_f32_16x16x32_bf16(kf0[ct], qa[g][0], a, 0,
                                                    0, 0);
        a = __builtin_amdgcn_mfma_f32_16x16x32_bf16(kf1[ct], qa[g][1], a, 0,
                                                    0, 0);
        sv[g][ct] = a;
      }
    __builtin_amdgcn_s_setprio(0);

#if HAVE_MFMA_16x16x16_BF16
    s16x4 vf[4][4];
#pragma unroll
    for (int ft = 0; ft < 4; ++ft) {
      const int fr = ft * 16 + c;
#pragma unroll
      for (int ct = 0; ct < 4; ++ct) {
        const int chunk = ((ct * 2 + (quad >> 1)) ^ (fr & 7)) * 8 +
                          (quad & 1) * 4;
        vf[ft][ct] = *(const s16x4*)&VsS[fr * 64 + chunk];
      }
    }
#endif

    s16x4 pb[2][4];
#pragma unroll
    for (int g = 0; g < 2; ++g)
#pragma unroll
      for (int ct = 0; ct < 4; ++ct) {
        f32x4 pv;
#pragma unroll
        for (int r = 0; r < 4; ++r) {
          float mb = (ct < 2) ? (float)rmb[g][0][ct * 4 + r]
                              : (float)rmb[g][1][(ct - 2) * 4 + r];
          pv[r] = EXP2F(sv[g][ct][r] * c1 + mb);
        }
        psum[g] += pv;
        __bf16 t4[4];
#pragma unroll
        for (int r = 0; r < 4; ++r) t4[r] = (__bf16)pv[r];
        pb[g][ct] = *(s16x4*)t4;
      }

#if HAVE_MFMA_16x16x16_BF16
    __builtin_amdgcn_s_setprio(1);
#pragma unroll
    for (int g = 0; g < 2; ++g)
#pragma unroll
      for (int ft = 0; ft < 4; ++ft)
#pragma unroll
        for (int ct = 0; ct < 4; ++ct)
          Oa[g][ft] = __builtin_amdgcn_mfma_f32_16x16x16bf16_1k(
              vf[ft][ct], pb[g][ct], Oa[g][ft], 0, 0, 0);
    __builtin_amdgcn_s_setprio(0);
#else
#pragma unroll
    for (int g = 0; g < 2; ++g) {
#pragma unroll
      for (int ct = 0; ct < 4; ++ct)
        *(bf16x4*)&P2[w][c * 72 + ct * 16 + quad * 4] = *(bf16x4*)&pb[g][ct];
      bf16x8 pf0 = *(const bf16x8*)&P2[w][c * 72 + quad * 8];
      bf16x8 pf1 = *(const bf16x8*)&P2[w][c * 72 + 32 + quad * 8];
#pragma unroll
      for (int ft = 0; ft < 4; ++ft) {
        const int fr = ft * 16 + c;
        bf16x8 vf0 = *(const bf16x8*)&VsS[fr * 64 + rs0];
        bf16x8 vf1 = *(const bf16x8*)&VsS[fr * 64 + rs1];
        Oa[g][ft] = __builtin_amdgcn_mfma_f32_16x16x32_bf16(vf0, pf0,
                                                            Oa[g][ft], 0, 0, 0);
        Oa[g][ft] = __builtin_amdgcn_mfma_f32_16x16x32_bf16(vf1, pf1,
                                                            Oa[g][ft], 0, 0, 0);
      }
    }
#endif
  };

  // preamble: DMA tile pair (0,1) into dbuf 0
  GLD_LDS16(Kg + (size_t)f0 * HD + sj0 * 8, &Ks[0][0][lds0]);
  GLD_LDS16(Kg + (size_t)f1 * HD + sj1 * 8, &Ks[0][0][lds1]);
  GLD_LDS16(Kg + (size_t)(64 + f0) * HD + sj0 * 8, &Ks[0][1][lds0]);
  GLD_LDS16(Kg + (size_t)(64 + f1) * HD + sj1 * 8, &Ks[0][1][lds1]);
  GLD_LDS16(Vg + (size_t)f0 * S_LEN + sj0 * 8, &Vs[0][0][lds0]);
  GLD_LDS16(Vg + (size_t)f1 * S_LEN + sj1 * 8, &Vs[0][0][lds1]);
  GLD_LDS16(Vg + (size_t)f0 * S_LEN + 64 + sj0 * 8, &Vs[0][1][lds0]);
  GLD_LDS16(Vg + (size_t)f1 * S_LEN + 64 + sj1 * 8, &Vs[0][1][lds1]);

  // strength-reduced DMA source pointers (tile pair (2,3))
  const __bf16* kgp0 = Kg + (size_t)(128 + f0) * HD + sj0 * 8;
  const __bf16* kgp1 = Kg + (size_t)(128 + f1) * HD + sj1 * 8;
  const __bf16* vgp0 = Vg + (size_t)f0 * S_LEN + 128 + sj0 * 8;
  const __bf16* vgp1 = Vg + (size_t)f1 * S_LEN + 128 + sj1 * 8;

  // MB fragment prefetch: subtile A = tile 0, subtile B = tile 1
  bf16x8 rMBA[2][2], rMBB[2][2];
  rMBA[0][0] = *(const bf16x8*)MBq0;
  rMBA[0][1] = *(const bf16x8*)(MBq0 + 8);
  rMBA[1][0] = *(const bf16x8*)MBq1;
  rMBA[1][1] = *(const bf16x8*)(MBq1 + 8);
  rMBB[0][0] = *(const bf16x8*)(MBq0 + 4096);
  rMBB[0][1] = *(const bf16x8*)(MBq0 + 4096 + 8);
  rMBB[1][0] = *(const bf16x8*)(MBq1 + 4096);
  rMBB[1][1] = *(const bf16x8*)(MBq1 + 4096 + 8);

  __syncthreads();

#pragma unroll 2
  for (int t = 0; t < 16; ++t) {
    const int cur = t & 1, nxt = cur ^ 1;
    // async DMA of the next tile pair into the inactive dbuf
    if (t < 15) {
      GLD_LDS16(kgp0, &Ks[nxt][0][lds0]);
      GLD_LDS16(kgp1, &Ks[nxt][0][lds1]);
      GLD_LDS16(kgp0 + 64 * HD, &Ks[nxt][1][lds0]);
      GLD_LDS16(kgp1 + 64 * HD, &Ks[nxt][1][lds1]);
      GLD_LDS16(vgp0, &Vs[nxt][0][lds0]);
      GLD_LDS16(vgp1, &Vs[nxt][0][lds1]);
      GLD_LDS16(vgp0 + 64, &Vs[nxt][1][lds0]);
      GLD_LDS16(vgp1 + 64, &Vs[nxt][1][lds1]);
    }
    kgp0 += 128 * HD;
    kgp1 += 128 * HD;
    vgp0 += 128;
    vgp1 += 128;

    // ---- subtile A (tile 2t) ----
    subtile(&Ks[cur][0][0], &Vs[cur][0][0], rMBA);

    // next iteration's MB fragments (tiles 2t+2, 2t+3); issued between
    // subtiles so HBM/L2 latency hides under subtile-B compute. Over-read
    // on the final iteration lands in the following MB tiles / Wt2 region
    // (allocated, read-only -- safe).
    bf16x8 nMBA[2][2], nMBB[2][2];
    {
      const __bf16* m0 = MBq0 + (size_t)(2 * t + 2) * 4096;
      const __bf16* m1 = MBq1 + (size_t)(2 * t + 2) * 4096;
      nMBA[0][0] = *(const bf16x8*)m0;
      nMBA[0][1] = *(const bf16x8*)(m0 + 8);
      nMBA[1][0] = *(const bf16x8*)m1;
      nMBA[1][1] = *(const bf16x8*)(m1 + 8);
      nMBB[0][0] = *(const bf16x8*)(m0 + 4096);
      nMBB[0][1] = *(const bf16x8*)(m0 + 4096 + 8);
      nMBB[1][0] = *(const bf16x8*)(m1 + 4096);
      nMBB[1][1] = *(const bf16x8*)(m1 + 4096 + 8);
    }

    // ---- subtile B (tile 2t+1) ----
    subtile(&Ks[cur][1][0], &Vs[cur][1][0], rMBB);

#pragma unroll
    for (int g = 0; g < 2; ++g) {
      rMBA[g][0] = nMBA[g][0];
      rMBA[g][1] = nMBA[g][1];
      rMBB[g][0] = nMBB[g][0];
      rMBB[g][1] = nMBB[g][1];
    }

    // one barrier per PAIR: LDS[cur] reads done; implicit vmcnt(0) completes
    // the next pair's DMAs (issued before ~2x compute).
    __syncthreads();
  }

  // full row sum + normalize + store, per group
#pragma unroll
  for (int g = 0; g < 2; ++g) {
    float lsum = psum[g][0] + psum[g][1] + psum[g][2] + psum[g][3];
    lsum += __shfl_xor(lsum, 16);
    lsum += __shfl_xor(lsum, 32);
    const float invl = 1.0f / lsum;
    __bf16* orow = AOb +
                   (size_t)(b * S_LEN + qt * 128 + g * 64 + w * 16 + c) *
                       DMODEL +
                   h * HD;
#pragma unroll
    for (int ft = 0; ft < 4; ++ft) {
      __bf16 t4[4];
#pragma unroll
      for (int r = 0; r < 4; ++r) t4[r] = (__bf16)(Oa[g][ft][r] * invl);
      *(bf16x4*)(orow + ft * 16 + quad * 4) = *(bf16x4*)t4;
    }
  }
}

// ---------------- Output projection: bf16 MFMA 128x64 tile ----------------
__global__ __launch_bounds__(256) void gemm_out_mfma(
    const __bf16* __restrict__ AOb, const __bf16* __restrict__ Wt2,
    const float* __restrict__ bout, float* __restrict__ Out) {
  __shared__ __align__(16) __bf16 As[128 * 32];
  __shared__ __align__(16) __bf16 Bs[64 * 32];
  const int tid = threadIdx.x;
  const int w = tid >> 6, lane = tid & 63;
  const int c = lane & 15, quad = lane >> 4;
  const int rowBase = blockIdx.y * 128;
  const int colBase = blockIdx.x * 64;

  f32x4 acc[2][4] = {};

  const __bf16* gA0 =
      AOb + (size_t)(rowBase + w * 32 + (lane >> 2)) * 1024 + (lane & 3) * 8;
  const __bf16* gB0 =
      Wt2 + (size_t)(colBase + w * 16 + (lane >> 2)) * 1024 + (lane & 3) * 8;
  __bf16* lA0 = &As[(w * 32) * 32];
  __bf16* lB0 = &Bs[(w * 16) * 32];

  for (int k0 = 0; k0 < 1024; k0 += 32) {
    __syncthreads();
#pragma unroll
    for (int p = 0; p < 2; ++p)
      GLD_LDS16(gA0 + (size_t)p * 16 * 1024 + k0, lA0 + p * 16 * 32);
    GLD_LDS16(gB0 + k0, lB0);
    __syncthreads();

    bf16x8 af[2], bfr[4];
#pragma unroll
    for (int mt = 0; mt < 2; ++mt)
      af[mt] = *(const bf16x8*)&As[(w * 32 + mt * 16 + c) * 32 + quad * 8];
#pragma unroll
    for (int nt = 0; nt < 4; ++nt)
      bfr[nt] = *(const bf16x8*)&Bs[(nt * 16 + c) * 32 + quad * 8];
#pragma unroll
    for (int mt = 0; mt < 2; ++mt)
#pragma unroll
      for (int nt = 0; nt < 4; ++nt)
        acc[mt][nt] = __builtin_amdgcn_mfma_f32_16x16x32_bf16(
            af[mt], bfr[nt], acc[mt][nt], 0, 0, 0);
  }

#pragma unroll
  for (int mt = 0; mt < 2; ++mt) {
    int row0 = rowBase + w * 32 + mt * 16 + quad * 4;
#pragma unroll
    for (int nt = 0; nt < 4; ++nt) {
      int col = colBase + nt * 16 + c;
      float bias = bout[col];
#pragma unroll
      for (int r = 0; r < 4; ++r)
        Out[(size_t)(row0 + r) * 1024 + col] = acc[mt][nt][r] + bias;
    }
  }
}

extern "C" void kernel_launch(void* const* d_in, const int* in_sizes, int n_in,
                              void* d_out, int out_size, void* d_ws,
                              size_t ws_size, hipStream_t stream) {
  const float* x = (const float*)d_in[0];
  const float* attn_mask = (const float*)d_in[1];
  const float* attn_bias = (const float*)d_in[2];
  const float* Wqkv = (const float*)d_in[3];
  const float* bqkv = (const float*)d_in[4];
  const float* Wout = (const float*)d_in[5];
  const float* bout = (const float*)d_in[6];
  float* out = (float*)d_out;

  __bf16* base = (__bf16*)d_ws;
  __bf16* Xb = base;                  // [0, 4M)
  __bf16* AOb = base;                 // aliases Xb (disjoint lifetime)
  __bf16* Wt = base + 4194304;        // [4M, 7M)
  __bf16* Qb = base + 8388608;        // [8M, 12M)
  __bf16* Kb = base + 12582912;       // [12M, 16M)
  __bf16* Vtb = base + 16777216;      // [16M, 20M)
  __bf16* MB = base + 20971520;       // [20M, 28M)
  __bf16* Wt2 = base + 29360128;      // [28M, 29M)

  preprocess<<<6144, 256, 0, stream>>>(x, attn_mask, attn_bias, Wqkv, Wout,
                                       Xb, Wt, Wt2, MB);
  gemm_qkv_mfma<<<dim3(24, 32), 256, 0, stream>>>(Xb, Wt, bqkv, Qb, Kb, Vtb);
  attn_mfma<<<dim3(16, NH, 2), 256, 0, stream>>>(Qb, Kb, Vtb, MB, AOb);
  gemm_out_mfma<<<dim3(16, 32), 256, 0, stream>>>(AOb, Wt2, bout, out);
}

// Round 6
// 263.239 us; speedup vs baseline: 1.0578x; 1.0288x over previous
//
#include <hip/hip_runtime.h>
#include <hip/hip_bf16.h>

// Problem: B=2, S=2048, D=1024, H=16, hd=64
// ws layout (58 MiB, bf16-element offsets from d_ws):
//   Xb  [0, 4M)        8 MiB  (x bf16)             -- dead after gemm_qkv
//   PO0 [0, 4M)        8 MiB  (attn partial half0) -- aliases Xb
//   Wt  [4M, 7M)       6 MiB  (Wqkv^T bf16)        -- dead after gemm_qkv
//   PO1 [4M, 8M)       8 MiB  (attn partial half1) -- aliases Wt+gap
//   Qb  [8M, 12M)      8 MiB
//   Kb  [12M, 16M)     8 MiB
//   Vtb [16M, 20M)     8 MiB  (V^T [B,H,hd,S])     -- dead after attn
//   AOb [16M, 20M)     8 MiB  (combined attn out)  -- aliases Vtb
//   MB  [20M, 28M)    16 MiB  (mask+bias, S^T-fragment order, *log2e)
//   Wt2 [28M+..]       2 MiB  (Wout^T bf16)
//   L sums (f32, 512KB) at the FRONT of d_out (overwritten by gemm_out).
//
// R13: R2-R5 showed attn latency-bound with capacity pinned at 2 wg/CU
// (registers ~190/wave AND R5's 64KB LDS). R4's KV-split failed ONLY
// because capacity couldn't rise. This round: raise capacity to 3 wg/CU
// (reg diet: per-group sv, JIT rMB reuse -> peak ~148; launch_bounds(256,3);
// LDS back to 32KB single-tile dbuf) THEN re-apply KV-split x2 (grid 1024)
// to fill it. 16 barriers/wg kept. Also: gemm_qkv V-epilogue via per-wave
// LDS transpose (was 8B-per-4KB scatter, ~8x write amplification).

#define S_LEN 2048
#define DMODEL 1024
#define NH 16
#define HD 64

typedef __bf16 bf16x8 __attribute__((ext_vector_type(8)));
typedef __bf16 bf16x4 __attribute__((ext_vector_type(4)));
typedef __bf16 bf16x2v __attribute__((ext_vector_type(2)));
typedef float f32x4 __attribute__((ext_vector_type(4)));
typedef short s16x4 __attribute__((ext_vector_type(4)));

#define GLD_LDS16(g, l)                                              \
  __builtin_amdgcn_global_load_lds(                                  \
      (const __attribute__((address_space(1))) unsigned int*)(g),    \
      (__attribute__((address_space(3))) unsigned int*)(l), 16, 0, 0)

#if __has_builtin(__builtin_amdgcn_mfma_f32_16x16x16bf16_1k)
#define HAVE_MFMA_16x16x16_BF16 1
#else
#define HAVE_MFMA_16x16x16_BF16 0
#endif

#if __has_builtin(__builtin_amdgcn_exp2f)
#define EXP2F(x) __builtin_amdgcn_exp2f(x)
#else
static __device__ __forceinline__ float EXP2F(float x) {
  float r;
  asm volatile("v_exp_f32 %0, %1" : "=v"(r) : "v"(x));
  return r;
}
#endif

#define LOG2E 1.44269504f

// ---------- fused preprocess: cvt_x | cvt_wt(Wqkv) | cvt_wt(Wout) | mb_fuse
// blockIdx.x ranges: [0,4096) cvt_x, [4096,4864) Wqkv^T, [4864,5120) Wout^T,
// [5120,6144) mb_fuse (BOTH b per block; mask read once).
__global__ __launch_bounds__(256) void preprocess(
    const float* __restrict__ x, const float* __restrict__ mask,
    const float* __restrict__ bias, const float* __restrict__ Wqkv,
    const float* __restrict__ Wout, __bf16* __restrict__ Xb,
    __bf16* __restrict__ Wt, __bf16* __restrict__ Wt2,
    __bf16* __restrict__ MB) {
  __shared__ __align__(16) char smem[64 * 65 * 4];
  const int bid = blockIdx.x;
  const int tid = threadIdx.x;

  if (bid < 4096) {
    // ---- cvt_x: fp32 -> bf16 ----
    int i = bid * 256 + tid;
    float4 v = ((const float4*)x)[i];
    bf16x4 o = {(__bf16)v.x, (__bf16)v.y, (__bf16)v.z, (__bf16)v.w};
    *(bf16x4*)&Xb[(size_t)i * 4] = o;
  } else if (bid < 5120) {
    // ---- cvt_wt: W[1024,ncols] -> Wt[ncols,1024] bf16 transpose ----
    const float* W;
    __bf16* Wo;
    int ncols, n0, k0;
    if (bid < 4864) {
      int id = bid - 4096;
      W = Wqkv; Wo = Wt; ncols = 3072;
      n0 = (id % 48) * 64; k0 = (id / 48) * 64;
    } else {
      int id = bid - 4864;
      W = Wout; Wo = Wt2; ncols = 1024;
      n0 = (id & 15) * 64; k0 = (id >> 4) * 64;
    }
    float(*tile)[65] = (float(*)[65])smem;
    {
      int c = tid & 63, r4 = tid >> 6;
#pragma unroll
      for (int p = 0; p < 16; ++p) {
        int r = r4 + p * 4;
        tile[r][c] = W[(size_t)(k0 + r) * ncols + n0 + c];
      }
    }
    __syncthreads();
    {
      int cc = (tid & 31) * 2, r8 = tid >> 5;
#pragma unroll
      for (int p = 0; p < 8; ++p) {
        int rr = r8 + p * 8;
        bf16x2v o = {(__bf16)tile[cc][rr], (__bf16)tile[cc + 1][rr]};
        *(bf16x2v*)&Wo[(size_t)(n0 + rr) * 1024 + k0 + cc] = o;
      }
    }
  } else {
    // ---- mb_fuse: (mask+bias)*log2e, BOTH b, mask loaded once ----
    int id = bid - 5120;  // [0,1024)
    const int kt = id & 31, qt = id >> 5;
    __bf16(*sm)[68] = (__bf16(*)[68])smem;
    const int r0 = tid >> 4;        // 0..15
    const int cc = (tid & 15) * 4;  // 0,4,..,60
    const float* mrow = mask + (size_t)(qt * 64) * S_LEN + kt * 64;
    float4 mld[4];
#pragma unroll
    for (int p = 0; p < 4; ++p)
      mld[p] = *(const float4*)(mrow + (size_t)(r0 + p * 16) * S_LEN + cc);
    const int w = tid >> 6, lane = tid & 63;
    const int quad = lane >> 4, cl = lane & 15;
    for (int b = 0; b < 2; ++b) {
      const float* brow =
          bias + ((size_t)b * S_LEN + qt * 64) * S_LEN + kt * 64;
#pragma unroll
      for (int p = 0; p < 4; ++p) {
        int r = r0 + p * 16;
        float4 a = *(const float4*)(brow + (size_t)r * S_LEN + cc);
        sm[r][cc + 0] = (__bf16)((mld[p].x + a.x) * LOG2E);
        sm[r][cc + 1] = (__bf16)((mld[p].y + a.y) * LOG2E);
        sm[r][cc + 2] = (__bf16)((mld[p].z + a.z) * LOG2E);
        sm[r][cc + 3] = (__bf16)((mld[p].w + a.w) * LOG2E);
      }
      __syncthreads();
      __bf16 vals[16];
#pragma unroll
      for (int ct = 0; ct < 4; ++ct) {
        bf16x4 v = *(const bf16x4*)&sm[w * 16 + cl][ct * 16 + quad * 4];
        *(bf16x4*)&vals[ct * 4] = v;
      }
      __bf16* op = MB + (((size_t)(b * 32 + qt) * 32 + kt) * 4096) +
                   (w * 64 + lane) * 16;
      *(bf16x8*)op = *(bf16x8*)&vals[0];
      *(bf16x8*)(op + 8) = *(bf16x8*)&vals[8];
      __syncthreads();  // sm reuse for next b
    }
  }
}

// ---------------- QKV projection: bf16 MFMA 128x128 tile ----------------
// R13: V-wgs (colBase>=2048) store via per-wave LDS transpose -> coalesced
// 128B stores along s (was 8B-per-4KB scatter, ~8x write amplification).
__global__ __launch_bounds__(256) void gemm_qkv_mfma(
    const __bf16* __restrict__ Xb, const __bf16* __restrict__ Wt,
    const float* __restrict__ bqkv, __bf16* __restrict__ Qb,
    __bf16* __restrict__ Kb, __bf16* __restrict__ Vtb) {
  // union region: As(8KB) + Bs(8KB) during k-loop; 4x 64x72 bf16 transpose
  // tiles (36,864B) during the V epilogue (after a barrier).
  __shared__ __align__(16) __bf16 shm[4 * 64 * 72];
  __bf16* As = shm;         // 128*32 elements
  __bf16* Bs = shm + 4096;  // 128*32 elements
  const int tid = threadIdx.x;
  const int w = tid >> 6, lane = tid & 63;
  const int c = lane & 15, quad = lane >> 4;
  const int wm = w >> 1, wn = w & 1;
  const int rowBase = blockIdx.y * 128;
  const int colBase = blockIdx.x * 128;

  f32x4 acc[4][4] = {};

  const __bf16* gA0 =
      Xb + (size_t)(rowBase + w * 32 + (lane >> 2)) * 1024 + (lane & 3) * 8;
  const __bf16* gB0 =
      Wt + (size_t)(colBase + w * 32 + (lane >> 2)) * 1024 + (lane & 3) * 8;
  __bf16* lA0 = &As[(w * 32) * 32];
  __bf16* lB0 = &Bs[(w * 32) * 32];

  for (int k0 = 0; k0 < 1024; k0 += 32) {
    __syncthreads();
#pragma unroll
    for (int p = 0; p < 2; ++p) {
      GLD_LDS16(gA0 + (size_t)p * 16 * 1024 + k0, lA0 + p * 16 * 32);
      GLD_LDS16(gB0 + (size_t)p * 16 * 1024 + k0, lB0 + p * 16 * 32);
    }
    __syncthreads();

    bf16x8 af[4], bfr[4];
#pragma unroll
    for (int mt = 0; mt < 4; ++mt)
      af[mt] = *(const bf16x8*)&As[(wm * 64 + mt * 16 + c) * 32 + quad * 8];
#pragma unroll
    for (int nt = 0; nt < 4; ++nt)
      bfr[nt] = *(const bf16x8*)&Bs[(wn * 64 + nt * 16 + c) * 32 + quad * 8];
#pragma unroll
    for (int mt = 0; mt < 4; ++mt)
#pragma unroll
      for (int nt = 0; nt < 4; ++nt)
        acc[mt][nt] = __builtin_amdgcn_mfma_f32_16x16x32_bf16(
            af[mt], bfr[nt], acc[mt][nt], 0, 0, 0);
  }

  if (colBase < 2048) {
    // ---- Q/K epilogue (unchanged scatter; 32B-contiguous per quad) ----
#pragma unroll
    for (int mt = 0; mt < 4; ++mt) {
      int row0 = rowBase + wm * 64 + mt * 16 + quad * 4;
#pragma unroll
      for (int nt = 0; nt < 4; ++nt) {
        int col = colBase + wn * 64 + nt * 16 + c;
        float bias = bqkv[col];
        int three = col >> 10;  // 0 or 1
        int h = (col & 1023) >> 6;
        int d = col & 63;
#pragma unroll
        for (int r = 0; r < 4; ++r) {
          int rr = row0 + r;
          int bb = rr >> 11, s = rr & 2047;
          float val = acc[mt][nt][r] + bias;
          size_t ho = (size_t)(bb * NH + h);
          if (three == 0)
            Qb[(ho * S_LEN + s) * HD + d] = (__bf16)val;
          else
            Kb[(ho * S_LEN + s) * HD + d] = (__bf16)val;
        }
      }
    }
  } else {
    // ---- V epilogue: per-wave LDS transpose, coalesced V^T stores ----
    __syncthreads();  // As/Bs dead (all waves past last ds_read)
    __bf16* Tt = shm + w * (64 * 72);  // [d_local][s_local], pad 72
    const int cols0 = colBase + wn * 64;
    const int rows0 = rowBase + wm * 64;
    const int hq = (cols0 & 1023) >> 6;
    const int bb = rows0 >> 11;
    const int sBase = rows0 & 2047;
#pragma unroll
    for (int nt = 0; nt < 4; ++nt) {
      float bias = bqkv[cols0 + nt * 16 + c];
#pragma unroll
      for (int mt = 0; mt < 4; ++mt) {
        __bf16 t4[4];
#pragma unroll
        for (int r = 0; r < 4; ++r) t4[r] = (__bf16)(acc[mt][nt][r] + bias);
        *(bf16x4*)&Tt[(nt * 16 + c) * 72 + mt * 16 + quad * 4] =
            *(bf16x4*)t4;
      }
    }
    __syncthreads();
    const size_t vbase = ((size_t)(bb * NH + hq) * HD) * S_LEN;
    const int s0 = (lane & 7) * 8;
    const int dl0 = lane >> 3;  // 0..7
#pragma unroll
    for (int dt = 0; dt < 8; ++dt) {
      int dl = dt * 8 + dl0;
      bf16x8 v = *(const bf16x8*)&Tt[dl * 72 + s0];
      *(bf16x8*)&Vtb[vbase + (size_t)dl * S_LEN + sBase + s0] = v;
    }
  }
}

// ------- MFMA flash attention: S^T dataflow, QBLK=128, KV-SPLIT x2 -------
// blockIdx.z = b*2 + half; each wg covers k-tiles [half*16, half*16+16).
// Capacity play: launch_bounds(256,3) + reg diet (per-group sv, JIT rMB
// reload into the same regs) + 32KB LDS -> 3 wg/CU; grid 1024 fills it.
// Writes UNNORMALIZED partial O (bf16) + row-sums (f32); no max-shift so
// combine is a plain sum: O = (PO0+PO1)/(L0+L1).
__global__ __launch_bounds__(256, 3) void attn_mfma(
    const __bf16* __restrict__ Qb, const __bf16* __restrict__ Kb,
    const __bf16* __restrict__ Vtb, const __bf16* __restrict__ MB,
    __bf16* __restrict__ PO, float* __restrict__ L) {
  const int qt = blockIdx.x, h = blockIdx.y;
  const int b = blockIdx.z >> 1, half = blockIdx.z & 1;
  const int tid = threadIdx.x;
  const int w = tid >> 6;
  const int lane = tid & 63;
  const int c = lane & 15;
  const int quad = lane >> 4;

  __shared__ __align__(16) __bf16 Ks[2][64 * 64];
  __shared__ __align__(16) __bf16 Vs[2][64 * 64];  // [feat][key], swizzled
#if !HAVE_MFMA_16x16x16_BF16
  __shared__ __align__(16) __bf16 P2[4][16 * 72];
#endif

  const size_t headoff = (size_t)(b * NH + h) * S_LEN * HD;
  const int kv0 = half * 1024;  // key offset of this half's window
  const __bf16* Qg = Qb + headoff + (size_t)(qt * 128) * HD;
  const __bf16* Kg = Kb + headoff + (size_t)kv0 * HD;
  const __bf16* Vg = Vtb + headoff;  // [hd][S]
  // MB fragment pointers (tile = half*16 + lkt), two q-groups
  const __bf16* mbp0 = MB +
                       ((size_t)(b * 32 + qt * 2 + 0) * 32 + half * 16) * 4096 +
                       (w * 64 + lane) * 16;
  const __bf16* mbp1 = MB +
                       ((size_t)(b * 32 + qt * 2 + 1) * 32 + half * 16) * 4096 +
                       (w * 64 + lane) * 16;

  __bf16* POx = PO + (size_t)half * 4194304;
  float* Lx = L + half * 65536;

  // staging geometry (chunk ch = p*256+tid -> row f, col-chunk j, swizzled)
  const int f0 = tid >> 3, f1 = f0 + 32;
  const int j = tid & 7;
  const int sj0 = j ^ (f0 & 7);
  const int sj1 = j ^ (f1 & 7);
  const int lds0 = tid * 8;
  const int lds1 = (256 + tid) * 8;

  // Q fragments: lane holds Q[qrow=g*64+w*16+c][d=quad*8+j] (loop-invariant)
  bf16x8 qa[2][2];
#pragma unroll
  for (int g = 0; g < 2; ++g) {
    qa[g][0] = *(const bf16x8*)(Qg + (g * 64 + w * 16 + c) * HD + quad * 8);
    qa[g][1] =
        *(const bf16x8*)(Qg + (g * 64 + w * 16 + c) * HD + quad * 8 + 32);
  }

  // swizzled b128 read offsets (row&7 == c&7)
  const int rs0 = (quad ^ (c & 7)) * 8;
  const int rs1 = ((quad + 4) ^ (c & 7)) * 8;

  f32x4 Oa[2][4] = {};  // O^T[d=ft*16+quad*4+r][qrow=c] per group
  f32x4 psum[2] = {};   // packed row-partial sums of p per group

  // preamble: DMA local tile 0 into buffer 0
  GLD_LDS16(Kg + (size_t)f0 * HD + sj0 * 8, &Ks[0][lds0]);
  GLD_LDS16(Kg + (size_t)f1 * HD + sj1 * 8, &Ks[0][lds1]);
  GLD_LDS16(Vg + (size_t)f0 * S_LEN + kv0 + sj0 * 8, &Vs[0][lds0]);
  GLD_LDS16(Vg + (size_t)f1 * S_LEN + kv0 + sj1 * 8, &Vs[0][lds1]);

  // strength-reduced DMA source pointers (next-tile positions)
  const __bf16* kgp0 = Kg + (size_t)(64 + f0) * HD + sj0 * 8;
  const __bf16* kgp1 = Kg + (size_t)(64 + f1) * HD + sj1 * 8;
  const __bf16* vgp0 = Vg + (size_t)f0 * S_LEN + kv0 + 64 + sj0 * 8;
  const __bf16* vgp1 = Vg + (size_t)f1 * S_LEN + kv0 + 64 + sj1 * 8;

  // MB fragments for tile 0 (JIT scheme: rMB always holds CURRENT tile)
  bf16x8 rMB[2][2];
  rMB[0][0] = *(const bf16x8*)mbp0;
  rMB[0][1] = *(const bf16x8*)(mbp0 + 8);
  rMB[1][0] = *(const bf16x8*)mbp1;
  rMB[1][1] = *(const bf16x8*)(mbp1 + 8);
  mbp0 += 4096;
  mbp1 += 4096;

  __syncthreads();

  const float c1 = 0.125f * LOG2E;  // 1/sqrt(hd) * log2(e)

#pragma unroll 2
  for (int t = 0; t < 16; ++t) {
    const int cur = t & 1, nxt = cur ^ 1;
    // async DMA of next local tile into the inactive buffer
    if (t < 15) {
      GLD_LDS16(kgp0, &Ks[nxt][lds0]);
      GLD_LDS16(kgp1, &Ks[nxt][lds1]);
      GLD_LDS16(vgp0, &Vs[nxt][lds0]);
      GLD_LDS16(vgp1, &Vs[nxt][lds1]);
    }
    kgp0 += 64 * HD;
    kgp1 += 64 * HD;
    vgp0 += 64;
    vgp1 += 64;

    // ---- K fragment reads (shared by both q-groups) ----
    bf16x8 kf0[4], kf1[4];
#pragma unroll
    for (int ct = 0; ct < 4; ++ct) {
      kf0[ct] = *(const bf16x8*)&Ks[cur][(ct * 16 + c) * 64 + rs0];
      kf1[ct] = *(const bf16x8*)&Ks[cur][(ct * 16 + c) * 64 + rs1];
    }

    // ---- per group: QK (sv reused, 16 regs) -> softmax -> JIT MB reload
    s16x4 pb[2][4];
#pragma unroll
    for (int g = 0; g < 2; ++g) {
      f32x4 sv[4];
      __builtin_amdgcn_s_setprio(1);
#pragma unroll
      for (int ct = 0; ct < 4; ++ct) {
        f32x4 a = {};
        a = __builtin_amdgcn_mfma_f32_16x16x32_bf16(kf0[ct], qa[g][0], a, 0,
                                                    0, 0);
        a = __builtin_amdgcn_mfma_f32_16x16x32_bf16(kf1[ct], qa[g][1], a, 0,
                                                    0, 0);
        sv[ct] = a;
      }
      __builtin_amdgcn_s_setprio(0);
#pragma unroll
      for (int ct = 0; ct < 4; ++ct) {
        f32x4 pv;
#pragma unroll
        for (int r = 0; r < 4; ++r) {
          float mb = (ct < 2) ? (float)rMB[g][0][ct * 4 + r]
                              : (float)rMB[g][1][(ct - 2) * 4 + r];
          pv[r] = EXP2F(sv[ct][r] * c1 + mb);
        }
        psum[g] += pv;
        __bf16 t4[4];
#pragma unroll
        for (int r = 0; r < 4; ++r) t4[r] = (__bf16)pv[r];
        pb[g][ct] = *(s16x4*)t4;
      }
      // JIT reload of rMB[g] for the NEXT tile (covered until next iter).
      // Final-iter over-read lands in the adjacent MB tile / Wt2 region
      // (allocated, read-only -- safe).
      const __bf16* mp = g ? mbp1 : mbp0;
      rMB[g][0] = *(const bf16x8*)mp;
      rMB[g][1] = *(const bf16x8*)(mp + 8);
    }
    mbp0 += 4096;
    mbp1 += 4096;

#if HAVE_MFMA_16x16x16_BF16
    // ---- V fragment reads + PV: pure-register MFMA cluster ----
    s16x4 vf[4][4];
#pragma unroll
    for (int ft = 0; ft < 4; ++ft) {
      const int fr = ft * 16 + c;
#pragma unroll
      for (int ct = 0; ct < 4; ++ct) {
        const int chunk = ((ct * 2 + (quad >> 1)) ^ (fr & 7)) * 8 +
                          (quad & 1) * 4;
        vf[ft][ct] = *(const s16x4*)&Vs[cur][fr * 64 + chunk];
      }
    }
    __builtin_amdgcn_s_setprio(1);
#pragma unroll
    for (int g = 0; g < 2; ++g)
#pragma unroll
      for (int ft = 0; ft < 4; ++ft)
#pragma unroll
        for (int ct = 0; ct < 4; ++ct)
          Oa[g][ft] = __builtin_amdgcn_mfma_f32_16x16x16bf16_1k(
              vf[ft][ct], pb[g][ct], Oa[g][ft], 0, 0, 0);
    __builtin_amdgcn_s_setprio(0);
#else
    // ---- fallback: P^T via wave-private LDS ----
#pragma unroll
    for (int g = 0; g < 2; ++g) {
#pragma unroll
      for (int ct = 0; ct < 4; ++ct)
        *(bf16x4*)&P2[w][c * 72 + ct * 16 + quad * 4] = *(bf16x4*)&pb[g][ct];
      bf16x8 pf0 = *(const bf16x8*)&P2[w][c * 72 + quad * 8];
      bf16x8 pf1 = *(const bf16x8*)&P2[w][c * 72 + 32 + quad * 8];
#pragma unroll
      for (int ft = 0; ft < 4; ++ft) {
        const int fr = ft * 16 + c;
        bf16x8 vv0 = *(const bf16x8*)&Vs[cur][fr * 64 + rs0];
        bf16x8 vv1 = *(const bf16x8*)&Vs[cur][fr * 64 + rs1];
        Oa[g][ft] = __builtin_amdgcn_mfma_f32_16x16x32_bf16(vv0, pf0,
                                                            Oa[g][ft], 0, 0, 0);
        Oa[g][ft] = __builtin_amdgcn_mfma_f32_16x16x32_bf16(vv1, pf1,
                                                            Oa[g][ft], 0, 0, 0);
      }
    }
#endif

    // one barrier per tile: LDS[cur] reads done; implicit vmcnt(0) completes
    // the next-tile DMAs (issued before the full compute body).
    __syncthreads();
  }

  // row-sum reduce + store partial L and UNNORMALIZED partial O
#pragma unroll
  for (int g = 0; g < 2; ++g) {
    float lsum = psum[g][0] + psum[g][1] + psum[g][2] + psum[g][3];
    lsum += __shfl_xor(lsum, 16);
    lsum += __shfl_xor(lsum, 32);
    if (lane < 16)  // quad 0: one writer per q-row
      Lx[(size_t)(b * NH + h) * S_LEN + qt * 128 + g * 64 + w * 16 + c] = lsum;
    __bf16* orow = POx +
                   (size_t)(b * S_LEN + qt * 128 + g * 64 + w * 16 + c) *
                       DMODEL +
                   h * HD;
#pragma unroll
    for (int ft = 0; ft < 4; ++ft) {
      __bf16 t4[4];
#pragma unroll
      for (int r = 0; r < 4; ++r) t4[r] = (__bf16)Oa[g][ft][r];
      *(bf16x4*)(orow + ft * 16 + quad * 4) = *(bf16x4*)t4;
    }
  }
}

// -------- combine: AOb = (PO0 + PO1) / (L0 + L1), elementwise --------
__global__ __launch_bounds__(256) void combine(const __bf16* __restrict__ PO,
                                               const float* __restrict__ L,
                                               __bf16* __restrict__ AOb) {
  const int i = blockIdx.x * 256 + threadIdx.x;
  const size_t e = (size_t)i * 8;
  const int hidx = (int)(e >> 6) & 15;
  const int s = (int)(e >> 10) & 2047;
  const int b = (int)(e >> 21);
  const size_t li = ((size_t)(b * NH + hidx) << 11) + s;
  const float invl = 1.0f / (L[li] + L[65536 + li]);
  bf16x8 a = *(const bf16x8*)&PO[e];
  bf16x8 c = *(const bf16x8*)&PO[4194304 + e];
  __bf16 o[8];
#pragma unroll
  for (int k = 0; k < 8; ++k)
    o[k] = (__bf16)(((float)a[k] + (float)c[k]) * invl);
  *(bf16x8*)&AOb[e] = *(bf16x8*)o;
}

// ---------------- Output projection: bf16 MFMA 128x64 tile ----------------
__global__ __launch_bounds__(256) void gemm_out_mfma(
    const __bf16* __restrict__ AOb, const __bf16* __restrict__ Wt2,
    const float* __restrict__ bout, float* __restrict__ Out) {
  __shared__ __align__(16) __bf16 As[128 * 32];
  __shared__ __align__(16) __bf16 Bs[64 * 32];
  const int tid = threadIdx.x;
  const int w = tid >> 6, lane = tid & 63;
  const int c = lane & 15, quad = lane >> 4;
  const int rowBase = blockIdx.y * 128;
  const int colBase = blockIdx.x * 64;

  f32x4 acc[2][4] = {};

  const __bf16* gA0 =
      AOb + (size_t)(rowBase + w * 32 + (lane >> 2)) * 1024 + (lane & 3) * 8;
  const __bf16* gB0 =
      Wt2 + (size_t)(colBase + w * 16 + (lane >> 2)) * 1024 + (lane & 3) * 8;
  __bf16* lA0 = &As[(w * 32) * 32];
  __bf16* lB0 = &Bs[(w * 16) * 32];

  for (int k0 = 0; k0 < 1024; k0 += 32) {
    __syncthreads();
#pragma unroll
    for (int p = 0; p < 2; ++p)
      GLD_LDS16(gA0 + (size_t)p * 16 * 1024 + k0, lA0 + p * 16 * 32);
    GLD_LDS16(gB0 + k0, lB0);
    __syncthreads();

    bf16x8 af[2], bfr[4];
#pragma unroll
    for (int mt = 0; mt < 2; ++mt)
      af[mt] = *(const bf16x8*)&As[(w * 32 + mt * 16 + c) * 32 + quad * 8];
#pragma unroll
    for (int nt = 0; nt < 4; ++nt)
      bfr[nt] = *(const bf16x8*)&Bs[(nt * 16 + c) * 32 + quad * 8];
#pragma unroll
    for (int mt = 0; mt < 2; ++mt)
#pragma unroll
      for (int nt = 0; nt < 4; ++nt)
        acc[mt][nt] = __builtin_amdgcn_mfma_f32_16x16x32_bf16(
            af[mt], bfr[nt], acc[mt][nt], 0, 0, 0);
  }

#pragma unroll
  for (int mt = 0; mt < 2; ++mt) {
    int row0 = rowBase + w * 32 + mt * 16 + quad * 4;
#pragma unroll
    for (int nt = 0; nt < 4; ++nt) {
      int col = colBase + nt * 16 + c;
      float bias = bout[col];
#pragma unroll
      for (int r = 0; r < 4; ++r)
        Out[(size_t)(row0 + r) * 1024 + col] = acc[mt][nt][r] + bias;
    }
  }
}

extern "C" void kernel_launch(void* const* d_in, const int* in_sizes, int n_in,
                              void* d_out, int out_size, void* d_ws,
                              size_t ws_size, hipStream_t stream) {
  const float* x = (const float*)d_in[0];
  const float* attn_mask = (const float*)d_in[1];
  const float* attn_bias = (const float*)d_in[2];
  const float* Wqkv = (const float*)d_in[3];
  const float* bqkv = (const float*)d_in[4];
  const float* Wout = (const float*)d_in[5];
  const float* bout = (const float*)d_in[6];
  float* out = (float*)d_out;

  __bf16* base = (__bf16*)d_ws;
  __bf16* Xb = base;                  // [0, 4M)
  __bf16* PO = base;                  // PO0 [0,4M), PO1 [4M,8M)
  __bf16* Wt = base + 4194304;        // [4M, 7M)
  __bf16* Qb = base + 8388608;        // [8M, 12M)
  __bf16* Kb = base + 12582912;       // [12M, 16M)
  __bf16* Vtb = base + 16777216;      // [16M, 20M)
  __bf16* AOb = base + 16777216;      // aliases Vtb (disjoint lifetime)
  __bf16* MB = base + 20971520;       // [20M, 28M)
  __bf16* Wt2 = base + 29360128;      // [28M, 29M)
  float* Lf = (float*)d_out;          // 512 KB at front of out (temp)

  preprocess<<<6144, 256, 0, stream>>>(x, attn_mask, attn_bias, Wqkv, Wout,
                                       Xb, Wt, Wt2, MB);
  gemm_qkv_mfma<<<dim3(24, 32), 256, 0, stream>>>(Xb, Wt, bqkv, Qb, Kb, Vtb);
  attn_mfma<<<dim3(16, NH, 4), 256, 0, stream>>>(Qb, Kb, Vtb, MB, PO, Lf);
  combine<<<2048, 256, 0, stream>>>(PO, Lf, AOb);
  gemm_out_mfma<<<dim3(16, 32), 256, 0, stream>>>(AOb, Wt2, bout, out);
}

// Round 7
// 259.141 us; speedup vs baseline: 1.0745x; 1.0158x over previous
//
#include <hip/hip_runtime.h>
#include <hip/hip_bf16.h>

// Problem: B=2, S=2048, D=1024, H=16, hd=64
// ws layout (58 MiB, bf16-element offsets from d_ws):
//   Xb  [0, 4M)        8 MiB  (x bf16)             -- dead after gemm_qkv
//   AOb [0, 4M)        8 MiB  (attn out bf16)      -- aliases Xb
//   Wt  [4M, 7M)       6 MiB  (Wqkv^T bf16)
//   Qb  [8M, 12M)      8 MiB
//   Kb  [12M, 16M)     8 MiB
//   Vtb [16M, 20M)     8 MiB  (V^T [B,H,hd,S])
//   MB  [20M, 28M)    16 MiB  (mask+bias, S^T-fragment order, *log2e)
//   Wt2 [28M+..]       2 MiB  (Wout^T bf16)
//
// R14: R6 proved waves are CONVOYED: +35% occupancy -> 0% speedup, all
// pipes <50%. The __syncthreads implicit vmcnt(0) drains the mid-loop MB
// JIT loads (only ~400cy cover) every iteration, and lockstep wgs align
// their stalls. Fix (T4): counted s_waitcnt vmcnt(4) + raw s_barrier --
// wait only for the K/V DMAs (full-iteration cover), never the MB loads.
// Plus phase rotation ((qt+h)&1)*16 so co-resident wgs anti-align DMA
// bursts. KV-split + combine reverted (proven neutral, cost ~6us).

#define S_LEN 2048
#define DMODEL 1024
#define NH 16
#define HD 64

typedef __bf16 bf16x8 __attribute__((ext_vector_type(8)));
typedef __bf16 bf16x4 __attribute__((ext_vector_type(4)));
typedef __bf16 bf16x2v __attribute__((ext_vector_type(2)));
typedef float f32x4 __attribute__((ext_vector_type(4)));
typedef short s16x4 __attribute__((ext_vector_type(4)));

#define GLD_LDS16(g, l)                                              \
  __builtin_amdgcn_global_load_lds(                                  \
      (const __attribute__((address_space(1))) unsigned int*)(g),    \
      (__attribute__((address_space(3))) unsigned int*)(l), 16, 0, 0)

#if __has_builtin(__builtin_amdgcn_mfma_f32_16x16x16bf16_1k)
#define HAVE_MFMA_16x16x16_BF16 1
#else
#define HAVE_MFMA_16x16x16_BF16 0
#endif

#if __has_builtin(__builtin_amdgcn_exp2f)
#define EXP2F(x) __builtin_amdgcn_exp2f(x)
#else
static __device__ __forceinline__ float EXP2F(float x) {
  float r;
  asm volatile("v_exp_f32 %0, %1" : "=v"(r) : "v"(x));
  return r;
}
#endif

#define LOG2E 1.44269504f

// ---------- fused preprocess: cvt_x | cvt_wt(Wqkv) | cvt_wt(Wout) | mb_fuse
// blockIdx.x ranges: [0,4096) cvt_x, [4096,4864) Wqkv^T, [4864,5120) Wout^T,
// [5120,6144) mb_fuse (BOTH b per block; mask read once).
__global__ __launch_bounds__(256) void preprocess(
    const float* __restrict__ x, const float* __restrict__ mask,
    const float* __restrict__ bias, const float* __restrict__ Wqkv,
    const float* __restrict__ Wout, __bf16* __restrict__ Xb,
    __bf16* __restrict__ Wt, __bf16* __restrict__ Wt2,
    __bf16* __restrict__ MB) {
  __shared__ __align__(16) char smem[64 * 65 * 4];
  const int bid = blockIdx.x;
  const int tid = threadIdx.x;

  if (bid < 4096) {
    // ---- cvt_x: fp32 -> bf16 ----
    int i = bid * 256 + tid;
    float4 v = ((const float4*)x)[i];
    bf16x4 o = {(__bf16)v.x, (__bf16)v.y, (__bf16)v.z, (__bf16)v.w};
    *(bf16x4*)&Xb[(size_t)i * 4] = o;
  } else if (bid < 5120) {
    // ---- cvt_wt: W[1024,ncols] -> Wt[ncols,1024] bf16 transpose ----
    const float* W;
    __bf16* Wo;
    int ncols, n0, k0;
    if (bid < 4864) {
      int id = bid - 4096;
      W = Wqkv; Wo = Wt; ncols = 3072;
      n0 = (id % 48) * 64; k0 = (id / 48) * 64;
    } else {
      int id = bid - 4864;
      W = Wout; Wo = Wt2; ncols = 1024;
      n0 = (id & 15) * 64; k0 = (id >> 4) * 64;
    }
    float(*tile)[65] = (float(*)[65])smem;
    {
      int c = tid & 63, r4 = tid >> 6;
#pragma unroll
      for (int p = 0; p < 16; ++p) {
        int r = r4 + p * 4;
        tile[r][c] = W[(size_t)(k0 + r) * ncols + n0 + c];
      }
    }
    __syncthreads();
    {
      int cc = (tid & 31) * 2, r8 = tid >> 5;
#pragma unroll
      for (int p = 0; p < 8; ++p) {
        int rr = r8 + p * 8;
        bf16x2v o = {(__bf16)tile[cc][rr], (__bf16)tile[cc + 1][rr]};
        *(bf16x2v*)&Wo[(size_t)(n0 + rr) * 1024 + k0 + cc] = o;
      }
    }
  } else {
    // ---- mb_fuse: (mask+bias)*log2e, BOTH b, mask loaded once ----
    int id = bid - 5120;  // [0,1024)
    const int kt = id & 31, qt = id >> 5;
    __bf16(*sm)[68] = (__bf16(*)[68])smem;
    const int r0 = tid >> 4;        // 0..15
    const int cc = (tid & 15) * 4;  // 0,4,..,60
    const float* mrow = mask + (size_t)(qt * 64) * S_LEN + kt * 64;
    float4 mld[4];
#pragma unroll
    for (int p = 0; p < 4; ++p)
      mld[p] = *(const float4*)(mrow + (size_t)(r0 + p * 16) * S_LEN + cc);
    const int w = tid >> 6, lane = tid & 63;
    const int quad = lane >> 4, cl = lane & 15;
    for (int b = 0; b < 2; ++b) {
      const float* brow =
          bias + ((size_t)b * S_LEN + qt * 64) * S_LEN + kt * 64;
#pragma unroll
      for (int p = 0; p < 4; ++p) {
        int r = r0 + p * 16;
        float4 a = *(const float4*)(brow + (size_t)r * S_LEN + cc);
        sm[r][cc + 0] = (__bf16)((mld[p].x + a.x) * LOG2E);
        sm[r][cc + 1] = (__bf16)((mld[p].y + a.y) * LOG2E);
        sm[r][cc + 2] = (__bf16)((mld[p].z + a.z) * LOG2E);
        sm[r][cc + 3] = (__bf16)((mld[p].w + a.w) * LOG2E);
      }
      __syncthreads();
      __bf16 vals[16];
#pragma unroll
      for (int ct = 0; ct < 4; ++ct) {
        bf16x4 v = *(const bf16x4*)&sm[w * 16 + cl][ct * 16 + quad * 4];
        *(bf16x4*)&vals[ct * 4] = v;
      }
      __bf16* op = MB + (((size_t)(b * 32 + qt) * 32 + kt) * 4096) +
                   (w * 64 + lane) * 16;
      *(bf16x8*)op = *(bf16x8*)&vals[0];
      *(bf16x8*)(op + 8) = *(bf16x8*)&vals[8];
      __syncthreads();  // sm reuse for next b
    }
  }
}

// ---------------- QKV projection: bf16 MFMA 128x128 tile ----------------
// V-wgs (colBase>=2048) store via per-wave LDS transpose -> coalesced
// 128B stores along s (was 8B-per-4KB scatter, ~8x write amplification).
__global__ __launch_bounds__(256) void gemm_qkv_mfma(
    const __bf16* __restrict__ Xb, const __bf16* __restrict__ Wt,
    const float* __restrict__ bqkv, __bf16* __restrict__ Qb,
    __bf16* __restrict__ Kb, __bf16* __restrict__ Vtb) {
  // union region: As(8KB) + Bs(8KB) during k-loop; 4x 64x72 bf16 transpose
  // tiles (36,864B) during the V epilogue (after a barrier).
  __shared__ __align__(16) __bf16 shm[4 * 64 * 72];
  __bf16* As = shm;         // 128*32 elements
  __bf16* Bs = shm + 4096;  // 128*32 elements
  const int tid = threadIdx.x;
  const int w = tid >> 6, lane = tid & 63;
  const int c = lane & 15, quad = lane >> 4;
  const int wm = w >> 1, wn = w & 1;
  const int rowBase = blockIdx.y * 128;
  const int colBase = blockIdx.x * 128;

  f32x4 acc[4][4] = {};

  const __bf16* gA0 =
      Xb + (size_t)(rowBase + w * 32 + (lane >> 2)) * 1024 + (lane & 3) * 8;
  const __bf16* gB0 =
      Wt + (size_t)(colBase + w * 32 + (lane >> 2)) * 1024 + (lane & 3) * 8;
  __bf16* lA0 = &As[(w * 32) * 32];
  __bf16* lB0 = &Bs[(w * 32) * 32];

  for (int k0 = 0; k0 < 1024; k0 += 32) {
    __syncthreads();
#pragma unroll
    for (int p = 0; p < 2; ++p) {
      GLD_LDS16(gA0 + (size_t)p * 16 * 1024 + k0, lA0 + p * 16 * 32);
      GLD_LDS16(gB0 + (size_t)p * 16 * 1024 + k0, lB0 + p * 16 * 32);
    }
    __syncthreads();

    bf16x8 af[4], bfr[4];
#pragma unroll
    for (int mt = 0; mt < 4; ++mt)
      af[mt] = *(const bf16x8*)&As[(wm * 64 + mt * 16 + c) * 32 + quad * 8];
#pragma unroll
    for (int nt = 0; nt < 4; ++nt)
      bfr[nt] = *(const bf16x8*)&Bs[(wn * 64 + nt * 16 + c) * 32 + quad * 8];
#pragma unroll
    for (int mt = 0; mt < 4; ++mt)
#pragma unroll
      for (int nt = 0; nt < 4; ++nt)
        acc[mt][nt] = __builtin_amdgcn_mfma_f32_16x16x32_bf16(
            af[mt], bfr[nt], acc[mt][nt], 0, 0, 0);
  }

  if (colBase < 2048) {
    // ---- Q/K epilogue (scatter; 32B-contiguous per quad) ----
#pragma unroll
    for (int mt = 0; mt < 4; ++mt) {
      int row0 = rowBase + wm * 64 + mt * 16 + quad * 4;
#pragma unroll
      for (int nt = 0; nt < 4; ++nt) {
        int col = colBase + wn * 64 + nt * 16 + c;
        float bias = bqkv[col];
        int three = col >> 10;  // 0 or 1
        int h = (col & 1023) >> 6;
        int d = col & 63;
#pragma unroll
        for (int r = 0; r < 4; ++r) {
          int rr = row0 + r;
          int bb = rr >> 11, s = rr & 2047;
          float val = acc[mt][nt][r] + bias;
          size_t ho = (size_t)(bb * NH + h);
          if (three == 0)
            Qb[(ho * S_LEN + s) * HD + d] = (__bf16)val;
          else
            Kb[(ho * S_LEN + s) * HD + d] = (__bf16)val;
        }
      }
    }
  } else {
    // ---- V epilogue: per-wave LDS transpose, coalesced V^T stores ----
    __syncthreads();  // As/Bs dead (all waves past last ds_read)
    __bf16* Tt = shm + w * (64 * 72);  // [d_local][s_local], pad 72
    const int cols0 = colBase + wn * 64;
    const int rows0 = rowBase + wm * 64;
    const int hq = (cols0 & 1023) >> 6;
    const int bb = rows0 >> 11;
    const int sBase = rows0 & 2047;
#pragma unroll
    for (int nt = 0; nt < 4; ++nt) {
      float bias = bqkv[cols0 + nt * 16 + c];
#pragma unroll
      for (int mt = 0; mt < 4; ++mt) {
        __bf16 t4[4];
#pragma unroll
        for (int r = 0; r < 4; ++r) t4[r] = (__bf16)(acc[mt][nt][r] + bias);
        *(bf16x4*)&Tt[(nt * 16 + c) * 72 + mt * 16 + quad * 4] =
            *(bf16x4*)t4;
      }
    }
    __syncthreads();
    const size_t vbase = ((size_t)(bb * NH + hq) * HD) * S_LEN;
    const int s0 = (lane & 7) * 8;
    const int dl0 = lane >> 3;  // 0..7
#pragma unroll
    for (int dt = 0; dt < 8; ++dt) {
      int dl = dt * 8 + dl0;
      bf16x8 v = *(const bf16x8*)&Tt[dl * 72 + s0];
      *(bf16x8*)&Vtb[vbase + (size_t)dl * S_LEN + sBase + s0] = v;
    }
  }
}

// ------- MFMA flash attention: S^T dataflow, QBLK=128, T4 sync -------
// S^T = K*Q^T via mfma(A=kf, B=qa): lane holds S^T[kcol][qrow=c]; that IS
// the B-operand layout of mfma_f32_16x16x16_bf16, so PV runs from registers.
// Sync (T4): counted `s_waitcnt vmcnt(4)` + raw s_barrier per tile --
// waits ONLY for the 4 K/V DMAs (full iteration of cover); the 4 younger
// MB loads stay in flight across the barrier. No vmcnt(0) drain anywhere
// in the loop. Phase rotation: tile ring starts at ((qt+h)&1)*16 so
// co-resident wgs anti-align their DMA bursts / barrier phases (valid:
// no-max-shift softmax is order-independent).
__global__ __launch_bounds__(256) void attn_mfma(
    const __bf16* __restrict__ Qb, const __bf16* __restrict__ Kb,
    const __bf16* __restrict__ Vtb, const __bf16* __restrict__ MB,
    __bf16* __restrict__ AOb) {
  const int qt = blockIdx.x, h = blockIdx.y, b = blockIdx.z;
  const int tid = threadIdx.x;
  const int w = tid >> 6;
  const int lane = tid & 63;
  const int c = lane & 15;
  const int quad = lane >> 4;

  __shared__ __align__(16) __bf16 Ks[2][64 * 64];
  __shared__ __align__(16) __bf16 Vs[2][64 * 64];  // [feat][key], swizzled
#if !HAVE_MFMA_16x16x16_BF16
  __shared__ __align__(16) __bf16 P2[4][16 * 72];
#endif

  const size_t headoff = (size_t)(b * NH + h) * S_LEN * HD;
  const __bf16* Qg = Qb + headoff + (size_t)(qt * 128) * HD;
  const __bf16* Kg = Kb + headoff;
  const __bf16* Vg = Vtb + headoff;  // [hd][S]
  // MB fragment bases (lane part folded in); tile kt is added per iter.
  const __bf16* MBq0 =
      MB + ((size_t)(b * 32 + qt * 2 + 0) * 32) * 4096 + (w * 64 + lane) * 16;
  const __bf16* MBq1 =
      MB + ((size_t)(b * 32 + qt * 2 + 1) * 32) * 4096 + (w * 64 + lane) * 16;

  // phase rotation: this wg walks tiles (start, start+1, ... mod 32)
  const int start = ((qt + h) & 1) << 4;

  // staging geometry (chunk ch = p*256+tid -> row f, col-chunk j, swizzled)
  const int f0 = tid >> 3, f1 = f0 + 32;
  const int j = tid & 7;
  const int sj0 = j ^ (f0 & 7);
  const int sj1 = j ^ (f1 & 7);
  const int lds0 = tid * 8;
  const int lds1 = (256 + tid) * 8;
  // per-lane invariant parts of the DMA source addresses
  const int kA0 = f0 * HD + sj0 * 8;
  const int kA1 = f1 * HD + sj1 * 8;
  const int vA0 = f0 * S_LEN + sj0 * 8;
  const int vA1 = f1 * S_LEN + sj1 * 8;

  // Q fragments: lane holds Q[qrow=g*64+w*16+c][d=quad*8+j] (loop-invariant)
  bf16x8 qa[2][2];
#pragma unroll
  for (int g = 0; g < 2; ++g) {
    qa[g][0] = *(const bf16x8*)(Qg + (g * 64 + w * 16 + c) * HD + quad * 8);
    qa[g][1] =
        *(const bf16x8*)(Qg + (g * 64 + w * 16 + c) * HD + quad * 8 + 32);
  }

  // swizzled b128 read offsets (row&7 == c&7)
  const int rs0 = (quad ^ (c & 7)) * 8;
  const int rs1 = ((quad + 4) ^ (c & 7)) * 8;

  f32x4 Oa[2][4] = {};  // O^T[d=ft*16+quad*4+r][qrow=c] per group
  f32x4 psum[2] = {};   // packed row-partial sums of p per group

  // preamble: DMA tile `start` into buffer 0; MB fragments for it
  GLD_LDS16(Kg + (size_t)start * 64 * HD + kA0, &Ks[0][lds0]);
  GLD_LDS16(Kg + (size_t)start * 64 * HD + kA1, &Ks[0][lds1]);
  GLD_LDS16(Vg + (size_t)start * 64 + vA0, &Vs[0][lds0]);
  GLD_LDS16(Vg + (size_t)start * 64 + vA1, &Vs[0][lds1]);

  bf16x8 rMB[2][2];
  rMB[0][0] = *(const bf16x8*)(MBq0 + (size_t)start * 4096);
  rMB[0][1] = *(const bf16x8*)(MBq0 + (size_t)start * 4096 + 8);
  rMB[1][0] = *(const bf16x8*)(MBq1 + (size_t)start * 4096);
  rMB[1][1] = *(const bf16x8*)(MBq1 + (size_t)start * 4096 + 8);

  __syncthreads();  // one-time full drain: tile0 LDS + qa + rMB ready

  const float c1 = 0.125f * LOG2E;  // 1/sqrt(hd) * log2(e)

#pragma unroll 2
  for (int t = 0; t < 32; ++t) {
    const int cur = t & 1, nxt = cur ^ 1;
    const int ktn = (start + t + 1) & 31;  // next tile in the ring
    // async DMA of next tile into the inactive buffer (4 oldest vmem ops)
    if (t < 31) {
      GLD_LDS16(Kg + (size_t)ktn * 64 * HD + kA0, &Ks[nxt][lds0]);
      GLD_LDS16(Kg + (size_t)ktn * 64 * HD + kA1, &Ks[nxt][lds1]);
      GLD_LDS16(Vg + (size_t)ktn * 64 + vA0, &Vs[nxt][lds0]);
      GLD_LDS16(Vg + (size_t)ktn * 64 + vA1, &Vs[nxt][lds1]);
    }

    // ---- K fragment reads (shared by both q-groups) ----
    bf16x8 kf0[4], kf1[4];
#pragma unroll
    for (int ct = 0; ct < 4; ++ct) {
      kf0[ct] = *(const bf16x8*)&Ks[cur][(ct * 16 + c) * 64 + rs0];
      kf1[ct] = *(const bf16x8*)&Ks[cur][(ct * 16 + c) * 64 + rs1];
    }

    // ---- per group: QK (sv reused) -> softmax -> JIT MB reload ----
    s16x4 pb[2][4];
#pragma unroll
    for (int g = 0; g < 2; ++g) {
      f32x4 sv[4];
      __builtin_amdgcn_s_setprio(1);
#pragma unroll
      for (int ct = 0; ct < 4; ++ct) {
        f32x4 a = {};
        a = __builtin_amdgcn_mfma_f32_16x16x32_bf16(kf0[ct], qa[g][0], a, 0,
                                                    0, 0);
        a = __builtin_amdgcn_mfma_f32_16x16x32_bf16(kf1[ct], qa[g][1], a, 0,
                                                    0, 0);
        sv[ct] = a;
      }
      __builtin_amdgcn_s_setprio(0);
#pragma unroll
      for (int ct = 0; ct < 4; ++ct) {
        f32x4 pv;
#pragma unroll
        for (int r = 0; r < 4; ++r) {
          float mb = (ct < 2) ? (float)rMB[g][0][ct * 4 + r]
                              : (float)rMB[g][1][(ct - 2) * 4 + r];
          pv[r] = EXP2F(sv[ct][r] * c1 + mb);
        }
        psum[g] += pv;
        __bf16 t4[4];
#pragma unroll
        for (int r = 0; r < 4; ++r) t4[r] = (__bf16)pv[r];
        pb[g][ct] = *(s16x4*)t4;
      }
      // JIT reload of rMB[g] for the NEXT tile (ring wraps; final-iter
      // reload re-reads tile `start` -- valid memory, value unused).
      const __bf16* mp =
          (g ? MBq1 : MBq0) + (size_t)ktn * 4096;
      rMB[g][0] = *(const bf16x8*)mp;
      rMB[g][1] = *(const bf16x8*)(mp + 8);
    }

#if HAVE_MFMA_16x16x16_BF16
    // ---- V fragment reads + PV: pure-register MFMA cluster ----
    s16x4 vf[4][4];
#pragma unroll
    for (int ft = 0; ft < 4; ++ft) {
      const int fr = ft * 16 + c;
#pragma unroll
      for (int ct = 0; ct < 4; ++ct) {
        const int chunk = ((ct * 2 + (quad >> 1)) ^ (fr & 7)) * 8 +
                          (quad & 1) * 4;
        vf[ft][ct] = *(const s16x4*)&Vs[cur][fr * 64 + chunk];
      }
    }
    __builtin_amdgcn_s_setprio(1);
#pragma unroll
    for (int g = 0; g < 2; ++g)
#pragma unroll
      for (int ft = 0; ft < 4; ++ft)
#pragma unroll
        for (int ct = 0; ct < 4; ++ct)
          Oa[g][ft] = __builtin_amdgcn_mfma_f32_16x16x16bf16_1k(
              vf[ft][ct], pb[g][ct], Oa[g][ft], 0, 0, 0);
    __builtin_amdgcn_s_setprio(0);
#else
    // ---- fallback: P^T via wave-private LDS ----
#pragma unroll
    for (int g = 0; g < 2; ++g) {
#pragma unroll
      for (int ct = 0; ct < 4; ++ct)
        *(bf16x4*)&P2[w][c * 72 + ct * 16 + quad * 4] = *(bf16x4*)&pb[g][ct];
      bf16x8 pf0 = *(const bf16x8*)&P2[w][c * 72 + quad * 8];
      bf16x8 pf1 = *(const bf16x8*)&P2[w][c * 72 + 32 + quad * 8];
#pragma unroll
      for (int ft = 0; ft < 4; ++ft) {
        const int fr = ft * 16 + c;
        bf16x8 vv0 = *(const bf16x8*)&Vs[cur][fr * 64 + rs0];
        bf16x8 vv1 = *(const bf16x8*)&Vs[cur][fr * 64 + rs1];
        Oa[g][ft] = __builtin_amdgcn_mfma_f32_16x16x32_bf16(vv0, pf0,
                                                            Oa[g][ft], 0, 0, 0);
        Oa[g][ft] = __builtin_amdgcn_mfma_f32_16x16x32_bf16(vv1, pf1,
                                                            Oa[g][ft], 0, 0, 0);
      }
    }
#endif

    // T4 sync: wait only for the 4 K/V DMAs (oldest); the 4 MB loads
    // (younger) stay in flight across the raw barrier. All this wave's
    // ds_reads were consumed by MFMAs above (lgkmcnt naturally drained),
    // so s_barrier alone orders the LDS read/write hazard.
    asm volatile("s_waitcnt vmcnt(4)" ::: "memory");
    __builtin_amdgcn_sched_barrier(0);
    __builtin_amdgcn_s_barrier();
    __builtin_amdgcn_sched_barrier(0);
  }

  // full row sum + normalize + store, per group
#pragma unroll
  for (int g = 0; g < 2; ++g) {
    float lsum = psum[g][0] + psum[g][1] + psum[g][2] + psum[g][3];
    lsum += __shfl_xor(lsum, 16);
    lsum += __shfl_xor(lsum, 32);
    const float invl = 1.0f / lsum;
    __bf16* orow = AOb +
                   (size_t)(b * S_LEN + qt * 128 + g * 64 + w * 16 + c) *
                       DMODEL +
                   h * HD;
#pragma unroll
    for (int ft = 0; ft < 4; ++ft) {
      __bf16 t4[4];
#pragma unroll
      for (int r = 0; r < 4; ++r) t4[r] = (__bf16)(Oa[g][ft][r] * invl);
      *(bf16x4*)(orow + ft * 16 + quad * 4) = *(bf16x4*)t4;
    }
  }
}

// ---------------- Output projection: bf16 MFMA 128x64 tile ----------------
__global__ __launch_bounds__(256) void gemm_out_mfma(
    const __bf16* __restrict__ AOb, const __bf16* __restrict__ Wt2,
    const float* __restrict__ bout, float* __restrict__ Out) {
  __shared__ __align__(16) __bf16 As[128 * 32];
  __shared__ __align__(16) __bf16 Bs[64 * 32];
  const int tid = threadIdx.x;
  const int w = tid >> 6, lane = tid & 63;
  const int c = lane & 15, quad = lane >> 4;
  const int rowBase = blockIdx.y * 128;
  const int colBase = blockIdx.x * 64;

  f32x4 acc[2][4] = {};

  const __bf16* gA0 =
      AOb + (size_t)(rowBase + w * 32 + (lane >> 2)) * 1024 + (lane & 3) * 8;
  const __bf16* gB0 =
      Wt2 + (size_t)(colBase + w * 16 + (lane >> 2)) * 1024 + (lane & 3) * 8;
  __bf16* lA0 = &As[(w * 32) * 32];
  __bf16* lB0 = &Bs[(w * 16) * 32];

  for (int k0 = 0; k0 < 1024; k0 += 32) {
    __syncthreads();
#pragma unroll
    for (int p = 0; p < 2; ++p)
      GLD_LDS16(gA0 + (size_t)p * 16 * 1024 + k0, lA0 + p * 16 * 32);
    GLD_LDS16(gB0 + k0, lB0);
    __syncthreads();

    bf16x8 af[2], bfr[4];
#pragma unroll
    for (int mt = 0; mt < 2; ++mt)
      af[mt] = *(const bf16x8*)&As[(w * 32 + mt * 16 + c) * 32 + quad * 8];
#pragma unroll
    for (int nt = 0; nt < 4; ++nt)
      bfr[nt] = *(const bf16x8*)&Bs[(nt * 16 + c) * 32 + quad * 8];
#pragma unroll
    for (int mt = 0; mt < 2; ++mt)
#pragma unroll
      for (int nt = 0; nt < 4; ++nt)
        acc[mt][nt] = __builtin_amdgcn_mfma_f32_16x16x32_bf16(
            af[mt], bfr[nt], acc[mt][nt], 0, 0, 0);
  }

#pragma unroll
  for (int mt = 0; mt < 2; ++mt) {
    int row0 = rowBase + w * 32 + mt * 16 + quad * 4;
#pragma unroll
    for (int nt = 0; nt < 4; ++nt) {
      int col = colBase + nt * 16 + c;
      float bias = bout[col];
#pragma unroll
      for (int r = 0; r < 4; ++r)
        Out[(size_t)(row0 + r) * 1024 + col] = acc[mt][nt][r] + bias;
    }
  }
}

extern "C" void kernel_launch(void* const* d_in, const int* in_sizes, int n_in,
                              void* d_out, int out_size, void* d_ws,
                              size_t ws_size, hipStream_t stream) {
  const float* x = (const float*)d_in[0];
  const float* attn_mask = (const float*)d_in[1];
  const float* attn_bias = (const float*)d_in[2];
  const float* Wqkv = (const float*)d_in[3];
  const float* bqkv = (const float*)d_in[4];
  const float* Wout = (const float*)d_in[5];
  const float* bout = (const float*)d_in[6];
  float* out = (float*)d_out;

  __bf16* base = (__bf16*)d_ws;
  __bf16* Xb = base;                  // [0, 4M)
  __bf16* AOb = base;                 // aliases Xb (disjoint lifetime)
  __bf16* Wt = base + 4194304;        // [4M, 7M)
  __bf16* Qb = base + 8388608;        // [8M, 12M)
  __bf16* Kb = base + 12582912;       // [12M, 16M)
  __bf16* Vtb = base + 16777216;      // [16M, 20M)
  __bf16* MB = base + 20971520;       // [20M, 28M)
  __bf16* Wt2 = base + 29360128;      // [28M, 29M)

  preprocess<<<6144, 256, 0, stream>>>(x, attn_mask, attn_bias, Wqkv, Wout,
                                       Xb, Wt, Wt2, MB);
  gemm_qkv_mfma<<<dim3(24, 32), 256, 0, stream>>>(Xb, Wt, bqkv, Qb, Kb, Vtb);
  attn_mfma<<<dim3(16, NH, 2), 256, 0, stream>>>(Qb, Kb, Vtb, MB, AOb);
  gemm_out_mfma<<<dim3(16, 32), 256, 0, stream>>>(AOb, Wt2, bout, out);
}

// Round 8
// 258.544 us; speedup vs baseline: 1.0770x; 1.0023x over previous
//
#include <hip/hip_runtime.h>
#include <hip/hip_bf16.h>

// Problem: B=2, S=2048, D=1024, H=16, hd=64
// ws layout (58 MiB, bf16-element offsets from d_ws):
//   Xb  [0, 4M)        8 MiB  (x bf16)             -- dead after gemm_qkv
//   AOb [0, 4M)        8 MiB  (attn out bf16)      -- aliases Xb
//   Wt  [4M, 7M)       6 MiB  (Wqkv^T bf16)
//   Qb  [8M, 12M)      8 MiB
//   Kb  [12M, 16M)     8 MiB
//   Vtb [16M, 20M)     8 MiB  (V^T [B,H,hd,S])
//   MB  [20M, 28M)    16 MiB  (mask+bias, S^T-fragment order, *log2e)
//   Wt2 [28M+..]       2 MiB  (Wout^T bf16)
//
// R15: R7's T4 graft (counted vmcnt + sched_barrier(0) + 32 barriers)
// regressed attn 70.6->82 -- sched_barrier pinning defeats compiler
// scheduling (m141 failure mode) and pair-amortization was lost. REVERT to
// the proven R5 structure (16 iters x 2 subtiles/barrier, 64KB LDS, plain
// __syncthreads) + R6 reg diet (per-group sv, JIT rMB reload). New: gemm_qkv
// Q/K epilogue via per-wave LDS transpose -> coalesced 128B stores (was
// 32B-granular scatter, ~4x write amplification on 16MB).

#define S_LEN 2048
#define DMODEL 1024
#define NH 16
#define HD 64

typedef __bf16 bf16x8 __attribute__((ext_vector_type(8)));
typedef __bf16 bf16x4 __attribute__((ext_vector_type(4)));
typedef __bf16 bf16x2v __attribute__((ext_vector_type(2)));
typedef float f32x4 __attribute__((ext_vector_type(4)));
typedef short s16x4 __attribute__((ext_vector_type(4)));

#define GLD_LDS16(g, l)                                              \
  __builtin_amdgcn_global_load_lds(                                  \
      (const __attribute__((address_space(1))) unsigned int*)(g),    \
      (__attribute__((address_space(3))) unsigned int*)(l), 16, 0, 0)

#if __has_builtin(__builtin_amdgcn_mfma_f32_16x16x16bf16_1k)
#define HAVE_MFMA_16x16x16_BF16 1
#else
#define HAVE_MFMA_16x16x16_BF16 0
#endif

#if __has_builtin(__builtin_amdgcn_exp2f)
#define EXP2F(x) __builtin_amdgcn_exp2f(x)
#else
static __device__ __forceinline__ float EXP2F(float x) {
  float r;
  asm volatile("v_exp_f32 %0, %1" : "=v"(r) : "v"(x));
  return r;
}
#endif

#define LOG2E 1.44269504f

// ---------- fused preprocess: cvt_x | cvt_wt(Wqkv) | cvt_wt(Wout) | mb_fuse
// blockIdx.x ranges: [0,4096) cvt_x, [4096,4864) Wqkv^T, [4864,5120) Wout^T,
// [5120,6144) mb_fuse (BOTH b per block; mask read once).
__global__ __launch_bounds__(256) void preprocess(
    const float* __restrict__ x, const float* __restrict__ mask,
    const float* __restrict__ bias, const float* __restrict__ Wqkv,
    const float* __restrict__ Wout, __bf16* __restrict__ Xb,
    __bf16* __restrict__ Wt, __bf16* __restrict__ Wt2,
    __bf16* __restrict__ MB) {
  __shared__ __align__(16) char smem[64 * 65 * 4];
  const int bid = blockIdx.x;
  const int tid = threadIdx.x;

  if (bid < 4096) {
    // ---- cvt_x: fp32 -> bf16 ----
    int i = bid * 256 + tid;
    float4 v = ((const float4*)x)[i];
    bf16x4 o = {(__bf16)v.x, (__bf16)v.y, (__bf16)v.z, (__bf16)v.w};
    *(bf16x4*)&Xb[(size_t)i * 4] = o;
  } else if (bid < 5120) {
    // ---- cvt_wt: W[1024,ncols] -> Wt[ncols,1024] bf16 transpose ----
    const float* W;
    __bf16* Wo;
    int ncols, n0, k0;
    if (bid < 4864) {
      int id = bid - 4096;
      W = Wqkv; Wo = Wt; ncols = 3072;
      n0 = (id % 48) * 64; k0 = (id / 48) * 64;
    } else {
      int id = bid - 4864;
      W = Wout; Wo = Wt2; ncols = 1024;
      n0 = (id & 15) * 64; k0 = (id >> 4) * 64;
    }
    float(*tile)[65] = (float(*)[65])smem;
    {
      int c = tid & 63, r4 = tid >> 6;
#pragma unroll
      for (int p = 0; p < 16; ++p) {
        int r = r4 + p * 4;
        tile[r][c] = W[(size_t)(k0 + r) * ncols + n0 + c];
      }
    }
    __syncthreads();
    {
      int cc = (tid & 31) * 2, r8 = tid >> 5;
#pragma unroll
      for (int p = 0; p < 8; ++p) {
        int rr = r8 + p * 8;
        bf16x2v o = {(__bf16)tile[cc][rr], (__bf16)tile[cc + 1][rr]};
        *(bf16x2v*)&Wo[(size_t)(n0 + rr) * 1024 + k0 + cc] = o;
      }
    }
  } else {
    // ---- mb_fuse: (mask+bias)*log2e, BOTH b, mask loaded once ----
    int id = bid - 5120;  // [0,1024)
    const int kt = id & 31, qt = id >> 5;
    __bf16(*sm)[68] = (__bf16(*)[68])smem;
    const int r0 = tid >> 4;        // 0..15
    const int cc = (tid & 15) * 4;  // 0,4,..,60
    const float* mrow = mask + (size_t)(qt * 64) * S_LEN + kt * 64;
    float4 mld[4];
#pragma unroll
    for (int p = 0; p < 4; ++p)
      mld[p] = *(const float4*)(mrow + (size_t)(r0 + p * 16) * S_LEN + cc);
    const int w = tid >> 6, lane = tid & 63;
    const int quad = lane >> 4, cl = lane & 15;
    for (int b = 0; b < 2; ++b) {
      const float* brow =
          bias + ((size_t)b * S_LEN + qt * 64) * S_LEN + kt * 64;
#pragma unroll
      for (int p = 0; p < 4; ++p) {
        int r = r0 + p * 16;
        float4 a = *(const float4*)(brow + (size_t)r * S_LEN + cc);
        sm[r][cc + 0] = (__bf16)((mld[p].x + a.x) * LOG2E);
        sm[r][cc + 1] = (__bf16)((mld[p].y + a.y) * LOG2E);
        sm[r][cc + 2] = (__bf16)((mld[p].z + a.z) * LOG2E);
        sm[r][cc + 3] = (__bf16)((mld[p].w + a.w) * LOG2E);
      }
      __syncthreads();
      __bf16 vals[16];
#pragma unroll
      for (int ct = 0; ct < 4; ++ct) {
        bf16x4 v = *(const bf16x4*)&sm[w * 16 + cl][ct * 16 + quad * 4];
        *(bf16x4*)&vals[ct * 4] = v;
      }
      __bf16* op = MB + (((size_t)(b * 32 + qt) * 32 + kt) * 4096) +
                   (w * 64 + lane) * 16;
      *(bf16x8*)op = *(bf16x8*)&vals[0];
      *(bf16x8*)(op + 8) = *(bf16x8*)&vals[8];
      __syncthreads();  // sm reuse for next b
    }
  }
}

// ---------------- QKV projection: bf16 MFMA 128x128 tile ----------------
// R15: ALL epilogues (Q, K, V) go through a per-wave LDS tile so global
// stores are fully-coalesced 128B rows. Q/K: Tt[s][d]; V: Tt[d][s].
__global__ __launch_bounds__(256) void gemm_qkv_mfma(
    const __bf16* __restrict__ Xb, const __bf16* __restrict__ Wt,
    const float* __restrict__ bqkv, __bf16* __restrict__ Qb,
    __bf16* __restrict__ Kb, __bf16* __restrict__ Vtb) {
  // union: As(8KB)+Bs(8KB) during k-loop; 4x 64x80 bf16 tiles (40KB) after.
  __shared__ __align__(16) __bf16 shm[4 * 64 * 80];
  __bf16* As = shm;         // 128*32 elements
  __bf16* Bs = shm + 4096;  // 128*32 elements
  const int tid = threadIdx.x;
  const int w = tid >> 6, lane = tid & 63;
  const int c = lane & 15, quad = lane >> 4;
  const int wm = w >> 1, wn = w & 1;
  const int rowBase = blockIdx.y * 128;
  const int colBase = blockIdx.x * 128;

  f32x4 acc[4][4] = {};

  const __bf16* gA0 =
      Xb + (size_t)(rowBase + w * 32 + (lane >> 2)) * 1024 + (lane & 3) * 8;
  const __bf16* gB0 =
      Wt + (size_t)(colBase + w * 32 + (lane >> 2)) * 1024 + (lane & 3) * 8;
  __bf16* lA0 = &As[(w * 32) * 32];
  __bf16* lB0 = &Bs[(w * 32) * 32];

  for (int k0 = 0; k0 < 1024; k0 += 32) {
    __syncthreads();
#pragma unroll
    for (int p = 0; p < 2; ++p) {
      GLD_LDS16(gA0 + (size_t)p * 16 * 1024 + k0, lA0 + p * 16 * 32);
      GLD_LDS16(gB0 + (size_t)p * 16 * 1024 + k0, lB0 + p * 16 * 32);
    }
    __syncthreads();

    bf16x8 af[4], bfr[4];
#pragma unroll
    for (int mt = 0; mt < 4; ++mt)
      af[mt] = *(const bf16x8*)&As[(wm * 64 + mt * 16 + c) * 32 + quad * 8];
#pragma unroll
    for (int nt = 0; nt < 4; ++nt)
      bfr[nt] = *(const bf16x8*)&Bs[(wn * 64 + nt * 16 + c) * 32 + quad * 8];
#pragma unroll
    for (int mt = 0; mt < 4; ++mt)
#pragma unroll
      for (int nt = 0; nt < 4; ++nt)
        acc[mt][nt] = __builtin_amdgcn_mfma_f32_16x16x32_bf16(
            af[mt], bfr[nt], acc[mt][nt], 0, 0, 0);
  }

  __syncthreads();  // As/Bs dead; shm becomes per-wave Tt tiles
  __bf16* Tt = shm + w * (64 * 80);  // per-wave private
  const int cols0 = colBase + wn * 64;
  const int rows0 = rowBase + wm * 64;
  const int three = colBase >> 10;  // 0=Q, 1=K, 2=V (wg-uniform)
  const int hq = (cols0 & 1023) >> 6;
  const int bb = rows0 >> 11;
  const int sBase = rows0 & 2047;

  if (three < 2) {
    // ---- Q/K epilogue: Tt[s_local][d_local], coalesced [s][d] stores ----
#pragma unroll
    for (int nt = 0; nt < 4; ++nt) {
      float bias = bqkv[cols0 + nt * 16 + c];
#pragma unroll
      for (int mt = 0; mt < 4; ++mt)
#pragma unroll
        for (int r = 0; r < 4; ++r)
          Tt[(mt * 16 + quad * 4 + r) * 80 + nt * 16 + c] =
              (__bf16)(acc[mt][nt][r] + bias);
    }
    // same-wave LDS ordering: compiler-inserted lgkmcnt suffices
    __bf16* qk = three ? Kb : Qb;
    const size_t rbase =
        ((size_t)(bb * NH + hq) * S_LEN + sBase) * HD;
    const int d8 = (lane & 7) * 8;
    const int sl0 = lane >> 3;
#pragma unroll
    for (int i = 0; i < 8; ++i) {
      int sl = sl0 + i * 8;
      bf16x8 v = *(const bf16x8*)&Tt[sl * 80 + d8];
      *(bf16x8*)&qk[rbase + (size_t)sl * HD + d8] = v;
    }
  } else {
    // ---- V epilogue: Tt[d_local][s_local], coalesced V^T stores ----
#pragma unroll
    for (int nt = 0; nt < 4; ++nt) {
      float bias = bqkv[cols0 + nt * 16 + c];
#pragma unroll
      for (int mt = 0; mt < 4; ++mt) {
        __bf16 t4[4];
#pragma unroll
        for (int r = 0; r < 4; ++r) t4[r] = (__bf16)(acc[mt][nt][r] + bias);
        *(bf16x4*)&Tt[(nt * 16 + c) * 80 + mt * 16 + quad * 4] =
            *(bf16x4*)t4;
      }
    }
    const size_t vbase = ((size_t)(bb * NH + hq) * HD) * S_LEN;
    const int s0 = (lane & 7) * 8;
    const int dl0 = lane >> 3;
#pragma unroll
    for (int dt = 0; dt < 8; ++dt) {
      int dl = dt * 8 + dl0;
      bf16x8 v = *(const bf16x8*)&Tt[dl * 80 + s0];
      *(bf16x8*)&Vtb[vbase + (size_t)dl * S_LEN + sBase + s0] = v;
    }
  }
}

// ------- MFMA flash attention: S^T dataflow, QBLK=128, 2 subtiles/barrier
// S^T = K*Q^T via mfma(A=kf, B=qa): lane holds S^T[kcol][qrow=c]; that IS
// the B-operand layout of mfma_f32_16x16x16_bf16, so PV runs from registers.
// R5 structure (proven 70.5us): TWO 64-key subtiles per barrier region
// (KVBLK=128 effective, 64KB LDS), plain __syncthreads, unroll-2.
// R6 reg diet: per-group sv; JIT rMB reload right after consumption (each
// reload has >= one subtile of compute cover before the barrier drain).
__global__ __launch_bounds__(256) void attn_mfma(
    const __bf16* __restrict__ Qb, const __bf16* __restrict__ Kb,
    const __bf16* __restrict__ Vtb, const __bf16* __restrict__ MB,
    __bf16* __restrict__ AOb) {
  const int qt = blockIdx.x, h = blockIdx.y, b = blockIdx.z;
  const int tid = threadIdx.x;
  const int w = tid >> 6;
  const int lane = tid & 63;
  const int c = lane & 15;
  const int quad = lane >> 4;

  __shared__ __align__(16) __bf16 Ks[2][2][64 * 64];  // [dbuf][subtile]
  __shared__ __align__(16) __bf16 Vs[2][2][64 * 64];  // [feat][key], swizzled
#if !HAVE_MFMA_16x16x16_BF16
  __shared__ __align__(16) __bf16 P2[4][16 * 72];
#endif

  const size_t headoff = (size_t)(b * NH + h) * S_LEN * HD;
  const __bf16* Qg = Qb + headoff + (size_t)(qt * 128) * HD;
  const __bf16* Kg = Kb + headoff;
  const __bf16* Vg = Vtb + headoff;  // [hd][S]
  const __bf16* MBq0 =
      MB + ((size_t)(b * 32 + qt * 2 + 0) * 32) * 4096 + (w * 64 + lane) * 16;
  const __bf16* MBq1 =
      MB + ((size_t)(b * 32 + qt * 2 + 1) * 32) * 4096 + (w * 64 + lane) * 16;

  // staging geometry (chunk ch = p*256+tid -> row f, col-chunk j, swizzled)
  const int f0 = tid >> 3, f1 = f0 + 32;
  const int j = tid & 7;
  const int sj0 = j ^ (f0 & 7);
  const int sj1 = j ^ (f1 & 7);
  const int lds0 = tid * 8;
  const int lds1 = (256 + tid) * 8;

  // Q fragments: lane holds Q[qrow=g*64+w*16+c][d=quad*8+j] (loop-invariant)
  bf16x8 qa[2][2];
#pragma unroll
  for (int g = 0; g < 2; ++g) {
    qa[g][0] = *(const bf16x8*)(Qg + (g * 64 + w * 16 + c) * HD + quad * 8);
    qa[g][1] =
        *(const bf16x8*)(Qg + (g * 64 + w * 16 + c) * HD + quad * 8 + 32);
  }

  // swizzled b128 read offsets (row&7 == c&7)
  const int rs0 = (quad ^ (c & 7)) * 8;
  const int rs1 = ((quad + 4) ^ (c & 7)) * 8;

  f32x4 Oa[2][4] = {};  // O^T[d=ft*16+quad*4+r][qrow=c] per group
  f32x4 psum[2] = {};   // packed row-partial sums of p per group

  const float c1 = 0.125f * LOG2E;  // 1/sqrt(hd) * log2(e)

  // one-subtile compute; after each group's softmax, rmb[g] is JIT-reloaded
  // from mbn (the SAME tile slot two k-tiles ahead).
  auto subtile = [&](const __bf16* KsS, const __bf16* VsS,
                     bf16x8(&rmb)[2][2], const __bf16* mbn0,
                     const __bf16* mbn1) {
    bf16x8 kf0[4], kf1[4];
#pragma unroll
    for (int ct = 0; ct < 4; ++ct) {
      kf0[ct] = *(const bf16x8*)&KsS[(ct * 16 + c) * 64 + rs0];
      kf1[ct] = *(const bf16x8*)&KsS[(ct * 16 + c) * 64 + rs1];
    }
    s16x4 pb[2][4];
#pragma unroll
    for (int g = 0; g < 2; ++g) {
      f32x4 sv[4];
      __builtin_amdgcn_s_setprio(1);
#pragma unroll
      for (int ct = 0; ct < 4; ++ct) {
        f32x4 a = {};
        a = __builtin_amdgcn_mfma_f32_16x16x32_bf16(kf0[ct], qa[g][0], a, 0,
                                                    0, 0);
        a = __builtin_amdgcn_mfma_f32_16x16x32_bf16(kf1[ct], qa[g][1], a, 0,
                                                    0, 0);
        sv[ct] = a;
      }
      __builtin_amdgcn_s_setprio(0);
#pragma unroll
      for (int ct = 0; ct < 4; ++ct) {
        f32x4 pv;
#pragma unroll
        for (int r = 0; r < 4; ++r) {
          float mb = (ct < 2) ? (float)rmb[g][0][ct * 4 + r]
                              : (float)rmb[g][1][(ct - 2) * 4 + r];
          pv[r] = EXP2F(sv[ct][r] * c1 + mb);
        }
        psum[g] += pv;
        __bf16 t4[4];
#pragma unroll
        for (int r = 0; r < 4; ++r) t4[r] = (__bf16)pv[r];
        pb[g][ct] = *(s16x4*)t4;
      }
      // JIT reload for tile+2 (final-iter over-read lands in the adjacent
      // MB tile / gap / Wt2 region -- allocated, read-only, safe).
      const __bf16* mp = g ? mbn1 : mbn0;
      rmb[g][0] = *(const bf16x8*)mp;
      rmb[g][1] = *(const bf16x8*)(mp + 8);
    }

#if HAVE_MFMA_16x16x16_BF16
    s16x4 vf[4][4];
#pragma unroll
    for (int ft = 0; ft < 4; ++ft) {
      const int fr = ft * 16 + c;
#pragma unroll
      for (int ct = 0; ct < 4; ++ct) {
        const int chunk = ((ct * 2 + (quad >> 1)) ^ (fr & 7)) * 8 +
                          (quad & 1) * 4;
        vf[ft][ct] = *(const s16x4*)&VsS[fr * 64 + chunk];
      }
    }
    __builtin_amdgcn_s_setprio(1);
#pragma unroll
    for (int g = 0; g < 2; ++g)
#pragma unroll
      for (int ft = 0; ft < 4; ++ft)
#pragma unroll
        for (int ct = 0; ct < 4; ++ct)
          Oa[g][ft] = __builtin_amdgcn_mfma_f32_16x16x16bf16_1k(
              vf[ft][ct], pb[g][ct], Oa[g][ft], 0, 0, 0);
    __builtin_amdgcn_s_setprio(0);
#else
#pragma unroll
    for (int g = 0; g < 2; ++g) {
#pragma unroll
      for (int ct = 0; ct < 4; ++ct)
        *(bf16x4*)&P2[w][c * 72 + ct * 16 + quad * 4] = *(bf16x4*)&pb[g][ct];
      bf16x8 pf0 = *(const bf16x8*)&P2[w][c * 72 + quad * 8];
      bf16x8 pf1 = *(const bf16x8*)&P2[w][c * 72 + 32 + quad * 8];
#pragma unroll
      for (int ft = 0; ft < 4; ++ft) {
        const int fr = ft * 16 + c;
        bf16x8 vv0 = *(const bf16x8*)&VsS[fr * 64 + rs0];
        bf16x8 vv1 = *(const bf16x8*)&VsS[fr * 64 + rs1];
        Oa[g][ft] = __builtin_amdgcn_mfma_f32_16x16x32_bf16(vv0, pf0,
                                                            Oa[g][ft], 0, 0, 0);
        Oa[g][ft] = __builtin_amdgcn_mfma_f32_16x16x32_bf16(vv1, pf1,
                                                            Oa[g][ft], 0, 0, 0);
      }
    }
#endif
  };

  // preamble: DMA tile pair (0,1) into dbuf 0
  GLD_LDS16(Kg + (size_t)f0 * HD + sj0 * 8, &Ks[0][0][lds0]);
  GLD_LDS16(Kg + (size_t)f1 * HD + sj1 * 8, &Ks[0][0][lds1]);
  GLD_LDS16(Kg + (size_t)(64 + f0) * HD + sj0 * 8, &Ks[0][1][lds0]);
  GLD_LDS16(Kg + (size_t)(64 + f1) * HD + sj1 * 8, &Ks[0][1][lds1]);
  GLD_LDS16(Vg + (size_t)f0 * S_LEN + sj0 * 8, &Vs[0][0][lds0]);
  GLD_LDS16(Vg + (size_t)f1 * S_LEN + sj1 * 8, &Vs[0][0][lds1]);
  GLD_LDS16(Vg + (size_t)f0 * S_LEN + 64 + sj0 * 8, &Vs[0][1][lds0]);
  GLD_LDS16(Vg + (size_t)f1 * S_LEN + 64 + sj1 * 8, &Vs[0][1][lds1]);

  // strength-reduced DMA source pointers (tile pair (2,3))
  const __bf16* kgp0 = Kg + (size_t)(128 + f0) * HD + sj0 * 8;
  const __bf16* kgp1 = Kg + (size_t)(128 + f1) * HD + sj1 * 8;
  const __bf16* vgp0 = Vg + (size_t)f0 * S_LEN + 128 + sj0 * 8;
  const __bf16* vgp1 = Vg + (size_t)f1 * S_LEN + 128 + sj1 * 8;

  // MB fragments: subtile A = tile 0, subtile B = tile 1
  bf16x8 rMBA[2][2], rMBB[2][2];
  rMBA[0][0] = *(const bf16x8*)MBq0;
  rMBA[0][1] = *(const bf16x8*)(MBq0 + 8);
  rMBA[1][0] = *(const bf16x8*)MBq1;
  rMBA[1][1] = *(const bf16x8*)(MBq1 + 8);
  rMBB[0][0] = *(const bf16x8*)(MBq0 + 4096);
  rMBB[0][1] = *(const bf16x8*)(MBq0 + 4096 + 8);
  rMBB[1][0] = *(const bf16x8*)(MBq1 + 4096);
  rMBB[1][1] = *(const bf16x8*)(MBq1 + 4096 + 8);

  __syncthreads();

#pragma unroll 2
  for (int t = 0; t < 16; ++t) {
    const int cur = t & 1, nxt = cur ^ 1;
    // async DMA of the next tile pair into the inactive dbuf
    if (t < 15) {
      GLD_LDS16(kgp0, &Ks[nxt][0][lds0]);
      GLD_LDS16(kgp1, &Ks[nxt][0][lds1]);
      GLD_LDS16(kgp0 + 64 * HD, &Ks[nxt][1][lds0]);
      GLD_LDS16(kgp1 + 64 * HD, &Ks[nxt][1][lds1]);
      GLD_LDS16(vgp0, &Vs[nxt][0][lds0]);
      GLD_LDS16(vgp1, &Vs[nxt][0][lds1]);
      GLD_LDS16(vgp0 + 64, &Vs[nxt][1][lds0]);
      GLD_LDS16(vgp1 + 64, &Vs[nxt][1][lds1]);
    }
    kgp0 += 128 * HD;
    kgp1 += 128 * HD;
    vgp0 += 128;
    vgp1 += 128;

    // subtile A (tile 2t): JIT-reloads rMBA from tile 2t+2
    subtile(&Ks[cur][0][0], &Vs[cur][0][0], rMBA,
            MBq0 + (size_t)(2 * t + 2) * 4096,
            MBq1 + (size_t)(2 * t + 2) * 4096);
    // subtile B (tile 2t+1): JIT-reloads rMBB from tile 2t+3
    subtile(&Ks[cur][1][0], &Vs[cur][1][0], rMBB,
            MBq0 + (size_t)(2 * t + 3) * 4096,
            MBq1 + (size_t)(2 * t + 3) * 4096);

    // one barrier per PAIR: LDS[cur] reads done; implicit vmcnt(0) completes
    // the next pair's DMAs (issued before ~2x compute).
    __syncthreads();
  }

  // full row sum + normalize + store, per group
#pragma unroll
  for (int g = 0; g < 2; ++g) {
    float lsum = psum[g][0] + psum[g][1] + psum[g][2] + psum[g][3];
    lsum += __shfl_xor(lsum, 16);
    lsum += __shfl_xor(lsum, 32);
    const float invl = 1.0f / lsum;
    __bf16* orow = AOb +
                   (size_t)(b * S_LEN + qt * 128 + g * 64 + w * 16 + c) *
                       DMODEL +
                   h * HD;
#pragma unroll
    for (int ft = 0; ft < 4; ++ft) {
      __bf16 t4[4];
#pragma unroll
      for (int r = 0; r < 4; ++r) t4[r] = (__bf16)(Oa[g][ft][r] * invl);
      *(bf16x4*)(orow + ft * 16 + quad * 4) = *(bf16x4*)t4;
    }
  }
}

// ---------------- Output projection: bf16 MFMA 128x64 tile ----------------
__global__ __launch_bounds__(256) void gemm_out_mfma(
    const __bf16* __restrict__ AOb, const __bf16* __restrict__ Wt2,
    const float* __restrict__ bout, float* __restrict__ Out) {
  __shared__ __align__(16) __bf16 As[128 * 32];
  __shared__ __align__(16) __bf16 Bs[64 * 32];
  const int tid = threadIdx.x;
  const int w = tid >> 6, lane = tid & 63;
  const int c = lane & 15, quad = lane >> 4;
  const int rowBase = blockIdx.y * 128;
  const int colBase = blockIdx.x * 64;

  f32x4 acc[2][4] = {};

  const __bf16* gA0 =
      AOb + (size_t)(rowBase + w * 32 + (lane >> 2)) * 1024 + (lane & 3) * 8;
  const __bf16* gB0 =
      Wt2 + (size_t)(colBase + w * 16 + (lane >> 2)) * 1024 + (lane & 3) * 8;
  __bf16* lA0 = &As[(w * 32) * 32];
  __bf16* lB0 = &Bs[(w * 16) * 32];

  for (int k0 = 0; k0 < 1024; k0 += 32) {
    __syncthreads();
#pragma unroll
    for (int p = 0; p < 2; ++p)
      GLD_LDS16(gA0 + (size_t)p * 16 * 1024 + k0, lA0 + p * 16 * 32);
    GLD_LDS16(gB0 + k0, lB0);
    __syncthreads();

    bf16x8 af[2], bfr[4];
#pragma unroll
    for (int mt = 0; mt < 2; ++mt)
      af[mt] = *(const bf16x8*)&As[(w * 32 + mt * 16 + c) * 32 + quad * 8];
#pragma unroll
    for (int nt = 0; nt < 4; ++nt)
      bfr[nt] = *(const bf16x8*)&Bs[(nt * 16 + c) * 32 + quad * 8];
#pragma unroll
    for (int mt = 0; mt < 2; ++mt)
#pragma unroll
      for (int nt = 0; nt < 4; ++nt)
        acc[mt][nt] = __builtin_amdgcn_mfma_f32_16x16x32_bf16(
            af[mt], bfr[nt], acc[mt][nt], 0, 0, 0);
  }

#pragma unroll
  for (int mt = 0; mt < 2; ++mt) {
    int row0 = rowBase + w * 32 + mt * 16 + quad * 4;
#pragma unroll
    for (int nt = 0; nt < 4; ++nt) {
      int col = colBase + nt * 16 + c;
      float bias = bout[col];
#pragma unroll
      for (int r = 0; r < 4; ++r)
        Out[(size_t)(row0 + r) * 1024 + col] = acc[mt][nt][r] + bias;
    }
  }
}

extern "C" void kernel_launch(void* const* d_in, const int* in_sizes, int n_in,
                              void* d_out, int out_size, void* d_ws,
                              size_t ws_size, hipStream_t stream) {
  const float* x = (const float*)d_in[0];
  const float* attn_mask = (const float*)d_in[1];
  const float* attn_bias = (const float*)d_in[2];
  const float* Wqkv = (const float*)d_in[3];
  const float* bqkv = (const float*)d_in[4];
  const float* Wout = (const float*)d_in[5];
  const float* bout = (const float*)d_in[6];
  float* out = (float*)d_out;

  __bf16* base = (__bf16*)d_ws;
  __bf16* Xb = base;                  // [0, 4M)
  __bf16* AOb = base;                 // aliases Xb (disjoint lifetime)
  __bf16* Wt = base + 4194304;        // [4M, 7M)
  __bf16* Qb = base + 8388608;        // [8M, 12M)
  __bf16* Kb = base + 12582912;       // [12M, 16M)
  __bf16* Vtb = base + 16777216;      // [16M, 20M)
  __bf16* MB = base + 20971520;       // [20M, 28M)
  __bf16* Wt2 = base + 29360128;      // [28M, 29M)

  preprocess<<<6144, 256, 0, stream>>>(x, attn_mask, attn_bias, Wqkv, Wout,
                                       Xb, Wt, Wt2, MB);
  gemm_qkv_mfma<<<dim3(24, 32), 256, 0, stream>>>(Xb, Wt, bqkv, Qb, Kb, Vtb);
  attn_mfma<<<dim3(16, NH, 2), 256, 0, stream>>>(Qb, Kb, Vtb, MB, AOb);
  gemm_out_mfma<<<dim3(16, 32), 256, 0, stream>>>(AOb, Wt2, bout, out);
}

// Round 9
// 252.489 us; speedup vs baseline: 1.1028x; 1.0240x over previous
//
#include <hip/hip_runtime.h>
#include <hip/hip_bf16.h>

// Problem: B=2, S=2048, D=1024, H=16, hd=64
// ws layout (58 MiB, bf16-element offsets from d_ws):
//   Xb  [0, 4M)        8 MiB  (x bf16)             -- dead after gemm_qkv
//   AOb [0, 4M)        8 MiB  (attn out bf16)      -- aliases Xb
//   Wt  [4M, 7M)       6 MiB  (Wqkv^T bf16)
//   Qb  [8M, 12M)      8 MiB
//   Kb  [12M, 16M)     8 MiB
//   Vtb [16M, 20M)     8 MiB  (V^T [B,H,hd,S])
//   MB  [20M, 28M)    16 MiB  (mask+bias, S^T-fragment order, *log2e)
//   Wt2 [28M+..]       2 MiB  (Wout^T bf16)
//
// R16: R8 split the evidence cleanly: (a) attn's JIT rMB reload cost ~4us
// vs R5's batched nMB dbuf -> RESTORE R5 attn verbatim (70.5us proven);
// (b) Q/K LDS-transpose epilogue REGRESSED gemm_qkv ~7us (Q/K scatter was
// already 32B-granular; the LDS round-trip added cost) -> revert to R7
// epilogue (scatter Q/K + LDS-transpose V only). NEW: both GEMM K-loops
// get attn's proven single-barrier LDS double-buffer (was 2 barriers/step
// with zero DMA cover -> ~500cy load latency exposed every step).

#define S_LEN 2048
#define DMODEL 1024
#define NH 16
#define HD 64

typedef __bf16 bf16x8 __attribute__((ext_vector_type(8)));
typedef __bf16 bf16x4 __attribute__((ext_vector_type(4)));
typedef __bf16 bf16x2v __attribute__((ext_vector_type(2)));
typedef float f32x4 __attribute__((ext_vector_type(4)));
typedef short s16x4 __attribute__((ext_vector_type(4)));

#define GLD_LDS16(g, l)                                              \
  __builtin_amdgcn_global_load_lds(                                  \
      (const __attribute__((address_space(1))) unsigned int*)(g),    \
      (__attribute__((address_space(3))) unsigned int*)(l), 16, 0, 0)

#if __has_builtin(__builtin_amdgcn_mfma_f32_16x16x16bf16_1k)
#define HAVE_MFMA_16x16x16_BF16 1
#else
#define HAVE_MFMA_16x16x16_BF16 0
#endif

#if __has_builtin(__builtin_amdgcn_exp2f)
#define EXP2F(x) __builtin_amdgcn_exp2f(x)
#else
static __device__ __forceinline__ float EXP2F(float x) {
  float r;
  asm volatile("v_exp_f32 %0, %1" : "=v"(r) : "v"(x));
  return r;
}
#endif

#define LOG2E 1.44269504f

// ---------- fused preprocess: cvt_x | cvt_wt(Wqkv) | cvt_wt(Wout) | mb_fuse
// blockIdx.x ranges: [0,4096) cvt_x, [4096,4864) Wqkv^T, [4864,5120) Wout^T,
// [5120,6144) mb_fuse (BOTH b per block; mask read once).
__global__ __launch_bounds__(256) void preprocess(
    const float* __restrict__ x, const float* __restrict__ mask,
    const float* __restrict__ bias, const float* __restrict__ Wqkv,
    const float* __restrict__ Wout, __bf16* __restrict__ Xb,
    __bf16* __restrict__ Wt, __bf16* __restrict__ Wt2,
    __bf16* __restrict__ MB) {
  __shared__ __align__(16) char smem[64 * 65 * 4];
  const int bid = blockIdx.x;
  const int tid = threadIdx.x;

  if (bid < 4096) {
    // ---- cvt_x: fp32 -> bf16 ----
    int i = bid * 256 + tid;
    float4 v = ((const float4*)x)[i];
    bf16x4 o = {(__bf16)v.x, (__bf16)v.y, (__bf16)v.z, (__bf16)v.w};
    *(bf16x4*)&Xb[(size_t)i * 4] = o;
  } else if (bid < 5120) {
    // ---- cvt_wt: W[1024,ncols] -> Wt[ncols,1024] bf16 transpose ----
    const float* W;
    __bf16* Wo;
    int ncols, n0, k0;
    if (bid < 4864) {
      int id = bid - 4096;
      W = Wqkv; Wo = Wt; ncols = 3072;
      n0 = (id % 48) * 64; k0 = (id / 48) * 64;
    } else {
      int id = bid - 4864;
      W = Wout; Wo = Wt2; ncols = 1024;
      n0 = (id & 15) * 64; k0 = (id >> 4) * 64;
    }
    float(*tile)[65] = (float(*)[65])smem;
    {
      int c = tid & 63, r4 = tid >> 6;
#pragma unroll
      for (int p = 0; p < 16; ++p) {
        int r = r4 + p * 4;
        tile[r][c] = W[(size_t)(k0 + r) * ncols + n0 + c];
      }
    }
    __syncthreads();
    {
      int cc = (tid & 31) * 2, r8 = tid >> 5;
#pragma unroll
      for (int p = 0; p < 8; ++p) {
        int rr = r8 + p * 8;
        bf16x2v o = {(__bf16)tile[cc][rr], (__bf16)tile[cc + 1][rr]};
        *(bf16x2v*)&Wo[(size_t)(n0 + rr) * 1024 + k0 + cc] = o;
      }
    }
  } else {
    // ---- mb_fuse: (mask+bias)*log2e, BOTH b, mask loaded once ----
    int id = bid - 5120;  // [0,1024)
    const int kt = id & 31, qt = id >> 5;
    __bf16(*sm)[68] = (__bf16(*)[68])smem;
    const int r0 = tid >> 4;        // 0..15
    const int cc = (tid & 15) * 4;  // 0,4,..,60
    const float* mrow = mask + (size_t)(qt * 64) * S_LEN + kt * 64;
    float4 mld[4];
#pragma unroll
    for (int p = 0; p < 4; ++p)
      mld[p] = *(const float4*)(mrow + (size_t)(r0 + p * 16) * S_LEN + cc);
    const int w = tid >> 6, lane = tid & 63;
    const int quad = lane >> 4, cl = lane & 15;
    for (int b = 0; b < 2; ++b) {
      const float* brow =
          bias + ((size_t)b * S_LEN + qt * 64) * S_LEN + kt * 64;
#pragma unroll
      for (int p = 0; p < 4; ++p) {
        int r = r0 + p * 16;
        float4 a = *(const float4*)(brow + (size_t)r * S_LEN + cc);
        sm[r][cc + 0] = (__bf16)((mld[p].x + a.x) * LOG2E);
        sm[r][cc + 1] = (__bf16)((mld[p].y + a.y) * LOG2E);
        sm[r][cc + 2] = (__bf16)((mld[p].z + a.z) * LOG2E);
        sm[r][cc + 3] = (__bf16)((mld[p].w + a.w) * LOG2E);
      }
      __syncthreads();
      __bf16 vals[16];
#pragma unroll
      for (int ct = 0; ct < 4; ++ct) {
        bf16x4 v = *(const bf16x4*)&sm[w * 16 + cl][ct * 16 + quad * 4];
        *(bf16x4*)&vals[ct * 4] = v;
      }
      __bf16* op = MB + (((size_t)(b * 32 + qt) * 32 + kt) * 4096) +
                   (w * 64 + lane) * 16;
      *(bf16x8*)op = *(bf16x8*)&vals[0];
      *(bf16x8*)(op + 8) = *(bf16x8*)&vals[8];
      __syncthreads();  // sm reuse for next b
    }
  }
}

// ---------------- QKV projection: bf16 MFMA 128x128 tile ----------------
// R16: single-barrier LDS double-buffered staging (attn's proven pattern):
// prefetch K-step k+1 into the alternate buffer, compute k, ONE barrier
// whose implicit vmcnt(0) has a full iteration of compute cover.
// Epilogue: Q/K direct scatter (32B-granular, was fine); V via per-wave
// LDS transpose -> coalesced 128B stores (R6's win, kept).
__global__ __launch_bounds__(256) void gemm_qkv_mfma(
    const __bf16* __restrict__ Xb, const __bf16* __restrict__ Wt,
    const float* __restrict__ bqkv, __bf16* __restrict__ Qb,
    __bf16* __restrict__ Kb, __bf16* __restrict__ Vtb) {
  // union: As[2]+Bs[2] staging (32KB) during k-loop; 4x 64x72 bf16
  // transpose tiles (36,864B) during the V epilogue.
  __shared__ __align__(16) __bf16 shm[4 * 64 * 72];
  __bf16* As = shm;         // [2][128*32]
  __bf16* Bs = shm + 8192;  // [2][128*32]
  const int tid = threadIdx.x;
  const int w = tid >> 6, lane = tid & 63;
  const int c = lane & 15, quad = lane >> 4;
  const int wm = w >> 1, wn = w & 1;
  const int rowBase = blockIdx.y * 128;
  const int colBase = blockIdx.x * 128;

  f32x4 acc[4][4] = {};

  const __bf16* gA0 =
      Xb + (size_t)(rowBase + w * 32 + (lane >> 2)) * 1024 + (lane & 3) * 8;
  const __bf16* gB0 =
      Wt + (size_t)(colBase + w * 32 + (lane >> 2)) * 1024 + (lane & 3) * 8;
  const int lOff = (w * 32) * 32;

  // preamble: stage k0=0 into buffer 0
#pragma unroll
  for (int p = 0; p < 2; ++p) {
    GLD_LDS16(gA0 + (size_t)p * 16 * 1024, As + lOff + p * 16 * 32);
    GLD_LDS16(gB0 + (size_t)p * 16 * 1024, Bs + lOff + p * 16 * 32);
  }
  __syncthreads();

#pragma unroll 2
  for (int k0 = 0; k0 < 1024; k0 += 32) {
    const int cur = (k0 >> 5) & 1, nxt = cur ^ 1;
    // prefetch next K-step into the inactive buffer (full-iter cover)
    if (k0 < 992) {
#pragma unroll
      for (int p = 0; p < 2; ++p) {
        GLD_LDS16(gA0 + (size_t)p * 16 * 1024 + k0 + 32,
                  As + nxt * 4096 + lOff + p * 16 * 32);
        GLD_LDS16(gB0 + (size_t)p * 16 * 1024 + k0 + 32,
                  Bs + nxt * 4096 + lOff + p * 16 * 32);
      }
    }

    bf16x8 af[4], bfr[4];
#pragma unroll
    for (int mt = 0; mt < 4; ++mt)
      af[mt] = *(const bf16x8*)&As[cur * 4096 +
                                   (wm * 64 + mt * 16 + c) * 32 + quad * 8];
#pragma unroll
    for (int nt = 0; nt < 4; ++nt)
      bfr[nt] = *(const bf16x8*)&Bs[cur * 4096 +
                                    (wn * 64 + nt * 16 + c) * 32 + quad * 8];
#pragma unroll
    for (int mt = 0; mt < 4; ++mt)
#pragma unroll
      for (int nt = 0; nt < 4; ++nt)
        acc[mt][nt] = __builtin_amdgcn_mfma_f32_16x16x32_bf16(
            af[mt], bfr[nt], acc[mt][nt], 0, 0, 0);

    // one barrier per K-step: LDS[cur] reads done; implicit vmcnt(0)
    // completes the prefetch DMAs (issued before the full MFMA body).
    __syncthreads();
  }

  if (colBase < 2048) {
    // ---- Q/K epilogue (scatter; 32B-contiguous per quad) ----
#pragma unroll
    for (int mt = 0; mt < 4; ++mt) {
      int row0 = rowBase + wm * 64 + mt * 16 + quad * 4;
#pragma unroll
      for (int nt = 0; nt < 4; ++nt) {
        int col = colBase + wn * 64 + nt * 16 + c;
        float bias = bqkv[col];
        int three = col >> 10;  // 0 or 1
        int h = (col & 1023) >> 6;
        int d = col & 63;
#pragma unroll
        for (int r = 0; r < 4; ++r) {
          int rr = row0 + r;
          int bb = rr >> 11, s = rr & 2047;
          float val = acc[mt][nt][r] + bias;
          size_t ho = (size_t)(bb * NH + h);
          if (three == 0)
            Qb[(ho * S_LEN + s) * HD + d] = (__bf16)val;
          else
            Kb[(ho * S_LEN + s) * HD + d] = (__bf16)val;
        }
      }
    }
  } else {
    // ---- V epilogue: per-wave LDS transpose, coalesced V^T stores ----
    // (final loop barrier already ensures all ds_reads of shm are done)
    __bf16* Tt = shm + w * (64 * 72);  // [d_local][s_local], pad 72
    const int cols0 = colBase + wn * 64;
    const int rows0 = rowBase + wm * 64;
    const int hq = (cols0 & 1023) >> 6;
    const int bb = rows0 >> 11;
    const int sBase = rows0 & 2047;
#pragma unroll
    for (int nt = 0; nt < 4; ++nt) {
      float bias = bqkv[cols0 + nt * 16 + c];
#pragma unroll
      for (int mt = 0; mt < 4; ++mt) {
        __bf16 t4[4];
#pragma unroll
        for (int r = 0; r < 4; ++r) t4[r] = (__bf16)(acc[mt][nt][r] + bias);
        *(bf16x4*)&Tt[(nt * 16 + c) * 72 + mt * 16 + quad * 4] =
            *(bf16x4*)t4;
      }
    }
    __syncthreads();
    const size_t vbase = ((size_t)(bb * NH + hq) * HD) * S_LEN;
    const int s0 = (lane & 7) * 8;
    const int dl0 = lane >> 3;  // 0..7
#pragma unroll
    for (int dt = 0; dt < 8; ++dt) {
      int dl = dt * 8 + dl0;
      bf16x8 v = *(const bf16x8*)&Tt[dl * 72 + s0];
      *(bf16x8*)&Vtb[vbase + (size_t)dl * S_LEN + sBase + s0] = v;
    }
  }
}

// ------- MFMA flash attention: S^T dataflow, QBLK=128, 2 subtiles/barrier
// R5 structure VERBATIM (proven 70.5us): TWO 64-key subtiles per barrier
// region (KVBLK=128 effective, 64KB LDS), plain __syncthreads, unroll-2,
// batched nMB register double-buffer prefetched between subtiles.
__global__ __launch_bounds__(256) void attn_mfma(
    const __bf16* __restrict__ Qb, const __bf16* __restrict__ Kb,
    const __bf16* __restrict__ Vtb, const __bf16* __restrict__ MB,
    __bf16* __restrict__ AOb) {
  const int qt = blockIdx.x, h = blockIdx.y, b = blockIdx.z;
  const int tid = threadIdx.x;
  const int w = tid >> 6;
  const int lane = tid & 63;
  const int c = lane & 15;
  const int quad = lane >> 4;

  __shared__ __align__(16) __bf16 Ks[2][2][64 * 64];  // [dbuf][subtile]
  __shared__ __align__(16) __bf16 Vs[2][2][64 * 64];  // [feat][key], swizzled
#if !HAVE_MFMA_16x16x16_BF16
  __shared__ __align__(16) __bf16 P2[4][16 * 72];
#endif

  const size_t headoff = (size_t)(b * NH + h) * S_LEN * HD;
  const __bf16* Qg = Qb + headoff + (size_t)(qt * 128) * HD;
  const __bf16* Kg = Kb + headoff;
  const __bf16* Vg = Vtb + headoff;  // [hd][S]
  const __bf16* MBq0 =
      MB + ((size_t)(b * 32 + qt * 2 + 0) * 32) * 4096 + (w * 64 + lane) * 16;
  const __bf16* MBq1 =
      MB + ((size_t)(b * 32 + qt * 2 + 1) * 32) * 4096 + (w * 64 + lane) * 16;

  // staging geometry (chunk ch = p*256+tid -> row f, col-chunk j, swizzled)
  const int f0 = tid >> 3, f1 = f0 + 32;
  const int j = tid & 7;
  const int sj0 = j ^ (f0 & 7);
  const int sj1 = j ^ (f1 & 7);
  const int lds0 = tid * 8;
  const int lds1 = (256 + tid) * 8;

  // Q fragments: lane holds Q[qrow=g*64+w*16+c][d=quad*8+j] (loop-invariant)
  bf16x8 qa[2][2];
#pragma unroll
  for (int g = 0; g < 2; ++g) {
    qa[g][0] = *(const bf16x8*)(Qg + (g * 64 + w * 16 + c) * HD + quad * 8);
    qa[g][1] =
        *(const bf16x8*)(Qg + (g * 64 + w * 16 + c) * HD + quad * 8 + 32);
  }

  // swizzled b128 read offsets (row&7 == c&7)
  const int rs0 = (quad ^ (c & 7)) * 8;
  const int rs1 = ((quad + 4) ^ (c & 7)) * 8;

  f32x4 Oa[2][4] = {};  // O^T[d=ft*16+quad*4+r][qrow=c] per group
  f32x4 psum[2] = {};   // packed row-partial sums of p per group

  const float c1 = 0.125f * LOG2E;  // 1/sqrt(hd) * log2(e)

  // one-subtile compute: QK -> softmax (with rmb) -> PV, accumulate Oa/psum
  auto subtile = [&](const __bf16* KsS, const __bf16* VsS,
                     bf16x8(&rmb)[2][2]) {
    bf16x8 kf0[4], kf1[4];
#pragma unroll
    for (int ct = 0; ct < 4; ++ct) {
      kf0[ct] = *(const bf16x8*)&KsS[(ct * 16 + c) * 64 + rs0];
      kf1[ct] = *(const bf16x8*)&KsS[(ct * 16 + c) * 64 + rs1];
    }
    f32x4 sv[2][4];
    __builtin_amdgcn_s_setprio(1);
#pragma unroll
    for (int g = 0; g < 2; ++g)
#pragma unroll
      for (int ct = 0; ct < 4; ++ct) {
        f32x4 a = {};
        a = __builtin_amdgcn_mfma_f32_16x16x32_bf16(kf0[ct], qa[g][0], a, 0,
                                                    0, 0);
        a = __builtin_amdgcn_mfma_f32_16x16x32_bf16(kf1[ct], qa[g][1], a, 0,
                                                    0, 0);
        sv[g][ct] = a;
      }
    __builtin_amdgcn_s_setprio(0);

#if HAVE_MFMA_16x16x16_BF16
    s16x4 vf[4][4];
#pragma unroll
    for (int ft = 0; ft < 4; ++ft) {
      const int fr = ft * 16 + c;
#pragma unroll
      for (int ct = 0; ct < 4; ++ct) {
        const int chunk = ((ct * 2 + (quad >> 1)) ^ (fr & 7)) * 8 +
                          (quad & 1) * 4;
        vf[ft][ct] = *(const s16x4*)&VsS[fr * 64 + chunk];
      }
    }
#endif

    s16x4 pb[2][4];
#pragma unroll
    for (int g = 0; g < 2; ++g)
#pragma unroll
      for (int ct = 0; ct < 4; ++ct) {
        f32x4 pv;
#pragma unroll
        for (int r = 0; r < 4; ++r) {
          float mb = (ct < 2) ? (float)rmb[g][0][ct * 4 + r]
                              : (float)rmb[g][1][(ct - 2) * 4 + r];
          pv[r] = EXP2F(sv[g][ct][r] * c1 + mb);
        }
        psum[g] += pv;
        __bf16 t4[4];
#pragma unroll
        for (int r = 0; r < 4; ++r) t4[r] = (__bf16)pv[r];
        pb[g][ct] = *(s16x4*)t4;
      }

#if HAVE_MFMA_16x16x16_BF16
    __builtin_amdgcn_s_setprio(1);
#pragma unroll
    for (int g = 0; g < 2; ++g)
#pragma unroll
      for (int ft = 0; ft < 4; ++ft)
#pragma unroll
        for (int ct = 0; ct < 4; ++ct)
          Oa[g][ft] = __builtin_amdgcn_mfma_f32_16x16x16bf16_1k(
              vf[ft][ct], pb[g][ct], Oa[g][ft], 0, 0, 0);
    __builtin_amdgcn_s_setprio(0);
#else
#pragma unroll
    for (int g = 0; g < 2; ++g) {
#pragma unroll
      for (int ct = 0; ct < 4; ++ct)
        *(bf16x4*)&P2[w][c * 72 + ct * 16 + quad * 4] = *(bf16x4*)&pb[g][ct];
      bf16x8 pf0 = *(const bf16x8*)&P2[w][c * 72 + quad * 8];
      bf16x8 pf1 = *(const bf16x8*)&P2[w][c * 72 + 32 + quad * 8];
#pragma unroll
      for (int ft = 0; ft < 4; ++ft) {
        const int fr = ft * 16 + c;
        bf16x8 vv0 = *(const bf16x8*)&VsS[fr * 64 + rs0];
        bf16x8 vv1 = *(const bf16x8*)&VsS[fr * 64 + rs1];
        Oa[g][ft] = __builtin_amdgcn_mfma_f32_16x16x32_bf16(vv0, pf0,
                                                            Oa[g][ft], 0, 0, 0);
        Oa[g][ft] = __builtin_amdgcn_mfma_f32_16x16x32_bf16(vv1, pf1,
                                                            Oa[g][ft], 0, 0, 0);
      }
    }
#endif
  };

  // preamble: DMA tile pair (0,1) into dbuf 0
  GLD_LDS16(Kg + (size_t)f0 * HD + sj0 * 8, &Ks[0][0][lds0]);
  GLD_LDS16(Kg + (size_t)f1 * HD + sj1 * 8, &Ks[0][0][lds1]);
  GLD_LDS16(Kg + (size_t)(64 + f0) * HD + sj0 * 8, &Ks[0][1][lds0]);
  GLD_LDS16(Kg + (size_t)(64 + f1) * HD + sj1 * 8, &Ks[0][1][lds1]);
  GLD_LDS16(Vg + (size_t)f0 * S_LEN + sj0 * 8, &Vs[0][0][lds0]);
  GLD_LDS16(Vg + (size_t)f1 * S_LEN + sj1 * 8, &Vs[0][0][lds1]);
  GLD_LDS16(Vg + (size_t)f0 * S_LEN + 64 + sj0 * 8, &Vs[0][1][lds0]);
  GLD_LDS16(Vg + (size_t)f1 * S_LEN + 64 + sj1 * 8, &Vs[0][1][lds1]);

  // strength-reduced DMA source pointers (tile pair (2,3))
  const __bf16* kgp0 = Kg + (size_t)(128 + f0) * HD + sj0 * 8;
  const __bf16* kgp1 = Kg + (size_t)(128 + f1) * HD + sj1 * 8;
  const __bf16* vgp0 = Vg + (size_t)f0 * S_LEN + 128 + sj0 * 8;
  const __bf16* vgp1 = Vg + (size_t)f1 * S_LEN + 128 + sj1 * 8;

  // MB fragments: subtile A = tile 0, subtile B = tile 1
  bf16x8 rMBA[2][2], rMBB[2][2];
  rMBA[0][0] = *(const bf16x8*)MBq0;
  rMBA[0][1] = *(const bf16x8*)(MBq0 + 8);
  rMBA[1][0] = *(const bf16x8*)MBq1;
  rMBA[1][1] = *(const bf16x8*)(MBq1 + 8);
  rMBB[0][0] = *(const bf16x8*)(MBq0 + 4096);
  rMBB[0][1] = *(const bf16x8*)(MBq0 + 4096 + 8);
  rMBB[1][0] = *(const bf16x8*)(MBq1 + 4096);
  rMBB[1][1] = *(const bf16x8*)(MBq1 + 4096 + 8);

  __syncthreads();

#pragma unroll 2
  for (int t = 0; t < 16; ++t) {
    const int cur = t & 1, nxt = cur ^ 1;
    // async DMA of the next tile pair into the inactive dbuf
    if (t < 15) {
      GLD_LDS16(kgp0, &Ks[nxt][0][lds0]);
      GLD_LDS16(kgp1, &Ks[nxt][0][lds1]);
      GLD_LDS16(kgp0 + 64 * HD, &Ks[nxt][1][lds0]);
      GLD_LDS16(kgp1 + 64 * HD, &Ks[nxt][1][lds1]);
      GLD_LDS16(vgp0, &Vs[nxt][0][lds0]);
      GLD_LDS16(vgp1, &Vs[nxt][0][lds1]);
      GLD_LDS16(vgp0 + 64, &Vs[nxt][1][lds0]);
      GLD_LDS16(vgp1 + 64, &Vs[nxt][1][lds1]);
    }
    kgp0 += 128 * HD;
    kgp1 += 128 * HD;
    vgp0 += 128;
    vgp1 += 128;

    // ---- subtile A (tile 2t) ----
    subtile(&Ks[cur][0][0], &Vs[cur][0][0], rMBA);

    // next iteration's MB fragments (tiles 2t+2, 2t+3); issued between
    // subtiles so HBM/L2 latency hides under subtile-B compute. Over-read
    // on the final iteration lands in the following MB tiles / Wt2 region
    // (allocated, read-only -- safe).
    bf16x8 nMBA[2][2], nMBB[2][2];
    {
      const __bf16* m0 = MBq0 + (size_t)(2 * t + 2) * 4096;
      const __bf16* m1 = MBq1 + (size_t)(2 * t + 2) * 4096;
      nMBA[0][0] = *(const bf16x8*)m0;
      nMBA[0][1] = *(const bf16x8*)(m0 + 8);
      nMBA[1][0] = *(const bf16x8*)m1;
      nMBA[1][1] = *(const bf16x8*)(m1 + 8);
      nMBB[0][0] = *(const bf16x8*)(m0 + 4096);
      nMBB[0][1] = *(const bf16x8*)(m0 + 4096 + 8);
      nMBB[1][0] = *(const bf16x8*)(m1 + 4096);
      nMBB[1][1] = *(const bf16x8*)(m1 + 4096 + 8);
    }

    // ---- subtile B (tile 2t+1) ----
    subtile(&Ks[cur][1][0], &Vs[cur][1][0], rMBB);

#pragma unroll
    for (int g = 0; g < 2; ++g) {
      rMBA[g][0] = nMBA[g][0];
      rMBA[g][1] = nMBA[g][1];
      rMBB[g][0] = nMBB[g][0];
      rMBB[g][1] = nMBB[g][1];
    }

    // one barrier per PAIR: LDS[cur] reads done; implicit vmcnt(0) completes
    // the next pair's DMAs (issued before ~2x compute).
    __syncthreads();
  }

  // full row sum + normalize + store, per group
#pragma unroll
  for (int g = 0; g < 2; ++g) {
    float lsum = psum[g][0] + psum[g][1] + psum[g][2] + psum[g][3];
    lsum += __shfl_xor(lsum, 16);
    lsum += __shfl_xor(lsum, 32);
    const float invl = 1.0f / lsum;
    __bf16* orow = AOb +
                   (size_t)(b * S_LEN + qt * 128 + g * 64 + w * 16 + c) *
                       DMODEL +
                   h * HD;
#pragma unroll
    for (int ft = 0; ft < 4; ++ft) {
      __bf16 t4[4];
#pragma unroll
      for (int r = 0; r < 4; ++r) t4[r] = (__bf16)(Oa[g][ft][r] * invl);
      *(bf16x4*)(orow + ft * 16 + quad * 4) = *(bf16x4*)t4;
    }
  }
}

// ---------------- Output projection: bf16 MFMA 128x64 tile ----------------
// R16: single-barrier LDS double-buffered staging (same pattern as qkv).
__global__ __launch_bounds__(256) void gemm_out_mfma(
    const __bf16* __restrict__ AOb, const __bf16* __restrict__ Wt2,
    const float* __restrict__ bout, float* __restrict__ Out) {
  __shared__ __align__(16) __bf16 As[2][128 * 32];
  __shared__ __align__(16) __bf16 Bs[2][64 * 32];
  const int tid = threadIdx.x;
  const int w = tid >> 6, lane = tid & 63;
  const int c = lane & 15, quad = lane >> 4;
  const int rowBase = blockIdx.y * 128;
  const int colBase = blockIdx.x * 64;

  f32x4 acc[2][4] = {};

  const __bf16* gA0 =
      AOb + (size_t)(rowBase + w * 32 + (lane >> 2)) * 1024 + (lane & 3) * 8;
  const __bf16* gB0 =
      Wt2 + (size_t)(colBase + w * 16 + (lane >> 2)) * 1024 + (lane & 3) * 8;
  const int lA = (w * 32) * 32;
  const int lB = (w * 16) * 32;

  // preamble: stage k0=0 into buffer 0
#pragma unroll
  for (int p = 0; p < 2; ++p)
    GLD_LDS16(gA0 + (size_t)p * 16 * 1024, &As[0][lA + p * 16 * 32]);
  GLD_LDS16(gB0, &Bs[0][lB]);
  __syncthreads();

#pragma unroll 2
  for (int k0 = 0; k0 < 1024; k0 += 32) {
    const int cur = (k0 >> 5) & 1, nxt = cur ^ 1;
    if (k0 < 992) {
#pragma unroll
      for (int p = 0; p < 2; ++p)
        GLD_LDS16(gA0 + (size_t)p * 16 * 1024 + k0 + 32,
                  &As[nxt][lA + p * 16 * 32]);
      GLD_LDS16(gB0 + k0 + 32, &Bs[nxt][lB]);
    }

    bf16x8 af[2], bfr[4];
#pragma unroll
    for (int mt = 0; mt < 2; ++mt)
      af[mt] =
          *(const bf16x8*)&As[cur][(w * 32 + mt * 16 + c) * 32 + quad * 8];
#pragma unroll
    for (int nt = 0; nt < 4; ++nt)
      bfr[nt] = *(const bf16x8*)&Bs[cur][(nt * 16 + c) * 32 + quad * 8];
#pragma unroll
    for (int mt = 0; mt < 2; ++mt)
#pragma unroll
      for (int nt = 0; nt < 4; ++nt)
        acc[mt][nt] = __builtin_amdgcn_mfma_f32_16x16x32_bf16(
            af[mt], bfr[nt], acc[mt][nt], 0, 0, 0);

    __syncthreads();
  }

#pragma unroll
  for (int mt = 0; mt < 2; ++mt) {
    int row0 = rowBase + w * 32 + mt * 16 + quad * 4;
#pragma unroll
    for (int nt = 0; nt < 4; ++nt) {
      int col = colBase + nt * 16 + c;
      float bias = bout[col];
#pragma unroll
      for (int r = 0; r < 4; ++r)
        Out[(size_t)(row0 + r) * 1024 + col] = acc[mt][nt][r] + bias;
    }
  }
}

extern "C" void kernel_launch(void* const* d_in, const int* in_sizes, int n_in,
                              void* d_out, int out_size, void* d_ws,
                              size_t ws_size, hipStream_t stream) {
  const float* x = (const float*)d_in[0];
  const float* attn_mask = (const float*)d_in[1];
  const float* attn_bias = (const float*)d_in[2];
  const float* Wqkv = (const float*)d_in[3];
  const float* bqkv = (const float*)d_in[4];
  const float* Wout = (const float*)d_in[5];
  const float* bout = (const float*)d_in[6];
  float* out = (float*)d_out;

  __bf16* base = (__bf16*)d_ws;
  __bf16* Xb = base;                  // [0, 4M)
  __bf16* AOb = base;                 // aliases Xb (disjoint lifetime)
  __bf16* Wt = base + 4194304;        // [4M, 7M)
  __bf16* Qb = base + 8388608;        // [8M, 12M)
  __bf16* Kb = base + 12582912;       // [12M, 16M)
  __bf16* Vtb = base + 16777216;      // [16M, 20M)
  __bf16* MB = base + 20971520;       // [20M, 28M)
  __bf16* Wt2 = base + 29360128;      // [28M, 29M)

  preprocess<<<6144, 256, 0, stream>>>(x, attn_mask, attn_bias, Wqkv, Wout,
                                       Xb, Wt, Wt2, MB);
  gemm_qkv_mfma<<<dim3(24, 32), 256, 0, stream>>>(Xb, Wt, bqkv, Qb, Kb, Vtb);
  attn_mfma<<<dim3(16, NH, 2), 256, 0, stream>>>(Qb, Kb, Vtb, MB, AOb);
  gemm_out_mfma<<<dim3(16, 32), 256, 0, stream>>>(AOb, Wt2, bout, out);
}

// Round 10
// 250.796 us; speedup vs baseline: 1.1103x; 1.0067x over previous
//
#include <hip/hip_runtime.h>
#include <hip/hip_bf16.h>

// Problem: B=2, S=2048, D=1024, H=16, hd=64
// ws layout (58 MiB, bf16-element offsets from d_ws):
//   Xb  [0, 4M)        8 MiB  (x bf16)             -- dead after gemm_qkv
//   AOb [0, 4M)        8 MiB  (attn out bf16)      -- aliases Xb
//   Wt  [4M, 7M)       6 MiB  (Wqkv^T bf16)
//   Qb  [8M, 12M)      8 MiB
//   Kb  [12M, 16M)     8 MiB
//   Vtb [16M, 20M)     8 MiB  (V^T [B,H,hd,S])
//   MB  [20M, 28M)    16 MiB  (mask+bias, S^T-fragment order, *log2e)
//   Wt2 [28M+..]       2 MiB  (Wout^T bf16)
//
// R17: R9 landed (252.5; attn 72.3, non-attn ~180). This round: T1
// XCD-aware chunked swizzle on all three MFMA kernels (each has strong
// inter-wg panel reuse the default round-robin dispatch destroys):
//   attn: 4 consecutive heads/XCD -> K/V (2MB) L2-resident; shortens the
//         K/V DMA latency chain the barrier drains on.
//   gemm_qkv: 4 A-panels/XCD (1MB L2-resident) instead of all 32 (thrash).
//   gemm_out: Wt2 (2MB) fully L2-resident per XCD.
// Plus gemm_out BK=64 pair-processing (grid-limited at 2 wg/CU, so the
// 24->48KB LDS growth is free; barriers 32->16 with 2x DMA cover).

#define S_LEN 2048
#define DMODEL 1024
#define NH 16
#define HD 64

typedef __bf16 bf16x8 __attribute__((ext_vector_type(8)));
typedef __bf16 bf16x4 __attribute__((ext_vector_type(4)));
typedef __bf16 bf16x2v __attribute__((ext_vector_type(2)));
typedef float f32x4 __attribute__((ext_vector_type(4)));
typedef short s16x4 __attribute__((ext_vector_type(4)));

#define GLD_LDS16(g, l)                                              \
  __builtin_amdgcn_global_load_lds(                                  \
      (const __attribute__((address_space(1))) unsigned int*)(g),    \
      (__attribute__((address_space(3))) unsigned int*)(l), 16, 0, 0)

#if __has_builtin(__builtin_amdgcn_mfma_f32_16x16x16bf16_1k)
#define HAVE_MFMA_16x16x16_BF16 1
#else
#define HAVE_MFMA_16x16x16_BF16 0
#endif

#if __has_builtin(__builtin_amdgcn_exp2f)
#define EXP2F(x) __builtin_amdgcn_exp2f(x)
#else
static __device__ __forceinline__ float EXP2F(float x) {
  float r;
  asm volatile("v_exp_f32 %0, %1" : "=v"(r) : "v"(x));
  return r;
}
#endif

#define LOG2E 1.44269504f

// ---------- fused preprocess: cvt_x | cvt_wt(Wqkv) | cvt_wt(Wout) | mb_fuse
// blockIdx.x ranges: [0,4096) cvt_x, [4096,4864) Wqkv^T, [4864,5120) Wout^T,
// [5120,6144) mb_fuse (BOTH b per block; mask read once).
__global__ __launch_bounds__(256) void preprocess(
    const float* __restrict__ x, const float* __restrict__ mask,
    const float* __restrict__ bias, const float* __restrict__ Wqkv,
    const float* __restrict__ Wout, __bf16* __restrict__ Xb,
    __bf16* __restrict__ Wt, __bf16* __restrict__ Wt2,
    __bf16* __restrict__ MB) {
  __shared__ __align__(16) char smem[64 * 65 * 4];
  const int bid = blockIdx.x;
  const int tid = threadIdx.x;

  if (bid < 4096) {
    // ---- cvt_x: fp32 -> bf16 ----
    int i = bid * 256 + tid;
    float4 v = ((const float4*)x)[i];
    bf16x4 o = {(__bf16)v.x, (__bf16)v.y, (__bf16)v.z, (__bf16)v.w};
    *(bf16x4*)&Xb[(size_t)i * 4] = o;
  } else if (bid < 5120) {
    // ---- cvt_wt: W[1024,ncols] -> Wt[ncols,1024] bf16 transpose ----
    const float* W;
    __bf16* Wo;
    int ncols, n0, k0;
    if (bid < 4864) {
      int id = bid - 4096;
      W = Wqkv; Wo = Wt; ncols = 3072;
      n0 = (id % 48) * 64; k0 = (id / 48) * 64;
    } else {
      int id = bid - 4864;
      W = Wout; Wo = Wt2; ncols = 1024;
      n0 = (id & 15) * 64; k0 = (id >> 4) * 64;
    }
    float(*tile)[65] = (float(*)[65])smem;
    {
      int c = tid & 63, r4 = tid >> 6;
#pragma unroll
      for (int p = 0; p < 16; ++p) {
        int r = r4 + p * 4;
        tile[r][c] = W[(size_t)(k0 + r) * ncols + n0 + c];
      }
    }
    __syncthreads();
    {
      int cc = (tid & 31) * 2, r8 = tid >> 5;
#pragma unroll
      for (int p = 0; p < 8; ++p) {
        int rr = r8 + p * 8;
        bf16x2v o = {(__bf16)tile[cc][rr], (__bf16)tile[cc + 1][rr]};
        *(bf16x2v*)&Wo[(size_t)(n0 + rr) * 1024 + k0 + cc] = o;
      }
    }
  } else {
    // ---- mb_fuse: (mask+bias)*log2e, BOTH b, mask loaded once ----
    int id = bid - 5120;  // [0,1024)
    const int kt = id & 31, qt = id >> 5;
    __bf16(*sm)[68] = (__bf16(*)[68])smem;
    const int r0 = tid >> 4;        // 0..15
    const int cc = (tid & 15) * 4;  // 0,4,..,60
    const float* mrow = mask + (size_t)(qt * 64) * S_LEN + kt * 64;
    float4 mld[4];
#pragma unroll
    for (int p = 0; p < 4; ++p)
      mld[p] = *(const float4*)(mrow + (size_t)(r0 + p * 16) * S_LEN + cc);
    const int w = tid >> 6, lane = tid & 63;
    const int quad = lane >> 4, cl = lane & 15;
    for (int b = 0; b < 2; ++b) {
      const float* brow =
          bias + ((size_t)b * S_LEN + qt * 64) * S_LEN + kt * 64;
#pragma unroll
      for (int p = 0; p < 4; ++p) {
        int r = r0 + p * 16;
        float4 a = *(const float4*)(brow + (size_t)r * S_LEN + cc);
        sm[r][cc + 0] = (__bf16)((mld[p].x + a.x) * LOG2E);
        sm[r][cc + 1] = (__bf16)((mld[p].y + a.y) * LOG2E);
        sm[r][cc + 2] = (__bf16)((mld[p].z + a.z) * LOG2E);
        sm[r][cc + 3] = (__bf16)((mld[p].w + a.w) * LOG2E);
      }
      __syncthreads();
      __bf16 vals[16];
#pragma unroll
      for (int ct = 0; ct < 4; ++ct) {
        bf16x4 v = *(const bf16x4*)&sm[w * 16 + cl][ct * 16 + quad * 4];
        *(bf16x4*)&vals[ct * 4] = v;
      }
      __bf16* op = MB + (((size_t)(b * 32 + qt) * 32 + kt) * 4096) +
                   (w * 64 + lane) * 16;
      *(bf16x8*)op = *(bf16x8*)&vals[0];
      *(bf16x8*)(op + 8) = *(bf16x8*)&vals[8];
      __syncthreads();  // sm reuse for next b
    }
  }
}

// ---------------- QKV projection: bf16 MFMA 128x128 tile ----------------
// Single-barrier LDS double-buffered staging; Q/K scatter epilogue,
// V via per-wave LDS transpose. R17: XCD chunked swizzle -- each XCD
// gets 4 consecutive row-panels (by), all columns: A-panels L2-resident.
__global__ __launch_bounds__(256) void gemm_qkv_mfma(
    const __bf16* __restrict__ Xb, const __bf16* __restrict__ Wt,
    const float* __restrict__ bqkv, __bf16* __restrict__ Qb,
    __bf16* __restrict__ Kb, __bf16* __restrict__ Vtb) {
  // union: As[2]+Bs[2] staging (32KB) during k-loop; 4x 64x72 bf16
  // transpose tiles (36,864B) during the V epilogue.
  __shared__ __align__(16) __bf16 shm[4 * 64 * 72];
  __bf16* As = shm;         // [2][128*32]
  __bf16* Bs = shm + 8192;  // [2][128*32]
  const int tid = threadIdx.x;
  const int w = tid >> 6, lane = tid & 63;
  const int c = lane & 15, quad = lane >> 4;
  const int wm = w >> 1, wn = w & 1;

  // T1 XCD chunked swizzle: 768 wg, 96/XCD -> by in [4k,4k+4) per XCD
  const int bid = blockIdx.y * 24 + blockIdx.x;
  const int swz = (bid & 7) * 96 + (bid >> 3);
  const int bx = swz % 24, by = swz / 24;
  const int rowBase = by * 128;
  const int colBase = bx * 128;

  f32x4 acc[4][4] = {};

  const __bf16* gA0 =
      Xb + (size_t)(rowBase + w * 32 + (lane >> 2)) * 1024 + (lane & 3) * 8;
  const __bf16* gB0 =
      Wt + (size_t)(colBase + w * 32 + (lane >> 2)) * 1024 + (lane & 3) * 8;
  const int lOff = (w * 32) * 32;

  // preamble: stage k0=0 into buffer 0
#pragma unroll
  for (int p = 0; p < 2; ++p) {
    GLD_LDS16(gA0 + (size_t)p * 16 * 1024, As + lOff + p * 16 * 32);
    GLD_LDS16(gB0 + (size_t)p * 16 * 1024, Bs + lOff + p * 16 * 32);
  }
  __syncthreads();

#pragma unroll 2
  for (int k0 = 0; k0 < 1024; k0 += 32) {
    const int cur = (k0 >> 5) & 1, nxt = cur ^ 1;
    // prefetch next K-step into the inactive buffer (full-iter cover)
    if (k0 < 992) {
#pragma unroll
      for (int p = 0; p < 2; ++p) {
        GLD_LDS16(gA0 + (size_t)p * 16 * 1024 + k0 + 32,
                  As + nxt * 4096 + lOff + p * 16 * 32);
        GLD_LDS16(gB0 + (size_t)p * 16 * 1024 + k0 + 32,
                  Bs + nxt * 4096 + lOff + p * 16 * 32);
      }
    }

    bf16x8 af[4], bfr[4];
#pragma unroll
    for (int mt = 0; mt < 4; ++mt)
      af[mt] = *(const bf16x8*)&As[cur * 4096 +
                                   (wm * 64 + mt * 16 + c) * 32 + quad * 8];
#pragma unroll
    for (int nt = 0; nt < 4; ++nt)
      bfr[nt] = *(const bf16x8*)&Bs[cur * 4096 +
                                    (wn * 64 + nt * 16 + c) * 32 + quad * 8];
#pragma unroll
    for (int mt = 0; mt < 4; ++mt)
#pragma unroll
      for (int nt = 0; nt < 4; ++nt)
        acc[mt][nt] = __builtin_amdgcn_mfma_f32_16x16x32_bf16(
            af[mt], bfr[nt], acc[mt][nt], 0, 0, 0);

    // one barrier per K-step: LDS[cur] reads done; implicit vmcnt(0)
    // completes the prefetch DMAs (issued before the full MFMA body).
    __syncthreads();
  }

  if (colBase < 2048) {
    // ---- Q/K epilogue (scatter; 32B-contiguous per quad) ----
#pragma unroll
    for (int mt = 0; mt < 4; ++mt) {
      int row0 = rowBase + wm * 64 + mt * 16 + quad * 4;
#pragma unroll
      for (int nt = 0; nt < 4; ++nt) {
        int col = colBase + wn * 64 + nt * 16 + c;
        float bias = bqkv[col];
        int three = col >> 10;  // 0 or 1
        int h = (col & 1023) >> 6;
        int d = col & 63;
#pragma unroll
        for (int r = 0; r < 4; ++r) {
          int rr = row0 + r;
          int bb = rr >> 11, s = rr & 2047;
          float val = acc[mt][nt][r] + bias;
          size_t ho = (size_t)(bb * NH + h);
          if (three == 0)
            Qb[(ho * S_LEN + s) * HD + d] = (__bf16)val;
          else
            Kb[(ho * S_LEN + s) * HD + d] = (__bf16)val;
        }
      }
    }
  } else {
    // ---- V epilogue: per-wave LDS transpose, coalesced V^T stores ----
    // (final loop barrier already ensures all ds_reads of shm are done)
    __bf16* Tt = shm + w * (64 * 72);  // [d_local][s_local], pad 72
    const int cols0 = colBase + wn * 64;
    const int rows0 = rowBase + wm * 64;
    const int hq = (cols0 & 1023) >> 6;
    const int bb = rows0 >> 11;
    const int sBase = rows0 & 2047;
#pragma unroll
    for (int nt = 0; nt < 4; ++nt) {
      float bias = bqkv[cols0 + nt * 16 + c];
#pragma unroll
      for (int mt = 0; mt < 4; ++mt) {
        __bf16 t4[4];
#pragma unroll
        for (int r = 0; r < 4; ++r) t4[r] = (__bf16)(acc[mt][nt][r] + bias);
        *(bf16x4*)&Tt[(nt * 16 + c) * 72 + mt * 16 + quad * 4] =
            *(bf16x4*)t4;
      }
    }
    __syncthreads();
    const size_t vbase = ((size_t)(bb * NH + hq) * HD) * S_LEN;
    const int s0 = (lane & 7) * 8;
    const int dl0 = lane >> 3;  // 0..7
#pragma unroll
    for (int dt = 0; dt < 8; ++dt) {
      int dl = dt * 8 + dl0;
      bf16x8 v = *(const bf16x8*)&Tt[dl * 72 + s0];
      *(bf16x8*)&Vtb[vbase + (size_t)dl * S_LEN + sBase + s0] = v;
    }
  }
}

// ------- MFMA flash attention: S^T dataflow, QBLK=128, 2 subtiles/barrier
// R5 structure (proven): TWO 64-key subtiles per barrier region (KVBLK=128
// effective, 64KB LDS), plain __syncthreads, unroll-2, batched nMB register
// double-buffer. R17: XCD chunked swizzle -- 4 consecutive heads per XCD
// -> K/V (2MB) L2-resident; shortens the DMA latency the barrier drains on.
__global__ __launch_bounds__(256) void attn_mfma(
    const __bf16* __restrict__ Qb, const __bf16* __restrict__ Kb,
    const __bf16* __restrict__ Vtb, const __bf16* __restrict__ MB,
    __bf16* __restrict__ AOb) {
  // T1 swizzle: 512 wg, 64/XCD -> 4 consecutive (b,h) heads per XCD
  const int bid = (blockIdx.z * 16 + blockIdx.y) * 16 + blockIdx.x;
  const int swz = (bid & 7) * 64 + (bid >> 3);
  const int qt = swz & 15;
  const int h = (swz >> 4) & 15;
  const int b = swz >> 8;
  const int tid = threadIdx.x;
  const int w = tid >> 6;
  const int lane = tid & 63;
  const int c = lane & 15;
  const int quad = lane >> 4;

  __shared__ __align__(16) __bf16 Ks[2][2][64 * 64];  // [dbuf][subtile]
  __shared__ __align__(16) __bf16 Vs[2][2][64 * 64];  // [feat][key], swizzled
#if !HAVE_MFMA_16x16x16_BF16
  __shared__ __align__(16) __bf16 P2[4][16 * 72];
#endif

  const size_t headoff = (size_t)(b * NH + h) * S_LEN * HD;
  const __bf16* Qg = Qb + headoff + (size_t)(qt * 128) * HD;
  const __bf16* Kg = Kb + headoff;
  const __bf16* Vg = Vtb + headoff;  // [hd][S]
  const __bf16* MBq0 =
      MB + ((size_t)(b * 32 + qt * 2 + 0) * 32) * 4096 + (w * 64 + lane) * 16;
  const __bf16* MBq1 =
      MB + ((size_t)(b * 32 + qt * 2 + 1) * 32) * 4096 + (w * 64 + lane) * 16;

  // staging geometry (chunk ch = p*256+tid -> row f, col-chunk j, swizzled)
  const int f0 = tid >> 3, f1 = f0 + 32;
  const int j = tid & 7;
  const int sj0 = j ^ (f0 & 7);
  const int sj1 = j ^ (f1 & 7);
  const int lds0 = tid * 8;
  const int lds1 = (256 + tid) * 8;

  // Q fragments: lane holds Q[qrow=g*64+w*16+c][d=quad*8+j] (loop-invariant)
  bf16x8 qa[2][2];
#pragma unroll
  for (int g = 0; g < 2; ++g) {
    qa[g][0] = *(const bf16x8*)(Qg + (g * 64 + w * 16 + c) * HD + quad * 8);
    qa[g][1] =
        *(const bf16x8*)(Qg + (g * 64 + w * 16 + c) * HD + quad * 8 + 32);
  }

  // swizzled b128 read offsets (row&7 == c&7)
  const int rs0 = (quad ^ (c & 7)) * 8;
  const int rs1 = ((quad + 4) ^ (c & 7)) * 8;

  f32x4 Oa[2][4] = {};  // O^T[d=ft*16+quad*4+r][qrow=c] per group
  f32x4 psum[2] = {};   // packed row-partial sums of p per group

  const float c1 = 0.125f * LOG2E;  // 1/sqrt(hd) * log2(e)

  // one-subtile compute: QK -> softmax (with rmb) -> PV, accumulate Oa/psum
  auto subtile = [&](const __bf16* KsS, const __bf16* VsS,
                     bf16x8(&rmb)[2][2]) {
    bf16x8 kf0[4], kf1[4];
#pragma unroll
    for (int ct = 0; ct < 4; ++ct) {
      kf0[ct] = *(const bf16x8*)&KsS[(ct * 16 + c) * 64 + rs0];
      kf1[ct] = *(const bf16x8*)&KsS[(ct * 16 + c) * 64 + rs1];
    }
    f32x4 sv[2][4];
    __builtin_amdgcn_s_setprio(1);
#pragma unroll
    for (int g = 0; g < 2; ++g)
#pragma unroll
      for (int ct = 0; ct < 4; ++ct) {
        f32x4 a = {};
        a = __builtin_amdgcn_mfma_f32_16x16x32_bf16(kf0[ct], qa[g][0], a, 0,
                                                    0, 0);
        a = __builtin_amdgcn_mfma_f32_16x16x32_bf16(kf1[ct], qa[g][1], a, 0,
                                                    0, 0);
        sv[g][ct] = a;
      }
    __builtin_amdgcn_s_setprio(0);

#if HAVE_MFMA_16x16x16_BF16
    s16x4 vf[4][4];
#pragma unroll
    for (int ft = 0; ft < 4; ++ft) {
      const int fr = ft * 16 + c;
#pragma unroll
      for (int ct = 0; ct < 4; ++ct) {
        const int chunk = ((ct * 2 + (quad >> 1)) ^ (fr & 7)) * 8 +
                          (quad & 1) * 4;
        vf[ft][ct] = *(const s16x4*)&VsS[fr * 64 + chunk];
      }
    }
#endif

    s16x4 pb[2][4];
#pragma unroll
    for (int g = 0; g < 2; ++g)
#pragma unroll
      for (int ct = 0; ct < 4; ++ct) {
        f32x4 pv;
#pragma unroll
        for (int r = 0; r < 4; ++r) {
          float mb = (ct < 2) ? (float)rmb[g][0][ct * 4 + r]
                              : (float)rmb[g][1][(ct - 2) * 4 + r];
          pv[r] = EXP2F(sv[g][ct][r] * c1 + mb);
        }
        psum[g] += pv;
        __bf16 t4[4];
#pragma unroll
        for (int r = 0; r < 4; ++r) t4[r] = (__bf16)pv[r];
        pb[g][ct] = *(s16x4*)t4;
      }

#if HAVE_MFMA_16x16x16_BF16
    __builtin_amdgcn_s_setprio(1);
#pragma unroll
    for (int g = 0; g < 2; ++g)
#pragma unroll
      for (int ft = 0; ft < 4; ++ft)
#pragma unroll
        for (int ct = 0; ct < 4; ++ct)
          Oa[g][ft] = __builtin_amdgcn_mfma_f32_16x16x16bf16_1k(
              vf[ft][ct], pb[g][ct], Oa[g][ft], 0, 0, 0);
    __builtin_amdgcn_s_setprio(0);
#else
#pragma unroll
    for (int g = 0; g < 2; ++g) {
#pragma unroll
      for (int ct = 0; ct < 4; ++ct)
        *(bf16x4*)&P2[w][c * 72 + ct * 16 + quad * 4] = *(bf16x4*)&pb[g][ct];
      bf16x8 pf0 = *(const bf16x8*)&P2[w][c * 72 + quad * 8];
      bf16x8 pf1 = *(const bf16x8*)&P2[w][c * 72 + 32 + quad * 8];
#pragma unroll
      for (int ft = 0; ft < 4; ++ft) {
        const int fr = ft * 16 + c;
        bf16x8 vv0 = *(const bf16x8*)&VsS[fr * 64 + rs0];
        bf16x8 vv1 = *(const bf16x8*)&VsS[fr * 64 + rs1];
        Oa[g][ft] = __builtin_amdgcn_mfma_f32_16x16x32_bf16(vv0, pf0,
                                                            Oa[g][ft], 0, 0, 0);
        Oa[g][ft] = __builtin_amdgcn_mfma_f32_16x16x32_bf16(vv1, pf1,
                                                            Oa[g][ft], 0, 0, 0);
      }
    }
#endif
  };

  // preamble: DMA tile pair (0,1) into dbuf 0
  GLD_LDS16(Kg + (size_t)f0 * HD + sj0 * 8, &Ks[0][0][lds0]);
  GLD_LDS16(Kg + (size_t)f1 * HD + sj1 * 8, &Ks[0][0][lds1]);
  GLD_LDS16(Kg + (size_t)(64 + f0) * HD + sj0 * 8, &Ks[0][1][lds0]);
  GLD_LDS16(Kg + (size_t)(64 + f1) * HD + sj1 * 8, &Ks[0][1][lds1]);
  GLD_LDS16(Vg + (size_t)f0 * S_LEN + sj0 * 8, &Vs[0][0][lds0]);
  GLD_LDS16(Vg + (size_t)f1 * S_LEN + sj1 * 8, &Vs[0][0][lds1]);
  GLD_LDS16(Vg + (size_t)f0 * S_LEN + 64 + sj0 * 8, &Vs[0][1][lds0]);
  GLD_LDS16(Vg + (size_t)f1 * S_LEN + 64 + sj1 * 8, &Vs[0][1][lds1]);

  // strength-reduced DMA source pointers (tile pair (2,3))
  const __bf16* kgp0 = Kg + (size_t)(128 + f0) * HD + sj0 * 8;
  const __bf16* kgp1 = Kg + (size_t)(128 + f1) * HD + sj1 * 8;
  const __bf16* vgp0 = Vg + (size_t)f0 * S_LEN + 128 + sj0 * 8;
  const __bf16* vgp1 = Vg + (size_t)f1 * S_LEN + 128 + sj1 * 8;

  // MB fragments: subtile A = tile 0, subtile B = tile 1
  bf16x8 rMBA[2][2], rMBB[2][2];
  rMBA[0][0] = *(const bf16x8*)MBq0;
  rMBA[0][1] = *(const bf16x8*)(MBq0 + 8);
  rMBA[1][0] = *(const bf16x8*)MBq1;
  rMBA[1][1] = *(const bf16x8*)(MBq1 + 8);
  rMBB[0][0] = *(const bf16x8*)(MBq0 + 4096);
  rMBB[0][1] = *(const bf16x8*)(MBq0 + 4096 + 8);
  rMBB[1][0] = *(const bf16x8*)(MBq1 + 4096);
  rMBB[1][1] = *(const bf16x8*)(MBq1 + 4096 + 8);

  __syncthreads();

#pragma unroll 2
  for (int t = 0; t < 16; ++t) {
    const int cur = t & 1, nxt = cur ^ 1;
    // async DMA of the next tile pair into the inactive dbuf
    if (t < 15) {
      GLD_LDS16(kgp0, &Ks[nxt][0][lds0]);
      GLD_LDS16(kgp1, &Ks[nxt][0][lds1]);
      GLD_LDS16(kgp0 + 64 * HD, &Ks[nxt][1][lds0]);
      GLD_LDS16(kgp1 + 64 * HD, &Ks[nxt][1][lds1]);
      GLD_LDS16(vgp0, &Vs[nxt][0][lds0]);
      GLD_LDS16(vgp1, &Vs[nxt][0][lds1]);
      GLD_LDS16(vgp0 + 64, &Vs[nxt][1][lds0]);
      GLD_LDS16(vgp1 + 64, &Vs[nxt][1][lds1]);
    }
    kgp0 += 128 * HD;
    kgp1 += 128 * HD;
    vgp0 += 128;
    vgp1 += 128;

    // ---- subtile A (tile 2t) ----
    subtile(&Ks[cur][0][0], &Vs[cur][0][0], rMBA);

    // next iteration's MB fragments (tiles 2t+2, 2t+3); issued between
    // subtiles so HBM/L2 latency hides under subtile-B compute. Over-read
    // on the final iteration lands in the following MB tiles / Wt2 region
    // (allocated, read-only -- safe).
    bf16x8 nMBA[2][2], nMBB[2][2];
    {
      const __bf16* m0 = MBq0 + (size_t)(2 * t + 2) * 4096;
      const __bf16* m1 = MBq1 + (size_t)(2 * t + 2) * 4096;
      nMBA[0][0] = *(const bf16x8*)m0;
      nMBA[0][1] = *(const bf16x8*)(m0 + 8);
      nMBA[1][0] = *(const bf16x8*)m1;
      nMBA[1][1] = *(const bf16x8*)(m1 + 8);
      nMBB[0][0] = *(const bf16x8*)(m0 + 4096);
      nMBB[0][1] = *(const bf16x8*)(m0 + 4096 + 8);
      nMBB[1][0] = *(const bf16x8*)(m1 + 4096);
      nMBB[1][1] = *(const bf16x8*)(m1 + 4096 + 8);
    }

    // ---- subtile B (tile 2t+1) ----
    subtile(&Ks[cur][1][0], &Vs[cur][1][0], rMBB);

#pragma unroll
    for (int g = 0; g < 2; ++g) {
      rMBA[g][0] = nMBA[g][0];
      rMBA[g][1] = nMBA[g][1];
      rMBB[g][0] = nMBB[g][0];
      rMBB[g][1] = nMBB[g][1];
    }

    // one barrier per PAIR: LDS[cur] reads done; implicit vmcnt(0) completes
    // the next pair's DMAs (issued before ~2x compute).
    __syncthreads();
  }

  // full row sum + normalize + store, per group
#pragma unroll
  for (int g = 0; g < 2; ++g) {
    float lsum = psum[g][0] + psum[g][1] + psum[g][2] + psum[g][3];
    lsum += __shfl_xor(lsum, 16);
    lsum += __shfl_xor(lsum, 32);
    const float invl = 1.0f / lsum;
    __bf16* orow = AOb +
                   (size_t)(b * S_LEN + qt * 128 + g * 64 + w * 16 + c) *
                       DMODEL +
                   h * HD;
#pragma unroll
    for (int ft = 0; ft < 4; ++ft) {
      __bf16 t4[4];
#pragma unroll
      for (int r = 0; r < 4; ++r) t4[r] = (__bf16)(Oa[g][ft][r] * invl);
      *(bf16x4*)(orow + ft * 16 + quad * 4) = *(bf16x4*)t4;
    }
  }
}

// ---------------- Output projection: bf16 MFMA 128x64 tile ----------------
// R17: XCD swizzle (Wt2 2MB L2-resident per XCD) + BK=64 pair-processing
// (2 subtiles per barrier; grid-limited 2 wg/CU so 48KB LDS is free).
__global__ __launch_bounds__(256) void gemm_out_mfma(
    const __bf16* __restrict__ AOb, const __bf16* __restrict__ Wt2,
    const float* __restrict__ bout, float* __restrict__ Out) {
  __shared__ __align__(16) __bf16 As[2][2][128 * 32];  // [dbuf][sub]
  __shared__ __align__(16) __bf16 Bs[2][2][64 * 32];
  const int tid = threadIdx.x;
  const int w = tid >> 6, lane = tid & 63;
  const int c = lane & 15, quad = lane >> 4;

  // T1 swizzle: 512 wg, 64/XCD -> 4 consecutive row-panels per XCD
  const int bid = blockIdx.y * 16 + blockIdx.x;
  const int swz = (bid & 7) * 64 + (bid >> 3);
  const int bx = swz & 15, by = swz >> 4;
  const int rowBase = by * 128;
  const int colBase = bx * 64;

  f32x4 acc[2][4] = {};

  const __bf16* gA0 =
      AOb + (size_t)(rowBase + w * 32 + (lane >> 2)) * 1024 + (lane & 3) * 8;
  const __bf16* gB0 =
      Wt2 + (size_t)(colBase + w * 16 + (lane >> 2)) * 1024 + (lane & 3) * 8;
  const int lA = (w * 32) * 32;
  const int lB = (w * 16) * 32;

  // preamble: stage K-steps 0,32 into dbuf 0 (subs 0,1)
#pragma unroll
  for (int s = 0; s < 2; ++s) {
#pragma unroll
    for (int p = 0; p < 2; ++p)
      GLD_LDS16(gA0 + (size_t)p * 16 * 1024 + s * 32,
                &As[0][s][lA + p * 16 * 32]);
    GLD_LDS16(gB0 + s * 32, &Bs[0][s][lB]);
  }
  __syncthreads();

#pragma unroll 2
  for (int t = 0; t < 16; ++t) {
    const int cur = t & 1, nxt = cur ^ 1;
    const int k0 = t * 64;
    // prefetch next pair into the inactive dbuf (2x compute cover)
    if (t < 15) {
#pragma unroll
      for (int s = 0; s < 2; ++s) {
#pragma unroll
        for (int p = 0; p < 2; ++p)
          GLD_LDS16(gA0 + (size_t)p * 16 * 1024 + k0 + 64 + s * 32,
                    &As[nxt][s][lA + p * 16 * 32]);
        GLD_LDS16(gB0 + k0 + 64 + s * 32, &Bs[nxt][s][lB]);
      }
    }

#pragma unroll
    for (int s = 0; s < 2; ++s) {
      bf16x8 af[2], bfr[4];
#pragma unroll
      for (int mt = 0; mt < 2; ++mt)
        af[mt] = *(const bf16x8*)&As[cur][s]
                                    [(w * 32 + mt * 16 + c) * 32 + quad * 8];
#pragma unroll
      for (int nt = 0; nt < 4; ++nt)
        bfr[nt] = *(const bf16x8*)&Bs[cur][s][(nt * 16 + c) * 32 + quad * 8];
#pragma unroll
      for (int mt = 0; mt < 2; ++mt)
#pragma unroll
        for (int nt = 0; nt < 4; ++nt)
          acc[mt][nt] = __builtin_amdgcn_mfma_f32_16x16x32_bf16(
              af[mt], bfr[nt], acc[mt][nt], 0, 0, 0);
    }

    // one barrier per PAIR
    __syncthreads();
  }

#pragma unroll
  for (int mt = 0; mt < 2; ++mt) {
    int row0 = rowBase + w * 32 + mt * 16 + quad * 4;
#pragma unroll
    for (int nt = 0; nt < 4; ++nt) {
      int col = colBase + nt * 16 + c;
      float bias = bout[col];
#pragma unroll
      for (int r = 0; r < 4; ++r)
        Out[(size_t)(row0 + r) * 1024 + col] = acc[mt][nt][r] + bias;
    }
  }
}

extern "C" void kernel_launch(void* const* d_in, const int* in_sizes, int n_in,
                              void* d_out, int out_size, void* d_ws,
                              size_t ws_size, hipStream_t stream) {
  const float* x = (const float*)d_in[0];
  const float* attn_mask = (const float*)d_in[1];
  const float* attn_bias = (const float*)d_in[2];
  const float* Wqkv = (const float*)d_in[3];
  const float* bqkv = (const float*)d_in[4];
  const float* Wout = (const float*)d_in[5];
  const float* bout = (const float*)d_in[6];
  float* out = (float*)d_out;

  __bf16* base = (__bf16*)d_ws;
  __bf16* Xb = base;                  // [0, 4M)
  __bf16* AOb = base;                 // aliases Xb (disjoint lifetime)
  __bf16* Wt = base + 4194304;        // [4M, 7M)
  __bf16* Qb = base + 8388608;        // [8M, 12M)
  __bf16* Kb = base + 12582912;       // [12M, 16M)
  __bf16* Vtb = base + 16777216;      // [16M, 20M)
  __bf16* MB = base + 20971520;       // [20M, 28M)
  __bf16* Wt2 = base + 29360128;      // [28M, 29M)

  preprocess<<<6144, 256, 0, stream>>>(x, attn_mask, attn_bias, Wqkv, Wout,
                                       Xb, Wt, Wt2, MB);
  gemm_qkv_mfma<<<dim3(24, 32), 256, 0, stream>>>(Xb, Wt, bqkv, Qb, Kb, Vtb);
  attn_mfma<<<dim3(16, NH, 2), 256, 0, stream>>>(Qb, Kb, Vtb, MB, AOb);
  gemm_out_mfma<<<dim3(16, 32), 256, 0, stream>>>(AOb, Wt2, bout, out);
}